// Round 10
// baseline (222.904 us; speedup 1.0000x reference)
//
#include <hip/hip_runtime.h>
#include <cstdint>
#include <cstddef>

#define B_   16
#define C_   512
#define H_   32
#define W_   32
#define HW_  1024
#define TC_  64
#define T_   48

typedef unsigned short u16;
typedef __attribute__((ext_vector_type(8))) short short8v;
typedef __attribute__((ext_vector_type(4))) float f32x4;

// ---------------------------------------------------------------------------
// bf16 helpers
// ---------------------------------------------------------------------------
__device__ __forceinline__ u16 tobf(float x) {
    unsigned u = __float_as_uint(x);
    return (u16)((u + 0x7FFFu + ((u >> 16) & 1u)) >> 16);    // RTNE
}
__device__ __forceinline__ float frombf(u16 h) {
    return __uint_as_float(((unsigned)h) << 16);
}

__device__ __forceinline__ void gld16(const void* g, void* l) {
    __builtin_amdgcn_global_load_lds(
        (const __attribute__((address_space(1))) void*)g,
        (__attribute__((address_space(3))) void*)l, 16, 0, 0);
}

// ---------------------------------------------------------------------------
// 1) Frobenius-norm helpers: partial[64][1024] (256 blocks of 128 rows)
// ---------------------------------------------------------------------------
__global__ void k_colsq(const float* __restrict__ x, float* __restrict__ partial) {
    int bid = blockIdx.x;            // 256 blocks: 4 col-tiles x 64 row-tiles
    int col = (bid & 3) * 256 + threadIdx.x;
    int r0  = (bid >> 2) * 128;
    const float* p = x + (size_t)r0 * HW_ + col;
    float s = 0.f;
    for (int r = 0; r < 128; ++r) { float v = p[(size_t)r * HW_]; s += v * v; }
    partial[(size_t)(bid >> 2) * HW_ + col] = s;
}

__global__ void k_rsqrt(const float* __restrict__ partial, float* __restrict__ ninv) {
    int i = blockIdx.x * 256 + threadIdx.x;
    if (i < HW_) {
        float s = 0.f;
        for (int r = 0; r < 64; ++r) s += partial[(size_t)r * HW_ + i];
        ninv[i] = rsqrtf(s);
    }
}

// ---------------------------------------------------------------------------
// 2) transpose + normalize: x [B,C,HW] -> xnH bf16 [B,HW,C]
// ---------------------------------------------------------------------------
__global__ void k_transpose(const float* __restrict__ x, const float* __restrict__ ninv,
                            u16* __restrict__ obH) {
    __shared__ float tile[32][33];
    int b  = blockIdx.z;
    int m0 = blockIdx.x * 32, c0 = blockIdx.y * 32;
    int tx = threadIdx.x, ty = threadIdx.y;
    const float* xb = x + (size_t)b * C_ * HW_;
    #pragma unroll
    for (int j = 0; j < 32; j += 8)
        tile[ty + j][tx] = xb[(size_t)(c0 + ty + j) * HW_ + m0 + tx];
    __syncthreads();
    size_t base = (size_t)b * HW_ * C_;
    #pragma unroll
    for (int j = 0; j < 32; j += 8) {
        int m = m0 + ty + j;
        obH[base + (size_t)m * C_ + c0 + tx] = tobf(tile[tx][ty + j] * ninv[m]);
    }
}

// ---------------------------------------------------------------------------
// 3) weight prep (hi plane only)
// ---------------------------------------------------------------------------
__global__ void k_packW(const float* __restrict__ in, u16* __restrict__ oh) {
    size_t i = (size_t)blockIdx.x * 256 + threadIdx.x;
    oh[i] = tobf(in[i]);
}
__global__ void k_packFG(const float* __restrict__ fW, const float* __restrict__ gW,
                         const float* __restrict__ fb, const float* __restrict__ gb,
                         u16* __restrict__ oh, float* __restrict__ fgb) {
    int idx = blockIdx.x * 256 + threadIdx.x;   // 65536
    int row = idx >> 9, c = idx & 511;
    float v = (row < 64) ? fW[row * 512 + c] : gW[(row - 64) * 512 + c];
    oh[idx] = tobf(v);
    if (idx < 128) fgb[idx] = (idx < 64) ? fb[idx] : gb[idx - 64];
}

// ---------------------------------------------------------------------------
// 4a) 1-term bf16 MFMA GEMM, 128x128, 4 waves, counted-vmcnt 2-phase (r9)
// ---------------------------------------------------------------------------
template<int PERMB, int EPI>
__global__ __launch_bounds__(256) void k_gemm1(
    const u16* __restrict__ A, const u16* __restrict__ Bm,
    const float* __restrict__ bias,
    float* __restrict__ Cf, u16* __restrict__ Ch,
    const float* __restrict__ scaleP,
    int N, int K, int lda, int ldb, long sA, long sB, long sC)
{
    __shared__ u16 lds[2 * 8192];
    const int b = blockIdx.z;
    const u16* pA = A + (size_t)b * sA;
    const u16* pB = Bm + (size_t)b * sB;
    const int m0 = blockIdx.y * 128, n0 = blockIdx.x * 128;
    const int tid = threadIdx.x, wave = tid >> 6, lane = tid & 63;
    const int wm = wave >> 1, wn = wave & 1;
    const int g = lane >> 4;

    f32x4 acc[4][4];
    #pragma unroll
    for (int i = 0; i < 4; ++i)
        #pragma unroll
        for (int j = 0; j < 4; ++j) { f32x4 z = {0.f,0.f,0.f,0.f}; acc[i][j] = z; }

    auto STAGE = [&](int kt, int half) {
        const int k0 = kt << 5;
        u16* lb = lds + half * 8192;
        #pragma unroll
        for (int q = 0; q < 4; ++q) {
            int ci = wave * 4 + q;
            bool isA = ci < 8;
            int li = ci & 7;
            const u16* gp = isA ? pA : pB;
            int ld = isA ? lda : ldb;
            int rb = isA ? m0 : n0;
            int rp = li * 8 + (lane >> 3);
            int gg = (lane & 7) ^ (rp & 7);
            int r  = rp * 2 + (gg >> 2);
            int kc = k0 + (gg & 3) * 8;
            int rowg = rb + r;
            if (PERMB && !isA) rowg = ((rowg & 31) << 5) | (rowg >> 5);
            gld16(gp + (size_t)rowg * ld + kc,
                  lb + (isA ? 0 : 4096) + li * 512 + lane * 8);
        }
    };
    auto COMPUTE = [&](int half) {
        const u16* As = lds + half * 8192;
        const u16* Bs = As + 4096;
        short8v av[4];
        #pragma unroll
        for (int i = 0; i < 4; ++i) {
            int r = wm * 64 + i * 16 + (lane & 15);
            int rp = r >> 1, gg = ((r & 1) << 2) + g;
            av[i] = *(const short8v*)(As + rp * 64 + ((gg ^ (rp & 7)) << 3));
        }
        #pragma unroll
        for (int j = 0; j < 4; ++j) {
            int r = wn * 64 + j * 16 + (lane & 15);
            int rp = r >> 1, gg = ((r & 1) << 2) + g;
            short8v bv = *(const short8v*)(Bs + rp * 64 + ((gg ^ (rp & 7)) << 3));
            #pragma unroll
            for (int i = 0; i < 4; ++i)
                acc[i][j] = __builtin_amdgcn_mfma_f32_16x16x32_bf16(av[i], bv, acc[i][j], 0, 0, 0);
        }
    };

    const int nkt = K >> 5;
    STAGE(0, 0);
    int cur = 0;
    for (int kt = 0; kt < nkt; ++kt) {
        if (kt + 1 < nkt) {
            STAGE(kt + 1, cur ^ 1);
            asm volatile("s_waitcnt vmcnt(4)" ::: "memory");
        } else {
            asm volatile("s_waitcnt vmcnt(0)" ::: "memory");
        }
        __builtin_amdgcn_s_barrier();
        __builtin_amdgcn_sched_barrier(0);
        COMPUTE(cur);
        __builtin_amdgcn_sched_barrier(0);
        __builtin_amdgcn_s_barrier();
        cur ^= 1;
    }

    const float sc = (EPI == 2) ? scaleP[0] : 0.f;
    const int colbase = n0 + wn * 64 + (lane & 15);
    const int rowbase = m0 + wm * 64 + ((lane >> 4) << 2);
    #pragma unroll
    for (int i = 0; i < 4; ++i)
        #pragma unroll
        for (int j = 0; j < 4; ++j) {
            int col = colbase + j * 16;
            #pragma unroll
            for (int rg = 0; rg < 4; ++rg) {
                int row = rowbase + i * 16 + rg;
                size_t idx = (size_t)b * sC + (size_t)row * N + col;
                float a = acc[i][j][rg];
                if (EPI == 0)      Cf[idx] = a;
                else if (EPI == 2) Ch[idx] = tobf(sc * a + frombf(Ch[idx]));
                else if (EPI == 4) Ch[idx] = tobf(a);
                else if (EPI == 5) Ch[idx] = tobf(a + bias[row]);
                else               Ch[idx] = tobf(a + bias[col]);
            }
        }
}

// ---------------------------------------------------------------------------
// 4b) 1-term bf16 MFMA GEMM, 128x256, 8 waves, counted-vmcnt (r9)
// ---------------------------------------------------------------------------
template<int PERMB, int EPI>
__global__ __launch_bounds__(512) void k_gemm2(
    const u16* __restrict__ A, const u16* __restrict__ Bm,
    const float* __restrict__ bias,
    float* __restrict__ Cf, u16* __restrict__ Ch,
    const float* __restrict__ scaleP,
    int N, int K, int lda, int ldb, long sA, long sB, long sC)
{
    __shared__ u16 lds[2 * 12288];
    const int b = blockIdx.z;
    const u16* pA = A + (size_t)b * sA;
    const u16* pB = Bm + (size_t)b * sB;
    const int m0 = blockIdx.y * 128, n0 = blockIdx.x * 256;
    const int tid = threadIdx.x, wave = tid >> 6, lane = tid & 63;
    const int wm = wave >> 2, wn = wave & 3;
    const int g = lane >> 4;

    f32x4 acc[4][4];
    #pragma unroll
    for (int i = 0; i < 4; ++i)
        #pragma unroll
        for (int j = 0; j < 4; ++j) { f32x4 z = {0.f,0.f,0.f,0.f}; acc[i][j] = z; }

    auto STAGE = [&](int kt, int half) {
        const int k0 = kt << 5;
        u16* lb = lds + half * 12288;
        #pragma unroll
        for (int q = 0; q < 3; ++q) {
            int ci = wave * 3 + q;
            bool isA = ci < 8;
            int li = isA ? ci : ci - 8;
            const u16* gp = isA ? pA : pB;
            int ld = isA ? lda : ldb;
            int rb = isA ? m0 : n0;
            int rp = li * 8 + (lane >> 3);
            int gg = (lane & 7) ^ (rp & 7);
            int r  = rp * 2 + (gg >> 2);
            int kc = k0 + (gg & 3) * 8;
            int rowg = rb + r;
            if (PERMB && !isA) rowg = ((rowg & 31) << 5) | (rowg >> 5);
            gld16(gp + (size_t)rowg * ld + kc,
                  lb + (isA ? 0 : 4096) + li * 512 + lane * 8);
        }
    };
    auto COMPUTE = [&](int half) {
        const u16* As = lds + half * 12288;
        const u16* Bs = As + 4096;
        short8v av[4];
        #pragma unroll
        for (int i = 0; i < 4; ++i) {
            int r = wm * 64 + i * 16 + (lane & 15);
            int rp = r >> 1, gg = ((r & 1) << 2) + g;
            av[i] = *(const short8v*)(As + rp * 64 + ((gg ^ (rp & 7)) << 3));
        }
        #pragma unroll
        for (int j = 0; j < 4; ++j) {
            int r = wn * 64 + j * 16 + (lane & 15);
            int rp = r >> 1, gg = ((r & 1) << 2) + g;
            short8v bv = *(const short8v*)(Bs + rp * 64 + ((gg ^ (rp & 7)) << 3));
            #pragma unroll
            for (int i = 0; i < 4; ++i)
                acc[i][j] = __builtin_amdgcn_mfma_f32_16x16x32_bf16(av[i], bv, acc[i][j], 0, 0, 0);
        }
    };

    const int nkt = K >> 5;
    STAGE(0, 0);
    int cur = 0;
    for (int kt = 0; kt < nkt; ++kt) {
        if (kt + 1 < nkt) {
            STAGE(kt + 1, cur ^ 1);
            asm volatile("s_waitcnt vmcnt(3)" ::: "memory");
        } else {
            asm volatile("s_waitcnt vmcnt(0)" ::: "memory");
        }
        __builtin_amdgcn_s_barrier();
        __builtin_amdgcn_sched_barrier(0);
        COMPUTE(cur);
        __builtin_amdgcn_sched_barrier(0);
        __builtin_amdgcn_s_barrier();
        cur ^= 1;
    }

    const float sc = (EPI == 2) ? scaleP[0] : 0.f;
    const int colbase = n0 + wn * 64 + (lane & 15);
    const int rowbase = m0 + wm * 64 + ((lane >> 4) << 2);
    #pragma unroll
    for (int i = 0; i < 4; ++i)
        #pragma unroll
        for (int j = 0; j < 4; ++j) {
            int col = colbase + j * 16;
            #pragma unroll
            for (int rg = 0; rg < 4; ++rg) {
                int row = rowbase + i * 16 + rg;
                size_t idx = (size_t)b * sC + (size_t)row * N + col;
                float a = acc[i][j][rg];
                if (EPI == 0)      Cf[idx] = a;
                else if (EPI == 2) Ch[idx] = tobf(sc * a + frombf(Ch[idx]));
                else if (EPI == 4) Ch[idx] = tobf(a);
                else if (EPI == 5) Ch[idx] = tobf(a + bias[row]);
                else               Ch[idx] = tobf(a + bias[col]);
            }
        }
}

// ---------------------------------------------------------------------------
// 5) row softmax on bf16 S, u16 in-place
// ---------------------------------------------------------------------------
__global__ __launch_bounds__(256) void k_softmax(u16* __restrict__ S) {
    size_t row = blockIdx.x;
    u16* r = S + row * (size_t)HW_;
    int t = threadIdx.x;
    ushort4 raw = ((const ushort4*)r)[t];
    float v0 = frombf(raw.x), v1 = frombf(raw.y), v2 = frombf(raw.z), v3 = frombf(raw.w);

    __shared__ float redm[4], reds[4];
    int wid = t >> 6, lane = t & 63;

    float m = fmaxf(fmaxf(v0, v1), fmaxf(v2, v3));
    for (int o = 32; o > 0; o >>= 1) m = fmaxf(m, __shfl_down(m, o));
    if (lane == 0) redm[wid] = m;
    __syncthreads();
    if (t == 0) redm[0] = fmaxf(fmaxf(redm[0], redm[1]), fmaxf(redm[2], redm[3]));
    __syncthreads();
    m = redm[0];

    v0 = expf(v0 - m); v1 = expf(v1 - m); v2 = expf(v2 - m); v3 = expf(v3 - m);
    float s = v0 + v1 + v2 + v3;
    for (int o = 32; o > 0; o >>= 1) s += __shfl_down(s, o);
    if (lane == 0) reds[wid] = s;
    __syncthreads();
    if (t == 0) reds[0] = reds[0] + reds[1] + reds[2] + reds[3];
    __syncthreads();
    float inv = 1.f / reds[0];
    ushort4 o4;
    o4.x = tobf(v0 * inv); o4.y = tobf(v1 * inv);
    o4.z = tobf(v2 * inv); o4.w = tobf(v3 * inv);
    ((ushort4*)r)[t] = o4;
}

// ---------------------------------------------------------------------------
// 6) single-plane u16 transpose of fdd flat view [512][1024] -> fddT [1024][512]
// ---------------------------------------------------------------------------
__global__ void k_tposeU1(const u16* __restrict__ src, u16* __restrict__ dst) {
    __shared__ u16 tile[32][33];
    int b = blockIdx.z;
    const u16* sb = src + (size_t)b * (C_ * HW_);
    u16* db = dst + (size_t)b * (C_ * HW_);
    int c0 = blockIdx.x * 32, r0 = blockIdx.y * 32;
    int tx = threadIdx.x, ty = threadIdx.y;
    #pragma unroll
    for (int j = 0; j < 32; j += 8)
        tile[ty + j][tx] = sb[(size_t)(r0 + ty + j) * HW_ + c0 + tx];
    __syncthreads();
    #pragma unroll
    for (int j = 0; j < 32; j += 8)
        db[(size_t)(c0 + ty + j) * C_ + r0 + tx] = tile[tx][ty + j];
}

// ---------------------------------------------------------------------------
// 7) FUSED corr + top-48: block = (32-row stripe, batch). K=512, 8 waves.
//    B-panel (fddT, L2-resident 1 MB/batch) staged in 64 KB K-chunks, dbuf,
//    counted vmcnt(9). After K-loop: corr rows -> LDS, wave-per-row tau-prune
//    top-48 (r8-verified; groups strided by 64 for conflict-free LDS reads).
//    corr never touches HBM.
// ---------------------------------------------------------------------------
__device__ __forceinline__ float sort64_desc(float v, int lane) {
    #pragma unroll
    for (int k = 2; k <= 64; k <<= 1) {
        #pragma unroll
        for (int j = k >> 1; j > 0; j >>= 1) {
            float o = __shfl_xor(v, j);
            bool takeMax = (((lane & k) == 0) == ((lane & j) == 0));
            v = takeMax ? fmaxf(v, o) : fminf(v, o);
        }
    }
    return v;
}
__device__ __forceinline__ float bmerge64_desc(float a, float b, int lane) {
    float br = __shfl(b, 63 - lane);
    float c = fmaxf(a, br);
    #pragma unroll
    for (int j = 32; j > 0; j >>= 1) {
        float o = __shfl_xor(c, j);
        c = ((lane & j) == 0) ? fmaxf(c, o) : fminf(c, o);
    }
    return c;
}

__global__ __launch_bounds__(512) void k_corrtopk(
    const u16* __restrict__ A,    // fdd  [B][1024][512] bf16
    const u16* __restrict__ Bm,   // fddT [B][1024][512] bf16
    float* __restrict__ topv)
{
    __shared__ u16 lds[67584];    // 2 x (B 32768 + A 1024) u16 = 132 KB; reused
    const int b = blockIdx.y;
    const int m0 = blockIdx.x * 32;
    const u16* pA = A + (size_t)b * 524288;
    const u16* pB = Bm + (size_t)b * 524288;
    const int tid = threadIdx.x, wave = tid >> 6, lane = tid & 63;
    const int g = lane >> 4;

    f32x4 acc[2][8];
    #pragma unroll
    for (int i = 0; i < 2; ++i)
        #pragma unroll
        for (int j = 0; j < 8; ++j) { f32x4 z = {0.f,0.f,0.f,0.f}; acc[i][j] = z; }

    auto STAGE = [&](int kt, int half) {
        const int k0 = kt << 5;
        u16* lb = lds + half * 33792;
        #pragma unroll
        for (int q = 0; q < 8; ++q) {               // B: 8 instr/wave
            int li = wave * 8 + q;                  // 0..63 chunks of 8 rp
            int rp = li * 8 + (lane >> 3);          // 0..511
            int gg = (lane & 7) ^ (rp & 7);
            int r  = rp * 2 + (gg >> 2);
            int kc = k0 + (gg & 3) * 8;
            gld16(pB + (size_t)r * 512 + kc, lb + li * 512 + lane * 8);
        }
        if (lane < 16) {                            // A: 1 instr/wave (16 lanes)
            int rp = wave * 2 + (lane >> 3);        // 0..15
            int gg = (lane & 7) ^ (rp & 7);
            int r  = rp * 2 + (gg >> 2);            // 0..31
            int kc = k0 + (gg & 3) * 8;
            gld16(pA + (size_t)(m0 + r) * 512 + kc,
                  lb + 32768 + wave * 128 + lane * 8);
        }
    };
    auto COMPUTE = [&](int half) {
        const u16* Bs = lds + half * 33792;
        const u16* As = Bs + 32768;
        short8v av[2];
        #pragma unroll
        for (int i = 0; i < 2; ++i) {
            int r = i * 16 + (lane & 15);
            int rp = r >> 1, gg = ((r & 1) << 2) + g;
            av[i] = *(const short8v*)(As + rp * 64 + ((gg ^ (rp & 7)) << 3));
        }
        #pragma unroll
        for (int j = 0; j < 8; ++j) {
            int n = wave * 128 + j * 16 + (lane & 15);
            int rp = n >> 1, gg = ((n & 1) << 2) + g;
            short8v bv = *(const short8v*)(Bs + rp * 64 + ((gg ^ (rp & 7)) << 3));
            #pragma unroll
            for (int i = 0; i < 2; ++i)
                acc[i][j] = __builtin_amdgcn_mfma_f32_16x16x32_bf16(av[i], bv, acc[i][j], 0, 0, 0);
        }
    };

    STAGE(0, 0);
    int cur = 0;
    for (int kt = 0; kt < 16; ++kt) {
        if (kt + 1 < 16) {
            STAGE(kt + 1, cur ^ 1);
            asm volatile("s_waitcnt vmcnt(9)" ::: "memory");
        } else {
            asm volatile("s_waitcnt vmcnt(0)" ::: "memory");
        }
        __builtin_amdgcn_s_barrier();
        __builtin_amdgcn_sched_barrier(0);
        COMPUTE(cur);
        __builtin_amdgcn_sched_barrier(0);
        __builtin_amdgcn_s_barrier();
        cur ^= 1;
    }

    // dump corr rows [32][1024] f32 into LDS (reuse staging space)
    __syncthreads();
    float* rows = (float*)lds;
    #pragma unroll
    for (int i = 0; i < 2; ++i) {
        int rb = i * 16 + ((lane >> 4) << 2);
        #pragma unroll
        for (int j = 0; j < 8; ++j) {
            int col = wave * 128 + j * 16 + (lane & 15);
            #pragma unroll
            for (int rg = 0; rg < 4; ++rg)
                rows[(rb + rg) * 1024 + col] = acc[i][j][rg];
        }
    }
    __syncthreads();

    // wave-per-row top-48 (4 rows/wave), strided 64-groups
    float* wb = rows + 32768 + wave * 128;
    for (int ro = 0; ro < 4; ++ro) {
        int lrow = wave * 4 + ro;
        const float* rd = rows + (size_t)lrow * 1024;
        float e[16];
        #pragma unroll
        for (int q = 0; q < 16; ++q) e[q] = rd[q * 64 + lane];

        float gm = e[0];
        #pragma unroll
        for (int q = 1; q < 16; ++q) gm = fmaxf(gm, e[q]);
        float sorted = sort64_desc(gm, lane);
        float tau = __shfl(sorted, T_ - 1);

        int c = 0;
        #pragma unroll
        for (int q = 0; q < 16; ++q) c += (e[q] >= tau);
        int sc2 = c;
        #pragma unroll
        for (int o = 1; o < 64; o <<= 1) {
            int t2 = __shfl_up(sc2, o);
            if (lane >= o) sc2 += t2;
        }
        int off = sc2 - c;
        int cnt = __shfl(sc2, 63);                  // >= 48 guaranteed

        float* orow = topv + ((size_t)b * HW_ + m0 + lrow) * T_;
        if (cnt <= 128) {
            #pragma unroll
            for (int q = 0; q < 16; ++q)
                if (e[q] >= tau) wb[off++] = e[q];
            if (cnt <= 64) {
                float a = (lane < cnt) ? wb[lane] : -INFINITY;
                a = sort64_desc(a, lane);
                if (lane < T_) orow[lane] = fmaxf(a, 0.f);
            } else {
                float a  = sort64_desc(wb[lane], lane);
                float b2 = sort64_desc((lane < cnt - 64) ? wb[64 + lane] : -INFINITY, lane);
                float m2 = bmerge64_desc(a, b2, lane);
                if (lane < T_) orow[lane] = fmaxf(m2, 0.f);
            }
        } else {
            // exact register-only tournament (rare: heavy ties)
            float m = sort64_desc(e[0], lane);
            #pragma unroll
            for (int q = 1; q < 16; ++q)
                m = bmerge64_desc(m, sort64_desc(e[q], lane), lane);
            if (lane < T_) orow[lane] = fmaxf(m, 0.f);
        }
    }
}

// ---------------------------------------------------------------------------
// 8) column norm over (B,H) and final transpose
// ---------------------------------------------------------------------------
__global__ void k_colss(const float* __restrict__ topv, float* __restrict__ colss) {
    int o = blockIdx.x;
    int w = o / T_, t = o % T_;
    int lane = threadIdx.x;
    float s = 0.f;
    for (int i = lane; i < 512; i += 64) {
        int b = i >> 5, h = i & 31;
        float v = topv[(size_t)((b << 10) + (h << 5) + w) * T_ + t];
        s += v * v;
    }
    for (int off = 32; off > 0; off >>= 1) s += __shfl_down(s, off);
    if (lane == 0) colss[o] = s;
}

__global__ void k_final(const float* __restrict__ topv, const float* __restrict__ colss,
                        float* __restrict__ out) {
    int idx = blockIdx.x * 256 + threadIdx.x;
    if (idx >= B_ * T_ * HW_) return;
    int w = idx & 31;
    int h = (idx >> 5) & 31;
    int t = (idx >> 10) % T_;
    int b = idx / (T_ * HW_);
    float v = topv[(size_t)((b << 10) + (h << 5) + w) * T_ + t];
    out[idx] = v * rsqrtf(colss[w * T_ + t]);
}

// ---------------------------------------------------------------------------
extern "C" void kernel_launch(void* const* d_in, const int* in_sizes, int n_in,
                              void* d_out, int out_size, void* d_ws, size_t ws_size,
                              hipStream_t stream) {
    const float* x     = (const float*)d_in[0];
    const float* fW    = (const float*)d_in[1];
    const float* fb    = (const float*)d_in[2];
    const float* gW    = (const float*)d_in[3];
    const float* gb    = (const float*)d_in[4];
    const float* hW    = (const float*)d_in[5];
    const float* hb    = (const float*)d_in[6];
    const float* scale = (const float*)d_in[7];
    float* out = (float*)d_out;

    char* wsb = (char*)d_ws;
    float* part = (float*)(wsb + 0);                 // 262144 B [64][1024]
    float* ninv = (float*)(wsb + 262144);            // 4096 B
    u16*   hWh  = (u16*)(wsb + 266240);              // 524288 B
    u16*   fgWh = (u16*)(wsb + 790528);              // 131072 B
    float* fgb  = (float*)(wsb + 921600);            // 512 B
    u16*   xnH  = (u16*)(wsb + 922112);              // 16 MB (xn -> fdd bf16)
    u16*   fgH  = (u16*)(wsb + 17699328);            // 4 MB (f|g; later topv)
    u16*   fgL  = (u16*)(wsb + 21893632);            // 4 MB (later colss)
    u16*   hvTH = (u16*)(wsb + 26087936);            // 16 MB (hv -> fddT)
    float* S    = (float*)(wsb + 42865152);          // 32 MB (S/P u16)
    float* topv = (float*)fgH;
    float* colss= (float*)fgL;
    u16*   Sp   = (u16*)S;

    const long sXn = 524288;    // [1024][512] elements per batch
    const long sFG = 131072;    // [1024][128]
    const long sS  = 1048576;   // [1024][1024]

    // 1) per-pixel Frobenius norm
    k_colsq<<<256, 256, 0, stream>>>(x, part);
    k_rsqrt<<<4, 256, 0, stream>>>(part, ninv);

    // 2) normalized channel-last bf16
    k_transpose<<<dim3(32, 16, 16), dim3(32, 8), 0, stream>>>(x, ninv, xnH);

    // 3) weight planes
    k_packW<<<1024, 256, 0, stream>>>(hW, hWh);
    k_packFG<<<256, 256, 0, stream>>>(fW, gW, fb, gb, fgWh, fgb);

    // 4) fg = bf16(xn @ [fW|gW]^T + bias[col])  [B,1024,128]
    k_gemm1<0, 6><<<dim3(1, 8, 16), 256, 0, stream>>>(
        xnH, fgWh, fgb, nullptr, fgH, nullptr,
        128, 512, 512, 512, sXn, 0, sFG);

    // 5) hv = bf16(hW @ xn^T + hb[row])  [B,512,1024]  (128x128, 512 blocks)
    k_gemm1<0, 5><<<dim3(8, 4, 16), 256, 0, stream>>>(
        hWh, xnH, hb, nullptr, hvTH, nullptr,
        1024, 512, 512, 512, 0, sXn, sXn);

    // 6) S = bf16(f @ perm(g)^T)  (K=64, W-major keys)
    k_gemm2<1, 4><<<dim3(4, 8, 16), 512, 0, stream>>>(
        fgH, fgH + 64, nullptr, nullptr, Sp, nullptr,
        1024, 64, 128, 128, sFG, sFG, sS);

    // 7) softmax rows, u16 in place -> P bf16
    k_softmax<<<B_ * HW_, 256, 0, stream>>>(Sp);

    // 8) fdd = bf16(scale*(P @ hv^T) + xn), in place over xnH (128x128, 512 blk)
    k_gemm1<0, 2><<<dim3(4, 8, 16), 256, 0, stream>>>(
        Sp, hvTH, nullptr, nullptr, xnH, scale,
        512, 1024, 1024, 1024, sS, sXn, sXn);

    // 9) fddT: transpose flat [512][1024] view of fddH -> hvTH [1024][512]
    k_tposeU1<<<dim3(32, 16, 16), dim3(32, 8), 0, stream>>>(xnH, hvTH);

    // 10+11) fused corr + top-48 (corr stays on-chip)
    k_corrtopk<<<dim3(32, 16), 512, 0, stream>>>(xnH, hvTH, topv);

    // 12) norm over (B,H) + output transpose
    k_colss<<<W_ * T_, 64, 0, stream>>>(topv, colss);
    k_final<<<(B_ * T_ * HW_ + 255) / 256, 256, 0, stream>>>(topv, colss, out);
}

// Round 11
// 215.424 us; speedup vs baseline: 1.0347x; 1.0347x over previous
//
#include <hip/hip_runtime.h>
#include <cstdint>
#include <cstddef>

#define B_   16
#define C_   512
#define H_   32
#define W_   32
#define HW_  1024
#define TC_  64
#define T_   48

typedef unsigned short u16;
typedef __attribute__((ext_vector_type(8))) short short8v;
typedef __attribute__((ext_vector_type(4))) float f32x4;

// ---------------------------------------------------------------------------
// bf16 helpers
// ---------------------------------------------------------------------------
__device__ __forceinline__ u16 tobf(float x) {
    unsigned u = __float_as_uint(x);
    return (u16)((u + 0x7FFFu + ((u >> 16) & 1u)) >> 16);    // RTNE
}
__device__ __forceinline__ float frombf(u16 h) {
    return __uint_as_float(((unsigned)h) << 16);
}

__device__ __forceinline__ void gld16(const void* g, void* l) {
    __builtin_amdgcn_global_load_lds(
        (const __attribute__((address_space(1))) void*)g,
        (__attribute__((address_space(3))) void*)l, 16, 0, 0);
}

// ---------------------------------------------------------------------------
// 1) Frobenius-norm helpers
// ---------------------------------------------------------------------------
__global__ void k_colsq(const float* __restrict__ x, float* __restrict__ partial) {
    int bid = blockIdx.x;            // 256 blocks: 4 col-tiles x 64 row-tiles
    int col = (bid & 3) * 256 + threadIdx.x;
    int r0  = (bid >> 2) * 128;
    const float* p = x + (size_t)r0 * HW_ + col;
    float s = 0.f;
    for (int r = 0; r < 128; ++r) { float v = p[(size_t)r * HW_]; s += v * v; }
    partial[(size_t)(bid >> 2) * HW_ + col] = s;
}

__global__ void k_rsqrt(const float* __restrict__ partial, float* __restrict__ ninv) {
    int i = blockIdx.x * 256 + threadIdx.x;
    if (i < HW_) {
        float s = 0.f;
        for (int r = 0; r < 64; ++r) s += partial[(size_t)r * HW_ + i];
        ninv[i] = rsqrtf(s);
    }
}

// ---------------------------------------------------------------------------
// 2) transpose + normalize: x [B,C,HW] -> xnH bf16 [B,HW,C]
// ---------------------------------------------------------------------------
__global__ void k_transpose(const float* __restrict__ x, const float* __restrict__ ninv,
                            u16* __restrict__ obH) {
    __shared__ float tile[32][33];
    int b  = blockIdx.z;
    int m0 = blockIdx.x * 32, c0 = blockIdx.y * 32;
    int tx = threadIdx.x, ty = threadIdx.y;
    const float* xb = x + (size_t)b * C_ * HW_;
    #pragma unroll
    for (int j = 0; j < 32; j += 8)
        tile[ty + j][tx] = xb[(size_t)(c0 + ty + j) * HW_ + m0 + tx];
    __syncthreads();
    size_t base = (size_t)b * HW_ * C_;
    #pragma unroll
    for (int j = 0; j < 32; j += 8) {
        int m = m0 + ty + j;
        obH[base + (size_t)m * C_ + c0 + tx] = tobf(tile[tx][ty + j] * ninv[m]);
    }
}

// ---------------------------------------------------------------------------
// 3) weight prep (hi plane only)
// ---------------------------------------------------------------------------
__global__ void k_packW(const float* __restrict__ in, u16* __restrict__ oh) {
    size_t i = (size_t)blockIdx.x * 256 + threadIdx.x;
    oh[i] = tobf(in[i]);
}
__global__ void k_packFG(const float* __restrict__ fW, const float* __restrict__ gW,
                         const float* __restrict__ fb, const float* __restrict__ gb,
                         u16* __restrict__ oh, float* __restrict__ fgb) {
    int idx = blockIdx.x * 256 + threadIdx.x;   // 65536
    int row = idx >> 9, c = idx & 511;
    float v = (row < 64) ? fW[row * 512 + c] : gW[(row - 64) * 512 + c];
    oh[idx] = tobf(v);
    if (idx < 128) fgb[idx] = (idx < 64) ? fb[idx] : gb[idx - 64];
}

// ---------------------------------------------------------------------------
// 4a) 1-term bf16 MFMA GEMM, 128x128, 4 waves, TRIPLE-buffered counted-vmcnt
//     pipeline, prefetch distance 2 (covers ~2 K-step latencies; r9's
//     distance-1 left MfmaUtil at 14%). 48 KB LDS -> 3 blocks/CU.
//     EPI 0: Cf fp32 = acc
//     EPI 2: Ch = bf16(scale*acc + frombf(Ch))
//     EPI 4: Ch = bf16(acc)
//     EPI 5: Ch = bf16(acc + bias[row])
//     EPI 6: Ch = bf16(acc + bias[col])
// ---------------------------------------------------------------------------
template<int PERMB, int EPI>
__global__ __launch_bounds__(256) void k_gemm1(
    const u16* __restrict__ A, const u16* __restrict__ Bm,
    const float* __restrict__ bias,
    float* __restrict__ Cf, u16* __restrict__ Ch,
    const float* __restrict__ scaleP,
    int N, int K, int lda, int ldb, long sA, long sB, long sC)
{
    __shared__ u16 lds[3 * 8192];
    const int b = blockIdx.z;
    const u16* pA = A + (size_t)b * sA;
    const u16* pB = Bm + (size_t)b * sB;
    const int m0 = blockIdx.y * 128, n0 = blockIdx.x * 128;
    const int tid = threadIdx.x, wave = tid >> 6, lane = tid & 63;
    const int wm = wave >> 1, wn = wave & 1;
    const int g = lane >> 4;

    f32x4 acc[4][4];
    #pragma unroll
    for (int i = 0; i < 4; ++i)
        #pragma unroll
        for (int j = 0; j < 4; ++j) { f32x4 z = {0.f,0.f,0.f,0.f}; acc[i][j] = z; }

    auto STAGE = [&](int kt, int buf) {
        const int k0 = kt << 5;
        u16* lb = lds + buf * 8192;
        #pragma unroll
        for (int q = 0; q < 4; ++q) {
            int ci = wave * 4 + q;
            bool isA = ci < 8;
            int li = ci & 7;
            const u16* gp = isA ? pA : pB;
            int ld = isA ? lda : ldb;
            int rb = isA ? m0 : n0;
            int rp = li * 8 + (lane >> 3);
            int gg = (lane & 7) ^ (rp & 7);
            int r  = rp * 2 + (gg >> 2);
            int kc = k0 + (gg & 3) * 8;
            int rowg = rb + r;
            if (PERMB && !isA) rowg = ((rowg & 31) << 5) | (rowg >> 5);
            gld16(gp + (size_t)rowg * ld + kc,
                  lb + (isA ? 0 : 4096) + li * 512 + lane * 8);
        }
    };
    auto COMPUTE = [&](int buf) {
        const u16* As = lds + buf * 8192;
        const u16* Bs = As + 4096;
        short8v av[4];
        #pragma unroll
        for (int i = 0; i < 4; ++i) {
            int r = wm * 64 + i * 16 + (lane & 15);
            int rp = r >> 1, gg = ((r & 1) << 2) + g;
            av[i] = *(const short8v*)(As + rp * 64 + ((gg ^ (rp & 7)) << 3));
        }
        #pragma unroll
        for (int j = 0; j < 4; ++j) {
            int r = wn * 64 + j * 16 + (lane & 15);
            int rp = r >> 1, gg = ((r & 1) << 2) + g;
            short8v bv = *(const short8v*)(Bs + rp * 64 + ((gg ^ (rp & 7)) << 3));
            #pragma unroll
            for (int i = 0; i < 4; ++i)
                acc[i][j] = __builtin_amdgcn_mfma_f32_16x16x32_bf16(av[i], bv, acc[i][j], 0, 0, 0);
        }
    };

    const int nkt = K >> 5;       // >= 2 for all uses
    STAGE(0, 0);
    STAGE(1, 1);
    int cur = 0;
    for (int kt = 0; kt < nkt; ++kt) {
        int nxt2 = cur + 2; if (nxt2 >= 3) nxt2 -= 3;
        if (kt + 2 < nkt) {
            STAGE(kt + 2, nxt2);
            asm volatile("s_waitcnt vmcnt(8)" ::: "memory");
        } else if (kt + 1 < nkt) {
            asm volatile("s_waitcnt vmcnt(4)" ::: "memory");
        } else {
            asm volatile("s_waitcnt vmcnt(0)" ::: "memory");
        }
        __builtin_amdgcn_s_barrier();
        __builtin_amdgcn_sched_barrier(0);
        COMPUTE(cur);
        __builtin_amdgcn_sched_barrier(0);
        __builtin_amdgcn_s_barrier();
        ++cur; if (cur >= 3) cur -= 3;
    }

    const float sc = (EPI == 2) ? scaleP[0] : 0.f;
    const int colbase = n0 + wn * 64 + (lane & 15);
    const int rowbase = m0 + wm * 64 + ((lane >> 4) << 2);
    #pragma unroll
    for (int i = 0; i < 4; ++i)
        #pragma unroll
        for (int j = 0; j < 4; ++j) {
            int col = colbase + j * 16;
            #pragma unroll
            for (int rg = 0; rg < 4; ++rg) {
                int row = rowbase + i * 16 + rg;
                size_t idx = (size_t)b * sC + (size_t)row * N + col;
                float a = acc[i][j][rg];
                if (EPI == 0)      Cf[idx] = a;
                else if (EPI == 2) Ch[idx] = tobf(sc * a + frombf(Ch[idx]));
                else if (EPI == 4) Ch[idx] = tobf(a);
                else if (EPI == 5) Ch[idx] = tobf(a + bias[row]);
                else               Ch[idx] = tobf(a + bias[col]);
            }
        }
}

// ---------------------------------------------------------------------------
// 4b) 1-term bf16 MFMA GEMM, 128x256, 8 waves, triple-buffered distance-2
//     (72 KB LDS -> 2 blocks/CU). Used for S (K=64).
// ---------------------------------------------------------------------------
template<int PERMB, int EPI>
__global__ __launch_bounds__(512) void k_gemm2(
    const u16* __restrict__ A, const u16* __restrict__ Bm,
    const float* __restrict__ bias,
    float* __restrict__ Cf, u16* __restrict__ Ch,
    const float* __restrict__ scaleP,
    int N, int K, int lda, int ldb, long sA, long sB, long sC)
{
    __shared__ u16 lds[3 * 12288];
    const int b = blockIdx.z;
    const u16* pA = A + (size_t)b * sA;
    const u16* pB = Bm + (size_t)b * sB;
    const int m0 = blockIdx.y * 128, n0 = blockIdx.x * 256;
    const int tid = threadIdx.x, wave = tid >> 6, lane = tid & 63;
    const int wm = wave >> 2, wn = wave & 3;
    const int g = lane >> 4;

    f32x4 acc[4][4];
    #pragma unroll
    for (int i = 0; i < 4; ++i)
        #pragma unroll
        for (int j = 0; j < 4; ++j) { f32x4 z = {0.f,0.f,0.f,0.f}; acc[i][j] = z; }

    auto STAGE = [&](int kt, int buf) {
        const int k0 = kt << 5;
        u16* lb = lds + buf * 12288;
        #pragma unroll
        for (int q = 0; q < 3; ++q) {
            int ci = wave * 3 + q;
            bool isA = ci < 8;
            int li = isA ? ci : ci - 8;
            const u16* gp = isA ? pA : pB;
            int ld = isA ? lda : ldb;
            int rb = isA ? m0 : n0;
            int rp = li * 8 + (lane >> 3);
            int gg = (lane & 7) ^ (rp & 7);
            int r  = rp * 2 + (gg >> 2);
            int kc = k0 + (gg & 3) * 8;
            int rowg = rb + r;
            if (PERMB && !isA) rowg = ((rowg & 31) << 5) | (rowg >> 5);
            gld16(gp + (size_t)rowg * ld + kc,
                  lb + (isA ? 0 : 4096) + li * 512 + lane * 8);
        }
    };
    auto COMPUTE = [&](int buf) {
        const u16* As = lds + buf * 12288;
        const u16* Bs = As + 4096;
        short8v av[4];
        #pragma unroll
        for (int i = 0; i < 4; ++i) {
            int r = wm * 64 + i * 16 + (lane & 15);
            int rp = r >> 1, gg = ((r & 1) << 2) + g;
            av[i] = *(const short8v*)(As + rp * 64 + ((gg ^ (rp & 7)) << 3));
        }
        #pragma unroll
        for (int j = 0; j < 4; ++j) {
            int r = wn * 64 + j * 16 + (lane & 15);
            int rp = r >> 1, gg = ((r & 1) << 2) + g;
            short8v bv = *(const short8v*)(Bs + rp * 64 + ((gg ^ (rp & 7)) << 3));
            #pragma unroll
            for (int i = 0; i < 4; ++i)
                acc[i][j] = __builtin_amdgcn_mfma_f32_16x16x32_bf16(av[i], bv, acc[i][j], 0, 0, 0);
        }
    };

    const int nkt = K >> 5;
    STAGE(0, 0);
    STAGE(1, 1);
    int cur = 0;
    for (int kt = 0; kt < nkt; ++kt) {
        int nxt2 = cur + 2; if (nxt2 >= 3) nxt2 -= 3;
        if (kt + 2 < nkt) {
            STAGE(kt + 2, nxt2);
            asm volatile("s_waitcnt vmcnt(6)" ::: "memory");
        } else if (kt + 1 < nkt) {
            asm volatile("s_waitcnt vmcnt(3)" ::: "memory");
        } else {
            asm volatile("s_waitcnt vmcnt(0)" ::: "memory");
        }
        __builtin_amdgcn_s_barrier();
        __builtin_amdgcn_sched_barrier(0);
        COMPUTE(cur);
        __builtin_amdgcn_sched_barrier(0);
        __builtin_amdgcn_s_barrier();
        ++cur; if (cur >= 3) cur -= 3;
    }

    const float sc = (EPI == 2) ? scaleP[0] : 0.f;
    const int colbase = n0 + wn * 64 + (lane & 15);
    const int rowbase = m0 + wm * 64 + ((lane >> 4) << 2);
    #pragma unroll
    for (int i = 0; i < 4; ++i)
        #pragma unroll
        for (int j = 0; j < 4; ++j) {
            int col = colbase + j * 16;
            #pragma unroll
            for (int rg = 0; rg < 4; ++rg) {
                int row = rowbase + i * 16 + rg;
                size_t idx = (size_t)b * sC + (size_t)row * N + col;
                float a = acc[i][j][rg];
                if (EPI == 0)      Cf[idx] = a;
                else if (EPI == 2) Ch[idx] = tobf(sc * a + frombf(Ch[idx]));
                else if (EPI == 4) Ch[idx] = tobf(a);
                else if (EPI == 5) Ch[idx] = tobf(a + bias[row]);
                else               Ch[idx] = tobf(a + bias[col]);
            }
        }
}

// ---------------------------------------------------------------------------
// 5) row softmax on bf16 S, u16 in-place
// ---------------------------------------------------------------------------
__global__ __launch_bounds__(256) void k_softmax(u16* __restrict__ S) {
    size_t row = blockIdx.x;
    u16* r = S + row * (size_t)HW_;
    int t = threadIdx.x;
    ushort4 raw = ((const ushort4*)r)[t];
    float v0 = frombf(raw.x), v1 = frombf(raw.y), v2 = frombf(raw.z), v3 = frombf(raw.w);

    __shared__ float redm[4], reds[4];
    int wid = t >> 6, lane = t & 63;

    float m = fmaxf(fmaxf(v0, v1), fmaxf(v2, v3));
    for (int o = 32; o > 0; o >>= 1) m = fmaxf(m, __shfl_down(m, o));
    if (lane == 0) redm[wid] = m;
    __syncthreads();
    if (t == 0) redm[0] = fmaxf(fmaxf(redm[0], redm[1]), fmaxf(redm[2], redm[3]));
    __syncthreads();
    m = redm[0];

    v0 = expf(v0 - m); v1 = expf(v1 - m); v2 = expf(v2 - m); v3 = expf(v3 - m);
    float s = v0 + v1 + v2 + v3;
    for (int o = 32; o > 0; o >>= 1) s += __shfl_down(s, o);
    if (lane == 0) reds[wid] = s;
    __syncthreads();
    if (t == 0) reds[0] = reds[0] + reds[1] + reds[2] + reds[3];
    __syncthreads();
    float inv = 1.f / reds[0];
    ushort4 o4;
    o4.x = tobf(v0 * inv); o4.y = tobf(v1 * inv);
    o4.z = tobf(v2 * inv); o4.w = tobf(v3 * inv);
    ((ushort4*)r)[t] = o4;
}

// ---------------------------------------------------------------------------
// 6) single-plane u16 transpose of fdd flat view [512][1024] -> fddT [1024][512]
// ---------------------------------------------------------------------------
__global__ void k_tposeU1(const u16* __restrict__ src, u16* __restrict__ dst) {
    __shared__ u16 tile[32][33];
    int b = blockIdx.z;
    const u16* sb = src + (size_t)b * (C_ * HW_);
    u16* db = dst + (size_t)b * (C_ * HW_);
    int c0 = blockIdx.x * 32, r0 = blockIdx.y * 32;
    int tx = threadIdx.x, ty = threadIdx.y;
    #pragma unroll
    for (int j = 0; j < 32; j += 8)
        tile[ty + j][tx] = sb[(size_t)(r0 + ty + j) * HW_ + c0 + tx];
    __syncthreads();
    #pragma unroll
    for (int j = 0; j < 32; j += 8)
        db[(size_t)(c0 + ty + j) * C_ + r0 + tx] = tile[tx][ty + j];
}

// ---------------------------------------------------------------------------
// 7) top-48, one WAVE per row (verified r8/r9)
// ---------------------------------------------------------------------------
__device__ __forceinline__ float sort64_desc(float v, int lane) {
    #pragma unroll
    for (int k = 2; k <= 64; k <<= 1) {
        #pragma unroll
        for (int j = k >> 1; j > 0; j >>= 1) {
            float o = __shfl_xor(v, j);
            bool takeMax = (((lane & k) == 0) == ((lane & j) == 0));
            v = takeMax ? fmaxf(v, o) : fminf(v, o);
        }
    }
    return v;
}
__device__ __forceinline__ float bmerge64_desc(float a, float b, int lane) {
    float br = __shfl(b, 63 - lane);
    float c = fmaxf(a, br);
    #pragma unroll
    for (int j = 32; j > 0; j >>= 1) {
        float o = __shfl_xor(c, j);
        c = ((lane & j) == 0) ? fmaxf(c, o) : fminf(c, o);
    }
    return c;
}

__global__ __launch_bounds__(256) void k_topk(const float* __restrict__ corr,
                                              float* __restrict__ topv) {
    __shared__ float buf[4][1024];
    int wave = threadIdx.x >> 6, lane = threadIdx.x & 63;
    int row = blockIdx.x * 4 + wave;
    const float4* rp = (const float4*)(corr + (size_t)row * HW_);

    float4 e[4];
    #pragma unroll
    for (int q = 0; q < 4; ++q) e[q] = rp[lane * 4 + q];

    float gm = -INFINITY;
    #pragma unroll
    for (int q = 0; q < 4; ++q)
        gm = fmaxf(gm, fmaxf(fmaxf(e[q].x, e[q].y), fmaxf(e[q].z, e[q].w)));
    float sorted = sort64_desc(gm, lane);
    float tau = __shfl(sorted, T_ - 1);

    int c = 0;
    #pragma unroll
    for (int q = 0; q < 4; ++q)
        c += (e[q].x >= tau) + (e[q].y >= tau) + (e[q].z >= tau) + (e[q].w >= tau);
    int sc = c;
    #pragma unroll
    for (int o = 1; o < 64; o <<= 1) {
        int t2 = __shfl_up(sc, o);
        if (lane >= o) sc += t2;
    }
    int off = sc - c;
    int cnt = __shfl(sc, 63);

    float* wb = buf[wave];
    #pragma unroll
    for (int q = 0; q < 4; ++q) {
        if (e[q].x >= tau) wb[off++] = e[q].x;
        if (e[q].y >= tau) wb[off++] = e[q].y;
        if (e[q].z >= tau) wb[off++] = e[q].z;
        if (e[q].w >= tau) wb[off++] = e[q].w;
    }

    float* orow = topv + (size_t)row * T_;
    if (cnt <= 64) {
        float a = (lane < cnt) ? wb[lane] : -INFINITY;
        a = sort64_desc(a, lane);
        if (lane < T_) orow[lane] = fmaxf(a, 0.f);
    } else if (cnt <= 128) {
        float a  = sort64_desc(wb[lane], lane);
        float b2 = sort64_desc((lane < cnt - 64) ? wb[64 + lane] : -INFINITY, lane);
        float m2 = bmerge64_desc(a, b2, lane);
        if (lane < T_) orow[lane] = fmaxf(m2, 0.f);
    } else {
        int P = 256; while (P < cnt) P <<= 1;
        for (int i = cnt + lane; i < P; i += 64) wb[i] = -INFINITY;
        for (int k = 2; k <= P; k <<= 1)
            for (int j = k >> 1; j > 0; j >>= 1)
                for (int t2 = lane; t2 < P; t2 += 64) {
                    int ixj = t2 ^ j;
                    if (ixj > t2) {
                        float a = wb[t2], b3 = wb[ixj];
                        bool desc = ((t2 & k) == 0);
                        if (desc ? (a < b3) : (a > b3)) { wb[t2] = b3; wb[ixj] = a; }
                    }
                }
        if (lane < T_) orow[lane] = fmaxf(wb[lane], 0.f);
    }
}

// ---------------------------------------------------------------------------
// 8) column norm over (B,H) and final transpose
// ---------------------------------------------------------------------------
__global__ void k_colss(const float* __restrict__ topv, float* __restrict__ colss) {
    int o = blockIdx.x;
    int w = o / T_, t = o % T_;
    int lane = threadIdx.x;
    float s = 0.f;
    for (int i = lane; i < 512; i += 64) {
        int b = i >> 5, h = i & 31;
        float v = topv[(size_t)((b << 10) + (h << 5) + w) * T_ + t];
        s += v * v;
    }
    for (int off = 32; off > 0; off >>= 1) s += __shfl_down(s, off);
    if (lane == 0) colss[o] = s;
}

__global__ void k_final(const float* __restrict__ topv, const float* __restrict__ colss,
                        float* __restrict__ out) {
    int idx = blockIdx.x * 256 + threadIdx.x;
    if (idx >= B_ * T_ * HW_) return;
    int w = idx & 31;
    int h = (idx >> 5) & 31;
    int t = (idx >> 10) % T_;
    int b = idx / (T_ * HW_);
    float v = topv[(size_t)((b << 10) + (h << 5) + w) * T_ + t];
    out[idx] = v * rsqrtf(colss[w * T_ + t]);
}

// ---------------------------------------------------------------------------
extern "C" void kernel_launch(void* const* d_in, const int* in_sizes, int n_in,
                              void* d_out, int out_size, void* d_ws, size_t ws_size,
                              hipStream_t stream) {
    const float* x     = (const float*)d_in[0];
    const float* fW    = (const float*)d_in[1];
    const float* fb    = (const float*)d_in[2];
    const float* gW    = (const float*)d_in[3];
    const float* gb    = (const float*)d_in[4];
    const float* hW    = (const float*)d_in[5];
    const float* hb    = (const float*)d_in[6];
    const float* scale = (const float*)d_in[7];
    float* out = (float*)d_out;

    char* wsb = (char*)d_ws;
    float* part = (float*)(wsb + 0);                 // 262144 B [64][1024]
    float* ninv = (float*)(wsb + 262144);            // 4096 B
    u16*   hWh  = (u16*)(wsb + 266240);              // 524288 B
    u16*   fgWh = (u16*)(wsb + 790528);              // 131072 B
    float* fgb  = (float*)(wsb + 921600);            // 512 B
    u16*   xnH  = (u16*)(wsb + 922112);              // 16 MB (xn -> fdd bf16)
    u16*   fgH  = (u16*)(wsb + 17699328);            // 4 MB (f|g; later topv)
    u16*   fgL  = (u16*)(wsb + 21893632);            // 4 MB (later colss)
    u16*   hvTH = (u16*)(wsb + 26087936);            // 16 MB (hv -> fddT)
    float* S    = (float*)(wsb + 42865152);          // 64 MB (S/P u16 -> corr fp32)
    float* topv = (float*)fgH;
    float* colss= (float*)fgL;
    u16*   Sp   = (u16*)S;

    const long sXn = 524288;    // [1024][512] elements per batch
    const long sFG = 131072;    // [1024][128]
    const long sS  = 1048576;   // [1024][1024]

    // 1) per-pixel Frobenius norm
    k_colsq<<<256, 256, 0, stream>>>(x, part);
    k_rsqrt<<<4, 256, 0, stream>>>(part, ninv);

    // 2) normalized channel-last bf16
    k_transpose<<<dim3(32, 16, 16), dim3(32, 8), 0, stream>>>(x, ninv, xnH);

    // 3) weight planes
    k_packW<<<1024, 256, 0, stream>>>(hW, hWh);
    k_packFG<<<256, 256, 0, stream>>>(fW, gW, fb, gb, fgWh, fgb);

    // 4) fg = bf16(xn @ [fW|gW]^T + bias[col])  [B,1024,128]
    k_gemm1<0, 6><<<dim3(1, 8, 16), 256, 0, stream>>>(
        xnH, fgWh, fgb, nullptr, fgH, nullptr,
        128, 512, 512, 512, sXn, 0, sFG);

    // 5) hv = bf16(hW @ xn^T + hb[row])  [B,512,1024]
    k_gemm1<0, 5><<<dim3(8, 4, 16), 256, 0, stream>>>(
        hWh, xnH, hb, nullptr, hvTH, nullptr,
        1024, 512, 512, 512, 0, sXn, sXn);

    // 6) S = bf16(f @ perm(g)^T)  (K=64, W-major keys)
    k_gemm2<1, 4><<<dim3(4, 8, 16), 512, 0, stream>>>(
        fgH, fgH + 64, nullptr, nullptr, Sp, nullptr,
        1024, 64, 128, 128, sFG, sFG, sS);

    // 7) softmax rows, u16 in place -> P bf16
    k_softmax<<<B_ * HW_, 256, 0, stream>>>(Sp);

    // 8) fdd = bf16(scale*(P @ hv^T) + xn), in place over xnH
    k_gemm1<0, 2><<<dim3(4, 8, 16), 256, 0, stream>>>(
        Sp, hvTH, nullptr, nullptr, xnH, scale,
        512, 1024, 1024, 1024, sS, sXn, sXn);

    // 9) fddT: transpose flat [512][1024] view of fddH -> hvTH [1024][512]
    k_tposeU1<<<dim3(32, 16, 16), dim3(32, 8), 0, stream>>>(xnH, hvTH);

    // 10) corr = fdd @ fddT^T -> fp32 into S (128x128, 1024 blocks)
    k_gemm1<0, 0><<<dim3(8, 8, 16), 256, 0, stream>>>(
        xnH, hvTH, nullptr, S, nullptr, nullptr,
        1024, 512, 512, 512, sXn, sXn, sS);

    // 11) top-48 desc + relu (wave-per-row)
    k_topk<<<B_ * HW_ / 4, 256, 0, stream>>>(S, topv);

    // 12) norm over (B,H) + output transpose
    k_colss<<<W_ * T_, 64, 0, stream>>>(topv, colss);
    k_final<<<(B_ * T_ * HW_ + 255) / 256, 256, 0, stream>>>(topv, colss, out);
}

// Round 12
// 195.385 us; speedup vs baseline: 1.1408x; 1.1026x over previous
//
#include <hip/hip_runtime.h>
#include <cstdint>
#include <cstddef>

#define B_   16
#define C_   512
#define H_   32
#define W_   32
#define HW_  1024
#define TC_  64
#define T_   48

typedef unsigned short u16;
typedef __attribute__((ext_vector_type(8))) short short8v;
typedef __attribute__((ext_vector_type(4))) float f32x4;

// ---------------------------------------------------------------------------
// bf16 helpers
// ---------------------------------------------------------------------------
__device__ __forceinline__ u16 tobf(float x) {
    unsigned u = __float_as_uint(x);
    return (u16)((u + 0x7FFFu + ((u >> 16) & 1u)) >> 16);    // RTNE
}
__device__ __forceinline__ float frombf(u16 h) {
    return __uint_as_float(((unsigned)h) << 16);
}

__device__ __forceinline__ void gld16(const void* g, void* l) {
    __builtin_amdgcn_global_load_lds(
        (const __attribute__((address_space(1))) void*)g,
        (__attribute__((address_space(3))) void*)l, 16, 0, 0);
}

// ---------------------------------------------------------------------------
// 1) Frobenius-norm helpers
// ---------------------------------------------------------------------------
__global__ void k_colsq(const float* __restrict__ x, float* __restrict__ partial) {
    int bid = blockIdx.x;
    int col = (bid & 3) * 256 + threadIdx.x;
    int r0  = (bid >> 2) * 128;
    const float* p = x + (size_t)r0 * HW_ + col;
    float s = 0.f;
    for (int r = 0; r < 128; ++r) { float v = p[(size_t)r * HW_]; s += v * v; }
    partial[(size_t)(bid >> 2) * HW_ + col] = s;
}

__global__ void k_rsqrt(const float* __restrict__ partial, float* __restrict__ ninv) {
    int i = blockIdx.x * 256 + threadIdx.x;
    if (i < HW_) {
        float s = 0.f;
        for (int r = 0; r < 64; ++r) s += partial[(size_t)r * HW_ + i];
        ninv[i] = rsqrtf(s);
    }
}

// ---------------------------------------------------------------------------
// 2) transpose + normalize: x [B,C,HW] -> xnH bf16 [B,HW,C]
// ---------------------------------------------------------------------------
__global__ void k_transpose(const float* __restrict__ x, const float* __restrict__ ninv,
                            u16* __restrict__ obH) {
    __shared__ float tile[32][33];
    int b  = blockIdx.z;
    int m0 = blockIdx.x * 32, c0 = blockIdx.y * 32;
    int tx = threadIdx.x, ty = threadIdx.y;
    const float* xb = x + (size_t)b * C_ * HW_;
    #pragma unroll
    for (int j = 0; j < 32; j += 8)
        tile[ty + j][tx] = xb[(size_t)(c0 + ty + j) * HW_ + m0 + tx];
    __syncthreads();
    size_t base = (size_t)b * HW_ * C_;
    #pragma unroll
    for (int j = 0; j < 32; j += 8) {
        int m = m0 + ty + j;
        obH[base + (size_t)m * C_ + c0 + tx] = tobf(tile[tx][ty + j] * ninv[m]);
    }
}

// ---------------------------------------------------------------------------
// 3) weight prep (hi plane only)
// ---------------------------------------------------------------------------
__global__ void k_packW(const float* __restrict__ in, u16* __restrict__ oh) {
    size_t i = (size_t)blockIdx.x * 256 + threadIdx.x;
    oh[i] = tobf(in[i]);
}
__global__ void k_packFG(const float* __restrict__ fW, const float* __restrict__ gW,
                         const float* __restrict__ fb, const float* __restrict__ gb,
                         u16* __restrict__ oh, float* __restrict__ fgb) {
    int idx = blockIdx.x * 256 + threadIdx.x;   // 65536
    int row = idx >> 9, c = idx & 511;
    float v = (row < 64) ? fW[row * 512 + c] : gW[(row - 64) * 512 + c];
    oh[idx] = tobf(v);
    if (idx < 128) fgb[idx] = (idx < 64) ? fb[idx] : gb[idx - 64];
}

// ---------------------------------------------------------------------------
// 4) 1-term bf16 MFMA GEMM, 128x128, 4 waves, triple-buffer counted-vmcnt
//    (r11 structure) + T1 XCD-aware block swizzle (all grids %8 == 0).
//    EPI 0: Cf fp32 = acc
//    EPI 2: Ch = bf16(scale*acc + frombf(Ch))
//    EPI 5: Ch = bf16(acc + bias[row])
//    EPI 6: Ch = bf16(acc + bias[col])
// ---------------------------------------------------------------------------
template<int EPI>
__global__ __launch_bounds__(256) void k_gemm1(
    const u16* __restrict__ A, const u16* __restrict__ Bm,
    const float* __restrict__ bias,
    float* __restrict__ Cf, u16* __restrict__ Ch,
    const float* __restrict__ scaleP,
    int N, int K, int lda, int ldb, long sA, long sB, long sC)
{
    __shared__ u16 lds[3 * 8192];
    // T1 XCD swizzle: contiguous work chunk per XCD
    const int gx = gridDim.x, gy = gridDim.y, gz = gridDim.z;
    int bidl = blockIdx.x + gx * (blockIdx.y + gy * blockIdx.z);
    int nwg = gx * gy * gz;
    int sw = (bidl & 7) * (nwg >> 3) + (bidl >> 3);
    int gxy = gx * gy;
    int bz = sw / gxy, rem = sw - bz * gxy;
    int by = rem / gx, bx = rem - by * gx;

    const int b = bz;
    const u16* pA = A + (size_t)b * sA;
    const u16* pB = Bm + (size_t)b * sB;
    const int m0 = by * 128, n0 = bx * 128;
    const int tid = threadIdx.x, wave = tid >> 6, lane = tid & 63;
    const int wm = wave >> 1, wn = wave & 1;
    const int g = lane >> 4;

    f32x4 acc[4][4];
    #pragma unroll
    for (int i = 0; i < 4; ++i)
        #pragma unroll
        for (int j = 0; j < 4; ++j) { f32x4 z = {0.f,0.f,0.f,0.f}; acc[i][j] = z; }

    auto STAGE = [&](int kt, int buf) {
        const int k0 = kt << 5;
        u16* lb = lds + buf * 8192;
        #pragma unroll
        for (int q = 0; q < 4; ++q) {
            int ci = wave * 4 + q;
            bool isA = ci < 8;
            int li = ci & 7;
            const u16* gp = isA ? pA : pB;
            int ld = isA ? lda : ldb;
            int rb = isA ? m0 : n0;
            int rp = li * 8 + (lane >> 3);
            int gg = (lane & 7) ^ (rp & 7);
            int r  = rp * 2 + (gg >> 2);
            int kc = k0 + (gg & 3) * 8;
            gld16(gp + (size_t)(rb + r) * ld + kc,
                  lb + (isA ? 0 : 4096) + li * 512 + lane * 8);
        }
    };
    auto COMPUTE = [&](int buf) {
        const u16* As = lds + buf * 8192;
        const u16* Bs = As + 4096;
        short8v av[4];
        #pragma unroll
        for (int i = 0; i < 4; ++i) {
            int r = wm * 64 + i * 16 + (lane & 15);
            int rp = r >> 1, gg = ((r & 1) << 2) + g;
            av[i] = *(const short8v*)(As + rp * 64 + ((gg ^ (rp & 7)) << 3));
        }
        #pragma unroll
        for (int j = 0; j < 4; ++j) {
            int r = wn * 64 + j * 16 + (lane & 15);
            int rp = r >> 1, gg = ((r & 1) << 2) + g;
            short8v bv = *(const short8v*)(Bs + rp * 64 + ((gg ^ (rp & 7)) << 3));
            #pragma unroll
            for (int i = 0; i < 4; ++i)
                acc[i][j] = __builtin_amdgcn_mfma_f32_16x16x32_bf16(av[i], bv, acc[i][j], 0, 0, 0);
        }
    };

    const int nkt = K >> 5;
    STAGE(0, 0);
    STAGE(1, 1);
    int cur = 0;
    for (int kt = 0; kt < nkt; ++kt) {
        int nxt2 = cur + 2; if (nxt2 >= 3) nxt2 -= 3;
        if (kt + 2 < nkt) {
            STAGE(kt + 2, nxt2);
            asm volatile("s_waitcnt vmcnt(8)" ::: "memory");
        } else if (kt + 1 < nkt) {
            asm volatile("s_waitcnt vmcnt(4)" ::: "memory");
        } else {
            asm volatile("s_waitcnt vmcnt(0)" ::: "memory");
        }
        __builtin_amdgcn_s_barrier();
        __builtin_amdgcn_sched_barrier(0);
        COMPUTE(cur);
        __builtin_amdgcn_sched_barrier(0);
        __builtin_amdgcn_s_barrier();
        ++cur; if (cur >= 3) cur -= 3;
    }

    const float sc = (EPI == 2) ? scaleP[0] : 0.f;
    const int colbase = n0 + wn * 64 + (lane & 15);
    const int rowbase = m0 + wm * 64 + ((lane >> 4) << 2);
    #pragma unroll
    for (int i = 0; i < 4; ++i)
        #pragma unroll
        for (int j = 0; j < 4; ++j) {
            int col = colbase + j * 16;
            #pragma unroll
            for (int rg = 0; rg < 4; ++rg) {
                int row = rowbase + i * 16 + rg;
                size_t idx = (size_t)b * sC + (size_t)row * N + col;
                float a = acc[i][j][rg];
                if (EPI == 0)      Cf[idx] = a;
                else if (EPI == 2) Ch[idx] = tobf(sc * a + frombf(Ch[idx]));
                else if (EPI == 5) Ch[idx] = tobf(a + bias[row]);
                else               Ch[idx] = tobf(a + bias[col]);
            }
        }
}

// ---------------------------------------------------------------------------
// 5) FUSED S-GEMM + row softmax -> P bf16.
//    Block = 64 query rows x all 1024 keys, K=64 one-shot. 8 waves (512 thr).
//    LDS: A 2x2048 u16 + B 2x32768 u16 (staging pattern verified in r10's
//    k_corrtopk) + red arrays. Softmax on f32 accumulators (one less bf16
//    rounding than the old S->softmax path). P written via XOR-row-swizzled
//    LDS bounce -> fully coalesced 16B/lane global stores.
// ---------------------------------------------------------------------------
__global__ __launch_bounds__(512) void k_ssoft(
    const u16* __restrict__ fg,   // [B][1024][128] (cols 0-63 f, 64-127 g)
    u16* __restrict__ P)          // [B][1024][1024]
{
    __shared__ u16 lds[69632];    // [A kc0 2048][A kc1 2048][B kc0 32768][B kc1 32768]
    __shared__ float red[512];
    __shared__ float rowm[64];
    __shared__ float rinv[64];

    const int b = blockIdx.y;
    const int m0 = blockIdx.x * 64;
    const u16* fgb = fg + (size_t)b * 131072;
    const int tid = threadIdx.x, wave = tid >> 6, lane = tid & 63;
    const int wn = wave;
    const int g = lane >> 4;

    // ---- stage A (64x64) + B (1024x64, W-major key perm), both K-chunks ----
    #pragma unroll
    for (int kc = 0; kc < 2; ++kc) {
        #pragma unroll
        for (int q = 0; q < 8; ++q) {               // B: 8 instr/wave/chunk
            int li = wave * 8 + q;                  // 0..63
            int rp = li * 8 + (lane >> 3);          // 0..511
            int gg = (lane & 7) ^ (rp & 7);
            int r  = rp * 2 + (gg >> 2);            // key index 0..1023
            int n2 = ((r & 31) << 5) | (r >> 5);    // W-major -> storage row
            int kcol = 64 + kc * 32 + (gg & 3) * 8;
            gld16(fgb + (size_t)n2 * 128 + kcol,
                  lds + 4096 + kc * 32768 + li * 512 + lane * 8);
        }
        if (lane < 32) {                            // A: 1 instr/wave/chunk
            int rp = wave * 4 + (lane >> 3);        // 0..31
            int gg = (lane & 7) ^ (rp & 7);
            int r  = rp * 2 + (gg >> 2);            // 0..63
            int kcol = kc * 32 + (gg & 3) * 8;
            gld16(fgb + (size_t)(m0 + r) * 128 + kcol,
                  lds + kc * 2048 + wave * 256 + lane * 8);
        }
    }
    __syncthreads();

    // ---- GEMM: wave wn owns cols wn*128..+127, all 64 rows ----
    f32x4 acc[4][8];
    #pragma unroll
    for (int i = 0; i < 4; ++i)
        #pragma unroll
        for (int j = 0; j < 8; ++j) { f32x4 z = {0.f,0.f,0.f,0.f}; acc[i][j] = z; }

    #pragma unroll
    for (int kc = 0; kc < 2; ++kc) {
        const u16* As = lds + kc * 2048;
        const u16* Bs = lds + 4096 + kc * 32768;
        short8v av[4];
        #pragma unroll
        for (int i = 0; i < 4; ++i) {
            int r = i * 16 + (lane & 15);
            int rp = r >> 1, gg = ((r & 1) << 2) + g;
            av[i] = *(const short8v*)(As + rp * 64 + ((gg ^ (rp & 7)) << 3));
        }
        #pragma unroll
        for (int j = 0; j < 8; ++j) {
            int n = wn * 128 + j * 16 + (lane & 15);
            int rp = n >> 1, gg = ((n & 1) << 2) + g;
            short8v bv = *(const short8v*)(Bs + rp * 64 + ((gg ^ (rp & 7)) << 3));
            #pragma unroll
            for (int i = 0; i < 4; ++i)
                acc[i][j] = __builtin_amdgcn_mfma_f32_16x16x32_bf16(av[i], bv, acc[i][j], 0, 0, 0);
        }
    }

    // ---- softmax over full rows (cols split across 8 waves) ----
    const int rgrp = (lane >> 4) << 2;              // row group offset
    float pm[4][4];
    #pragma unroll
    for (int i = 0; i < 4; ++i)
        #pragma unroll
        for (int rg = 0; rg < 4; ++rg) {
            float m = acc[i][0][rg];
            #pragma unroll
            for (int j = 1; j < 8; ++j) m = fmaxf(m, acc[i][j][rg]);
            pm[i][rg] = m;
        }
    #pragma unroll
    for (int o = 1; o < 16; o <<= 1)
        #pragma unroll
        for (int i = 0; i < 4; ++i)
            #pragma unroll
            for (int rg = 0; rg < 4; ++rg)
                pm[i][rg] = fmaxf(pm[i][rg], __shfl_xor(pm[i][rg], o));
    if ((lane & 15) == 0)
        #pragma unroll
        for (int i = 0; i < 4; ++i)
            #pragma unroll
            for (int rg = 0; rg < 4; ++rg)
                red[wn * 64 + i * 16 + rgrp + rg] = pm[i][rg];
    __syncthreads();
    if (tid < 64) {
        float m = red[tid];
        #pragma unroll
        for (int w = 1; w < 8; ++w) m = fmaxf(m, red[w * 64 + tid]);
        rowm[tid] = m;
    }
    __syncthreads();

    float ps[4][4];
    #pragma unroll
    for (int i = 0; i < 4; ++i)
        #pragma unroll
        for (int rg = 0; rg < 4; ++rg) {
            float m = rowm[i * 16 + rgrp + rg];
            float s = 0.f;
            #pragma unroll
            for (int j = 0; j < 8; ++j) {
                float e = expf(acc[i][j][rg] - m);
                acc[i][j][rg] = e;
                s += e;
            }
            ps[i][rg] = s;
        }
    #pragma unroll
    for (int o = 1; o < 16; o <<= 1)
        #pragma unroll
        for (int i = 0; i < 4; ++i)
            #pragma unroll
            for (int rg = 0; rg < 4; ++rg)
                ps[i][rg] += __shfl_xor(ps[i][rg], o);
    if ((lane & 15) == 0)
        #pragma unroll
        for (int i = 0; i < 4; ++i)
            #pragma unroll
            for (int rg = 0; rg < 4; ++rg)
                red[wn * 64 + i * 16 + rgrp + rg] = ps[i][rg];
    __syncthreads();
    if (tid < 64) {
        float s = red[tid];
        #pragma unroll
        for (int w = 1; w < 8; ++w) s += red[w * 64 + tid];
        rinv[tid] = 1.f / s;
    }
    __syncthreads();

    // ---- normalize + cvt + XOR-swizzled LDS bounce (reuse B region) ----
    u16* Plds = lds + 4096;                         // [64][1024] u16
    #pragma unroll
    for (int i = 0; i < 4; ++i)
        #pragma unroll
        for (int rg = 0; rg < 4; ++rg) {
            int r = i * 16 + rgrp + rg;
            float riv = rinv[r];
            int sx = (r & 7) << 4;
            #pragma unroll
            for (int j = 0; j < 8; ++j) {
                u16 v = tobf(acc[i][j][rg] * riv);
                int col = wn * 128 + ((j * 16) ^ sx) + (lane & 15);
                Plds[r * 1024 + col] = v;
            }
        }
    __syncthreads();

    // ---- cooperative fully-coalesced global write ----
    for (int it = 0; it < 16; ++it) {
        int r  = it * 4 + (tid >> 7);
        int cb = (tid & 127) * 8;
        int sx = (r & 7) << 4;
        int src = r * 1024 + (cb & ~127) + ((cb & 127) ^ sx);
        short8v v = *(const short8v*)(Plds + src);
        *(short8v*)(P + ((size_t)b * HW_ + m0 + r) * (size_t)HW_ + cb) = v;
    }
}

// ---------------------------------------------------------------------------
// 6) single-plane u16 transpose of fdd flat view [512][1024] -> fddT [1024][512]
// ---------------------------------------------------------------------------
__global__ void k_tposeU1(const u16* __restrict__ src, u16* __restrict__ dst) {
    __shared__ u16 tile[32][33];
    int b = blockIdx.z;
    const u16* sb = src + (size_t)b * (C_ * HW_);
    u16* db = dst + (size_t)b * (C_ * HW_);
    int c0 = blockIdx.x * 32, r0 = blockIdx.y * 32;
    int tx = threadIdx.x, ty = threadIdx.y;
    #pragma unroll
    for (int j = 0; j < 32; j += 8)
        tile[ty + j][tx] = sb[(size_t)(r0 + ty + j) * HW_ + c0 + tx];
    __syncthreads();
    #pragma unroll
    for (int j = 0; j < 32; j += 8)
        db[(size_t)(c0 + ty + j) * C_ + r0 + tx] = tile[tx][ty + j];
}

// ---------------------------------------------------------------------------
// 7) top-48, one WAVE per row (verified r8-r11)
// ---------------------------------------------------------------------------
__device__ __forceinline__ float sort64_desc(float v, int lane) {
    #pragma unroll
    for (int k = 2; k <= 64; k <<= 1) {
        #pragma unroll
        for (int j = k >> 1; j > 0; j >>= 1) {
            float o = __shfl_xor(v, j);
            bool takeMax = (((lane & k) == 0) == ((lane & j) == 0));
            v = takeMax ? fmaxf(v, o) : fminf(v, o);
        }
    }
    return v;
}
__device__ __forceinline__ float bmerge64_desc(float a, float b, int lane) {
    float br = __shfl(b, 63 - lane);
    float c = fmaxf(a, br);
    #pragma unroll
    for (int j = 32; j > 0; j >>= 1) {
        float o = __shfl_xor(c, j);
        c = ((lane & j) == 0) ? fmaxf(c, o) : fminf(c, o);
    }
    return c;
}

__global__ __launch_bounds__(256) void k_topk(const float* __restrict__ corr,
                                              float* __restrict__ topv) {
    __shared__ float buf[4][1024];
    int wave = threadIdx.x >> 6, lane = threadIdx.x & 63;
    int row = blockIdx.x * 4 + wave;
    const float4* rp = (const float4*)(corr + (size_t)row * HW_);

    float4 e[4];
    #pragma unroll
    for (int q = 0; q < 4; ++q) e[q] = rp[lane * 4 + q];

    float gm = -INFINITY;
    #pragma unroll
    for (int q = 0; q < 4; ++q)
        gm = fmaxf(gm, fmaxf(fmaxf(e[q].x, e[q].y), fmaxf(e[q].z, e[q].w)));
    float sorted = sort64_desc(gm, lane);
    float tau = __shfl(sorted, T_ - 1);

    int c = 0;
    #pragma unroll
    for (int q = 0; q < 4; ++q)
        c += (e[q].x >= tau) + (e[q].y >= tau) + (e[q].z >= tau) + (e[q].w >= tau);
    int sc = c;
    #pragma unroll
    for (int o = 1; o < 64; o <<= 1) {
        int t2 = __shfl_up(sc, o);
        if (lane >= o) sc += t2;
    }
    int off = sc - c;
    int cnt = __shfl(sc, 63);

    float* wb = buf[wave];
    #pragma unroll
    for (int q = 0; q < 4; ++q) {
        if (e[q].x >= tau) wb[off++] = e[q].x;
        if (e[q].y >= tau) wb[off++] = e[q].y;
        if (e[q].z >= tau) wb[off++] = e[q].z;
        if (e[q].w >= tau) wb[off++] = e[q].w;
    }

    float* orow = topv + (size_t)row * T_;
    if (cnt <= 64) {
        float a = (lane < cnt) ? wb[lane] : -INFINITY;
        a = sort64_desc(a, lane);
        if (lane < T_) orow[lane] = fmaxf(a, 0.f);
    } else if (cnt <= 128) {
        float a  = sort64_desc(wb[lane], lane);
        float b2 = sort64_desc((lane < cnt - 64) ? wb[64 + lane] : -INFINITY, lane);
        float m2 = bmerge64_desc(a, b2, lane);
        if (lane < T_) orow[lane] = fmaxf(m2, 0.f);
    } else {
        int P = 256; while (P < cnt) P <<= 1;
        for (int i = cnt + lane; i < P; i += 64) wb[i] = -INFINITY;
        for (int k = 2; k <= P; k <<= 1)
            for (int j = k >> 1; j > 0; j >>= 1)
                for (int t2 = lane; t2 < P; t2 += 64) {
                    int ixj = t2 ^ j;
                    if (ixj > t2) {
                        float a = wb[t2], b3 = wb[ixj];
                        bool desc = ((t2 & k) == 0);
                        if (desc ? (a < b3) : (a > b3)) { wb[t2] = b3; wb[ixj] = a; }
                    }
                }
        if (lane < T_) orow[lane] = fmaxf(wb[lane], 0.f);
    }
}

// ---------------------------------------------------------------------------
// 8) column norm over (B,H) and final transpose
// ---------------------------------------------------------------------------
__global__ void k_colss(const float* __restrict__ topv, float* __restrict__ colss) {
    int o = blockIdx.x;
    int w = o / T_, t = o % T_;
    int lane = threadIdx.x;
    float s = 0.f;
    for (int i = lane; i < 512; i += 64) {
        int b = i >> 5, h = i & 31;
        float v = topv[(size_t)((b << 10) + (h << 5) + w) * T_ + t];
        s += v * v;
    }
    for (int off = 32; off > 0; off >>= 1) s += __shfl_down(s, off);
    if (lane == 0) colss[o] = s;
}

__global__ void k_final(const float* __restrict__ topv, const float* __restrict__ colss,
                        float* __restrict__ out) {
    int idx = blockIdx.x * 256 + threadIdx.x;
    if (idx >= B_ * T_ * HW_) return;
    int w = idx & 31;
    int h = (idx >> 5) & 31;
    int t = (idx >> 10) % T_;
    int b = idx / (T_ * HW_);
    float v = topv[(size_t)((b << 10) + (h << 5) + w) * T_ + t];
    out[idx] = v * rsqrtf(colss[w * T_ + t]);
}

// ---------------------------------------------------------------------------
extern "C" void kernel_launch(void* const* d_in, const int* in_sizes, int n_in,
                              void* d_out, int out_size, void* d_ws, size_t ws_size,
                              hipStream_t stream) {
    const float* x     = (const float*)d_in[0];
    const float* fW    = (const float*)d_in[1];
    const float* fb    = (const float*)d_in[2];
    const float* gW    = (const float*)d_in[3];
    const float* gb    = (const float*)d_in[4];
    const float* hW    = (const float*)d_in[5];
    const float* hb    = (const float*)d_in[6];
    const float* scale = (const float*)d_in[7];
    float* out = (float*)d_out;

    char* wsb = (char*)d_ws;
    float* part = (float*)(wsb + 0);                 // 262144 B [64][1024]
    float* ninv = (float*)(wsb + 262144);            // 4096 B
    u16*   hWh  = (u16*)(wsb + 266240);              // 524288 B
    u16*   fgWh = (u16*)(wsb + 790528);              // 131072 B
    float* fgb  = (float*)(wsb + 921600);            // 512 B
    u16*   xnH  = (u16*)(wsb + 922112);              // 16 MB (xn -> fdd bf16)
    u16*   fgH  = (u16*)(wsb + 17699328);            // 4 MB (f|g; later topv)
    u16*   fgL  = (u16*)(wsb + 21893632);            // 4 MB (later colss)
    u16*   hvTH = (u16*)(wsb + 26087936);            // 16 MB (hv -> fddT)
    float* S    = (float*)(wsb + 42865152);          // 64 MB (P u16 -> corr fp32)
    float* topv = (float*)fgH;
    float* colss= (float*)fgL;
    u16*   Sp   = (u16*)S;

    const long sXn = 524288;    // [1024][512] elements per batch
    const long sFG = 131072;    // [1024][128]
    const long sS  = 1048576;   // [1024][1024]

    // 1) per-pixel Frobenius norm
    k_colsq<<<256, 256, 0, stream>>>(x, part);
    k_rsqrt<<<4, 256, 0, stream>>>(part, ninv);

    // 2) normalized channel-last bf16
    k_transpose<<<dim3(32, 16, 16), dim3(32, 8), 0, stream>>>(x, ninv, xnH);

    // 3) weight planes
    k_packW<<<1024, 256, 0, stream>>>(hW, hWh);
    k_packFG<<<256, 256, 0, stream>>>(fW, gW, fb, gb, fgWh, fgb);

    // 4) fg = bf16(xn @ [fW|gW]^T + bias[col])  [B,1024,128]
    k_gemm1<6><<<dim3(1, 8, 16), 256, 0, stream>>>(
        xnH, fgWh, fgb, nullptr, fgH, nullptr,
        128, 512, 512, 512, sXn, 0, sFG);

    // 5) hv = bf16(hW @ xn^T + hb[row])  [B,512,1024]
    k_gemm1<5><<<dim3(8, 4, 16), 256, 0, stream>>>(
        hWh, xnH, hb, nullptr, hvTH, nullptr,
        1024, 512, 512, 512, 0, sXn, sXn);

    // 6+7) fused S-GEMM + softmax -> P bf16 (64-row blocks, W-major keys)
    k_ssoft<<<dim3(16, 16), 512, 0, stream>>>(fgH, Sp);

    // 8) fdd = bf16(scale*(P @ hv^T) + xn), in place over xnH
    k_gemm1<2><<<dim3(4, 8, 16), 256, 0, stream>>>(
        Sp, hvTH, nullptr, nullptr, xnH, scale,
        512, 1024, 1024, 1024, sS, sXn, sXn);

    // 9) fddT: transpose flat [512][1024] view of fddH -> hvTH [1024][512]
    k_tposeU1<<<dim3(32, 16, 16), dim3(32, 8), 0, stream>>>(xnH, hvTH);

    // 10) corr = fdd @ fddT^T -> fp32 into S
    k_gemm1<0><<<dim3(8, 8, 16), 256, 0, stream>>>(
        xnH, hvTH, nullptr, S, nullptr, nullptr,
        1024, 512, 512, 512, sXn, sXn, sS);

    // 11) top-48 desc + relu (wave-per-row)
    k_topk<<<B_ * HW_ / 4, 256, 0, stream>>>(S, topv);

    // 12) norm over (B,H) + output transpose
    k_colss<<<W_ * T_, 64, 0, stream>>>(topv, colss);
    k_final<<<(B_ * T_ * HW_ + 255) / 256, 256, 0, stream>>>(topv, colss, out);
}

// Round 13
// 186.326 us; speedup vs baseline: 1.1963x; 1.0486x over previous
//
#include <hip/hip_runtime.h>
#include <cstdint>
#include <cstddef>

#define B_   16
#define C_   512
#define H_   32
#define W_   32
#define HW_  1024
#define TC_  64
#define T_   48

typedef unsigned short u16;
typedef __attribute__((ext_vector_type(8))) short short8v;
typedef __attribute__((ext_vector_type(4))) float f32x4;

// ---------------------------------------------------------------------------
// bf16 helpers
// ---------------------------------------------------------------------------
__device__ __forceinline__ u16 tobf(float x) {
    unsigned u = __float_as_uint(x);
    return (u16)((u + 0x7FFFu + ((u >> 16) & 1u)) >> 16);    // RTNE
}
__device__ __forceinline__ float frombf(u16 h) {
    return __uint_as_float(((unsigned)h) << 16);
}

__device__ __forceinline__ void gld16(const void* g, void* l) {
    __builtin_amdgcn_global_load_lds(
        (const __attribute__((address_space(1))) void*)g,
        (__attribute__((address_space(3))) void*)l, 16, 0, 0);
}

// ---------------------------------------------------------------------------
// 1) Frobenius-norm helpers
// ---------------------------------------------------------------------------
__global__ void k_colsq(const float* __restrict__ x, float* __restrict__ partial) {
    int bid = blockIdx.x;
    int col = (bid & 3) * 256 + threadIdx.x;
    int r0  = (bid >> 2) * 128;
    const float* p = x + (size_t)r0 * HW_ + col;
    float s = 0.f;
    for (int r = 0; r < 128; ++r) { float v = p[(size_t)r * HW_]; s += v * v; }
    partial[(size_t)(bid >> 2) * HW_ + col] = s;
}

__global__ void k_rsqrt(const float* __restrict__ partial, float* __restrict__ ninv) {
    int i = blockIdx.x * 256 + threadIdx.x;
    if (i < HW_) {
        float s = 0.f;
        for (int r = 0; r < 64; ++r) s += partial[(size_t)r * HW_ + i];
        ninv[i] = rsqrtf(s);
    }
}

// ---------------------------------------------------------------------------
// 2) transpose + normalize: x [B,C,HW] -> xnH bf16 [B,HW,C]
// ---------------------------------------------------------------------------
__global__ void k_transpose(const float* __restrict__ x, const float* __restrict__ ninv,
                            u16* __restrict__ obH) {
    __shared__ float tile[32][33];
    int b  = blockIdx.z;
    int m0 = blockIdx.x * 32, c0 = blockIdx.y * 32;
    int tx = threadIdx.x, ty = threadIdx.y;
    const float* xb = x + (size_t)b * C_ * HW_;
    #pragma unroll
    for (int j = 0; j < 32; j += 8)
        tile[ty + j][tx] = xb[(size_t)(c0 + ty + j) * HW_ + m0 + tx];
    __syncthreads();
    size_t base = (size_t)b * HW_ * C_;
    #pragma unroll
    for (int j = 0; j < 32; j += 8) {
        int m = m0 + ty + j;
        obH[base + (size_t)m * C_ + c0 + tx] = tobf(tile[tx][ty + j] * ninv[m]);
    }
}

// ---------------------------------------------------------------------------
// 3) weight prep (hi plane only)
// ---------------------------------------------------------------------------
__global__ void k_packW(const float* __restrict__ in, u16* __restrict__ oh) {
    size_t i = (size_t)blockIdx.x * 256 + threadIdx.x;
    oh[i] = tobf(in[i]);
}
__global__ void k_packFG(const float* __restrict__ fW, const float* __restrict__ gW,
                         const float* __restrict__ fb, const float* __restrict__ gb,
                         u16* __restrict__ oh, float* __restrict__ fgb) {
    int idx = blockIdx.x * 256 + threadIdx.x;   // 65536
    int row = idx >> 9, c = idx & 511;
    float v = (row < 64) ? fW[row * 512 + c] : gW[(row - 64) * 512 + c];
    oh[idx] = tobf(v);
    if (idx < 128) fgb[idx] = (idx < 64) ? fb[idx] : gb[idx - 64];
}

// ---------------------------------------------------------------------------
// 4) 1-term bf16 MFMA GEMM, 128x128, 4 waves, 2-buffer counted-vmcnt (r9) +
//    XCD swizzle (r12). LDS 36 KB (staging 32 KB; EPI7 reuses as TL[256][72]).
//    EPI 0: Cf fp32 = acc
//    EPI 5: Ch = bf16(acc + bias[row])
//    EPI 6: Ch = bf16(acc + bias[col])
//    EPI 7: PV: Ch = bf16(scale*acc + frombf(Ch)) in place over xn, AND
//           transposed flat-view write to Ct (fddT[c][r], r=m>>1,
//           c=(m&1)*512+n) via LDS bounce — replaces the k_tposeU1 pass.
// ---------------------------------------------------------------------------
template<int EPI>
__global__ __launch_bounds__(256) void k_gemm1(
    const u16* __restrict__ A, const u16* __restrict__ Bm,
    const float* __restrict__ bias,
    float* __restrict__ Cf, u16* __restrict__ Ch, u16* __restrict__ Ct,
    const float* __restrict__ scaleP,
    int N, int K, int lda, int ldb, long sA, long sB, long sC)
{
    __shared__ u16 lds[18432];     // 2 x 8192 staging; EPI7: TL[256][72]
    // T1 XCD swizzle (all grids %8 == 0)
    const int gx = gridDim.x, gy = gridDim.y, gz = gridDim.z;
    int bidl = blockIdx.x + gx * (blockIdx.y + gy * blockIdx.z);
    int nwg = gx * gy * gz;
    int sw = (bidl & 7) * (nwg >> 3) + (bidl >> 3);
    int gxy = gx * gy;
    int bz = sw / gxy, rem = sw - bz * gxy;
    int by = rem / gx, bx = rem - by * gx;

    const int b = bz;
    const u16* pA = A + (size_t)b * sA;
    const u16* pB = Bm + (size_t)b * sB;
    const int m0 = by * 128, n0 = bx * 128;
    const int tid = threadIdx.x, wave = tid >> 6, lane = tid & 63;
    const int wm = wave >> 1, wn = wave & 1;
    const int g = lane >> 4;

    f32x4 acc[4][4];
    #pragma unroll
    for (int i = 0; i < 4; ++i)
        #pragma unroll
        for (int j = 0; j < 4; ++j) { f32x4 z = {0.f,0.f,0.f,0.f}; acc[i][j] = z; }

    auto STAGE = [&](int kt, int buf) {
        const int k0 = kt << 5;
        u16* lb = lds + buf * 8192;
        #pragma unroll
        for (int q = 0; q < 4; ++q) {
            int ci = wave * 4 + q;
            bool isA = ci < 8;
            int li = ci & 7;
            const u16* gp = isA ? pA : pB;
            int ld = isA ? lda : ldb;
            int rb = isA ? m0 : n0;
            int rp = li * 8 + (lane >> 3);
            int gg = (lane & 7) ^ (rp & 7);
            int r  = rp * 2 + (gg >> 2);
            int kc = k0 + (gg & 3) * 8;
            gld16(gp + (size_t)(rb + r) * ld + kc,
                  lb + (isA ? 0 : 4096) + li * 512 + lane * 8);
        }
    };
    auto COMPUTE = [&](int buf) {
        const u16* As = lds + buf * 8192;
        const u16* Bs = As + 4096;
        short8v av[4];
        #pragma unroll
        for (int i = 0; i < 4; ++i) {
            int r = wm * 64 + i * 16 + (lane & 15);
            int rp = r >> 1, gg = ((r & 1) << 2) + g;
            av[i] = *(const short8v*)(As + rp * 64 + ((gg ^ (rp & 7)) << 3));
        }
        #pragma unroll
        for (int j = 0; j < 4; ++j) {
            int r = wn * 64 + j * 16 + (lane & 15);
            int rp = r >> 1, gg = ((r & 1) << 2) + g;
            short8v bv = *(const short8v*)(Bs + rp * 64 + ((gg ^ (rp & 7)) << 3));
            #pragma unroll
            for (int i = 0; i < 4; ++i)
                acc[i][j] = __builtin_amdgcn_mfma_f32_16x16x32_bf16(av[i], bv, acc[i][j], 0, 0, 0);
        }
    };

    const int nkt = K >> 5;
    STAGE(0, 0);
    int cur = 0;
    for (int kt = 0; kt < nkt; ++kt) {
        if (kt + 1 < nkt) {
            STAGE(kt + 1, cur ^ 1);
            asm volatile("s_waitcnt vmcnt(4)" ::: "memory");
        } else {
            asm volatile("s_waitcnt vmcnt(0)" ::: "memory");
        }
        __builtin_amdgcn_s_barrier();
        __builtin_amdgcn_sched_barrier(0);
        COMPUTE(cur);
        __builtin_amdgcn_sched_barrier(0);
        __builtin_amdgcn_s_barrier();
        cur ^= 1;
    }

    const float sc = (EPI == 7) ? scaleP[0] : 0.f;
    const int colbase = n0 + wn * 64 + (lane & 15);
    const int rowbase = m0 + wm * 64 + ((lane >> 4) << 2);
    #pragma unroll
    for (int i = 0; i < 4; ++i)
        #pragma unroll
        for (int j = 0; j < 4; ++j) {
            int col = colbase + j * 16;
            #pragma unroll
            for (int rg = 0; rg < 4; ++rg) {
                int row = rowbase + i * 16 + rg;
                size_t idx = (size_t)b * sC + (size_t)row * N + col;
                float a = acc[i][j][rg];
                if (EPI == 0)      Cf[idx] = a;
                else if (EPI == 5) Ch[idx] = tobf(a + bias[row]);
                else if (EPI == 6) Ch[idx] = tobf(a + bias[col]);
                else {             // EPI == 7
                    u16 v = tobf(sc * a + frombf(Ch[idx]));
                    Ch[idx] = v;
                    int lr = row - m0, lc = col - n0;
                    lds[(size_t)((lr & 1) * 128 + lc) * 72 + (lr >> 1)] = v;
                }
            }
        }

    if (EPI == 7) {
        __syncthreads();
        // cooperative transposed write: Ct[c][r], 256 tc-rows x 64 r each
        #pragma unroll
        for (int it = 0; it < 8; ++it) {
            int task = it * 256 + tid;
            int tc = task >> 3, ch = task & 7;
            short8v v = *(const short8v*)(lds + tc * 72 + ch * 8);
            int cg = ((tc >> 7) ? 512 : 0) + n0 + (tc & 127);
            *(short8v*)(Ct + (size_t)b * 524288 + (size_t)cg * 512 + (m0 >> 1) + ch * 8) = v;
        }
    }
}

// ---------------------------------------------------------------------------
// 5) FUSED S-GEMM + row softmax -> P bf16 (verified r12)
// ---------------------------------------------------------------------------
__global__ __launch_bounds__(512) void k_ssoft(
    const u16* __restrict__ fg,   // [B][1024][128] (cols 0-63 f, 64-127 g)
    u16* __restrict__ P)          // [B][1024][1024]
{
    __shared__ u16 lds[69632];
    __shared__ float red[512];
    __shared__ float rowm[64];
    __shared__ float rinv[64];

    const int b = blockIdx.y;
    const int m0 = blockIdx.x * 64;
    const u16* fgb = fg + (size_t)b * 131072;
    const int tid = threadIdx.x, wave = tid >> 6, lane = tid & 63;
    const int wn = wave;
    const int g = lane >> 4;

    #pragma unroll
    for (int kc = 0; kc < 2; ++kc) {
        #pragma unroll
        for (int q = 0; q < 8; ++q) {
            int li = wave * 8 + q;
            int rp = li * 8 + (lane >> 3);
            int gg = (lane & 7) ^ (rp & 7);
            int r  = rp * 2 + (gg >> 2);
            int n2 = ((r & 31) << 5) | (r >> 5);
            int kcol = 64 + kc * 32 + (gg & 3) * 8;
            gld16(fgb + (size_t)n2 * 128 + kcol,
                  lds + 4096 + kc * 32768 + li * 512 + lane * 8);
        }
        if (lane < 32) {
            int rp = wave * 4 + (lane >> 3);
            int gg = (lane & 7) ^ (rp & 7);
            int r  = rp * 2 + (gg >> 2);
            int kcol = kc * 32 + (gg & 3) * 8;
            gld16(fgb + (size_t)(m0 + r) * 128 + kcol,
                  lds + kc * 2048 + wave * 256 + lane * 8);
        }
    }
    __syncthreads();

    f32x4 acc[4][8];
    #pragma unroll
    for (int i = 0; i < 4; ++i)
        #pragma unroll
        for (int j = 0; j < 8; ++j) { f32x4 z = {0.f,0.f,0.f,0.f}; acc[i][j] = z; }

    #pragma unroll
    for (int kc = 0; kc < 2; ++kc) {
        const u16* As = lds + kc * 2048;
        const u16* Bs = lds + 4096 + kc * 32768;
        short8v av[4];
        #pragma unroll
        for (int i = 0; i < 4; ++i) {
            int r = i * 16 + (lane & 15);
            int rp = r >> 1, gg = ((r & 1) << 2) + g;
            av[i] = *(const short8v*)(As + rp * 64 + ((gg ^ (rp & 7)) << 3));
        }
        #pragma unroll
        for (int j = 0; j < 8; ++j) {
            int n = wn * 128 + j * 16 + (lane & 15);
            int rp = n >> 1, gg = ((n & 1) << 2) + g;
            short8v bv = *(const short8v*)(Bs + rp * 64 + ((gg ^ (rp & 7)) << 3));
            #pragma unroll
            for (int i = 0; i < 4; ++i)
                acc[i][j] = __builtin_amdgcn_mfma_f32_16x16x32_bf16(av[i], bv, acc[i][j], 0, 0, 0);
        }
    }

    const int rgrp = (lane >> 4) << 2;
    float pm[4][4];
    #pragma unroll
    for (int i = 0; i < 4; ++i)
        #pragma unroll
        for (int rg = 0; rg < 4; ++rg) {
            float m = acc[i][0][rg];
            #pragma unroll
            for (int j = 1; j < 8; ++j) m = fmaxf(m, acc[i][j][rg]);
            pm[i][rg] = m;
        }
    #pragma unroll
    for (int o = 1; o < 16; o <<= 1)
        #pragma unroll
        for (int i = 0; i < 4; ++i)
            #pragma unroll
            for (int rg = 0; rg < 4; ++rg)
                pm[i][rg] = fmaxf(pm[i][rg], __shfl_xor(pm[i][rg], o));
    if ((lane & 15) == 0)
        #pragma unroll
        for (int i = 0; i < 4; ++i)
            #pragma unroll
            for (int rg = 0; rg < 4; ++rg)
                red[wn * 64 + i * 16 + rgrp + rg] = pm[i][rg];
    __syncthreads();
    if (tid < 64) {
        float m = red[tid];
        #pragma unroll
        for (int w = 1; w < 8; ++w) m = fmaxf(m, red[w * 64 + tid]);
        rowm[tid] = m;
    }
    __syncthreads();

    float ps[4][4];
    #pragma unroll
    for (int i = 0; i < 4; ++i)
        #pragma unroll
        for (int rg = 0; rg < 4; ++rg) {
            float m = rowm[i * 16 + rgrp + rg];
            float s = 0.f;
            #pragma unroll
            for (int j = 0; j < 8; ++j) {
                float e = expf(acc[i][j][rg] - m);
                acc[i][j][rg] = e;
                s += e;
            }
            ps[i][rg] = s;
        }
    #pragma unroll
    for (int o = 1; o < 16; o <<= 1)
        #pragma unroll
        for (int i = 0; i < 4; ++i)
            #pragma unroll
            for (int rg = 0; rg < 4; ++rg)
                ps[i][rg] += __shfl_xor(ps[i][rg], o);
    if ((lane & 15) == 0)
        #pragma unroll
        for (int i = 0; i < 4; ++i)
            #pragma unroll
            for (int rg = 0; rg < 4; ++rg)
                red[wn * 64 + i * 16 + rgrp + rg] = ps[i][rg];
    __syncthreads();
    if (tid < 64) {
        float s = red[tid];
        #pragma unroll
        for (int w = 1; w < 8; ++w) s += red[w * 64 + tid];
        rinv[tid] = 1.f / s;
    }
    __syncthreads();

    u16* Plds = lds + 4096;
    #pragma unroll
    for (int i = 0; i < 4; ++i)
        #pragma unroll
        for (int rg = 0; rg < 4; ++rg) {
            int r = i * 16 + rgrp + rg;
            float riv = rinv[r];
            int sx = (r & 7) << 4;
            #pragma unroll
            for (int j = 0; j < 8; ++j) {
                u16 v = tobf(acc[i][j][rg] * riv);
                int col = wn * 128 + ((j * 16) ^ sx) + (lane & 15);
                Plds[r * 1024 + col] = v;
            }
        }
    __syncthreads();

    for (int it = 0; it < 16; ++it) {
        int r  = it * 4 + (tid >> 7);
        int cb = (tid & 127) * 8;
        int sx = (r & 7) << 4;
        int src = r * 1024 + (cb & ~127) + ((cb & 127) ^ sx);
        short8v v = *(const short8v*)(Plds + src);
        *(short8v*)(P + ((size_t)b * HW_ + m0 + r) * (size_t)HW_ + cb) = v;
    }
}

// ---------------------------------------------------------------------------
// 6) top-48, one WAVE per row (verified r8-r12)
// ---------------------------------------------------------------------------
__device__ __forceinline__ float sort64_desc(float v, int lane) {
    #pragma unroll
    for (int k = 2; k <= 64; k <<= 1) {
        #pragma unroll
        for (int j = k >> 1; j > 0; j >>= 1) {
            float o = __shfl_xor(v, j);
            bool takeMax = (((lane & k) == 0) == ((lane & j) == 0));
            v = takeMax ? fmaxf(v, o) : fminf(v, o);
        }
    }
    return v;
}
__device__ __forceinline__ float bmerge64_desc(float a, float b, int lane) {
    float br = __shfl(b, 63 - lane);
    float c = fmaxf(a, br);
    #pragma unroll
    for (int j = 32; j > 0; j >>= 1) {
        float o = __shfl_xor(c, j);
        c = ((lane & j) == 0) ? fmaxf(c, o) : fminf(c, o);
    }
    return c;
}

__global__ __launch_bounds__(256) void k_topk(const float* __restrict__ corr,
                                              float* __restrict__ topv) {
    __shared__ float buf[4][1024];
    int wave = threadIdx.x >> 6, lane = threadIdx.x & 63;
    int row = blockIdx.x * 4 + wave;
    const float4* rp = (const float4*)(corr + (size_t)row * HW_);

    float4 e[4];
    #pragma unroll
    for (int q = 0; q < 4; ++q) e[q] = rp[lane * 4 + q];

    float gm = -INFINITY;
    #pragma unroll
    for (int q = 0; q < 4; ++q)
        gm = fmaxf(gm, fmaxf(fmaxf(e[q].x, e[q].y), fmaxf(e[q].z, e[q].w)));
    float sorted = sort64_desc(gm, lane);
    float tau = __shfl(sorted, T_ - 1);

    int c = 0;
    #pragma unroll
    for (int q = 0; q < 4; ++q)
        c += (e[q].x >= tau) + (e[q].y >= tau) + (e[q].z >= tau) + (e[q].w >= tau);
    int sc = c;
    #pragma unroll
    for (int o = 1; o < 64; o <<= 1) {
        int t2 = __shfl_up(sc, o);
        if (lane >= o) sc += t2;
    }
    int off = sc - c;
    int cnt = __shfl(sc, 63);

    float* wb = buf[wave];
    #pragma unroll
    for (int q = 0; q < 4; ++q) {
        if (e[q].x >= tau) wb[off++] = e[q].x;
        if (e[q].y >= tau) wb[off++] = e[q].y;
        if (e[q].z >= tau) wb[off++] = e[q].z;
        if (e[q].w >= tau) wb[off++] = e[q].w;
    }

    float* orow = topv + (size_t)row * T_;
    if (cnt <= 64) {
        float a = (lane < cnt) ? wb[lane] : -INFINITY;
        a = sort64_desc(a, lane);
        if (lane < T_) orow[lane] = fmaxf(a, 0.f);
    } else if (cnt <= 128) {
        float a  = sort64_desc(wb[lane], lane);
        float b2 = sort64_desc((lane < cnt - 64) ? wb[64 + lane] : -INFINITY, lane);
        float m2 = bmerge64_desc(a, b2, lane);
        if (lane < T_) orow[lane] = fmaxf(m2, 0.f);
    } else {
        int P = 256; while (P < cnt) P <<= 1;
        for (int i = cnt + lane; i < P; i += 64) wb[i] = -INFINITY;
        for (int k = 2; k <= P; k <<= 1)
            for (int j = k >> 1; j > 0; j >>= 1)
                for (int t2 = lane; t2 < P; t2 += 64) {
                    int ixj = t2 ^ j;
                    if (ixj > t2) {
                        float a = wb[t2], b3 = wb[ixj];
                        bool desc = ((t2 & k) == 0);
                        if (desc ? (a < b3) : (a > b3)) { wb[t2] = b3; wb[ixj] = a; }
                    }
                }
        if (lane < T_) orow[lane] = fmaxf(wb[lane], 0.f);
    }
}

// ---------------------------------------------------------------------------
// 7) column norm over (B,H) and final transpose
// ---------------------------------------------------------------------------
__global__ void k_colss(const float* __restrict__ topv, float* __restrict__ colss) {
    int o = blockIdx.x;
    int w = o / T_, t = o % T_;
    int lane = threadIdx.x;
    float s = 0.f;
    for (int i = lane; i < 512; i += 64) {
        int b = i >> 5, h = i & 31;
        float v = topv[(size_t)((b << 10) + (h << 5) + w) * T_ + t];
        s += v * v;
    }
    for (int off = 32; off > 0; off >>= 1) s += __shfl_down(s, off);
    if (lane == 0) colss[o] = s;
}

__global__ void k_final(const float* __restrict__ topv, const float* __restrict__ colss,
                        float* __restrict__ out) {
    int idx = blockIdx.x * 256 + threadIdx.x;
    if (idx >= B_ * T_ * HW_) return;
    int w = idx & 31;
    int h = (idx >> 5) & 31;
    int t = (idx >> 10) % T_;
    int b = idx / (T_ * HW_);
    float v = topv[(size_t)((b << 10) + (h << 5) + w) * T_ + t];
    out[idx] = v * rsqrtf(colss[w * T_ + t]);
}

// ---------------------------------------------------------------------------
extern "C" void kernel_launch(void* const* d_in, const int* in_sizes, int n_in,
                              void* d_out, int out_size, void* d_ws, size_t ws_size,
                              hipStream_t stream) {
    const float* x     = (const float*)d_in[0];
    const float* fW    = (const float*)d_in[1];
    const float* fb    = (const float*)d_in[2];
    const float* gW    = (const float*)d_in[3];
    const float* gb    = (const float*)d_in[4];
    const float* hW    = (const float*)d_in[5];
    const float* hb    = (const float*)d_in[6];
    const float* scale = (const float*)d_in[7];
    float* out = (float*)d_out;

    char* wsb = (char*)d_ws;
    float* part = (float*)(wsb + 0);                 // 262144 B [64][1024]
    float* ninv = (float*)(wsb + 262144);            // 4096 B
    u16*   hWh  = (u16*)(wsb + 266240);              // 524288 B
    u16*   fgWh = (u16*)(wsb + 790528);              // 131072 B
    float* fgb  = (float*)(wsb + 921600);            // 512 B
    u16*   xnH  = (u16*)(wsb + 922112);              // 16 MB (xn -> fdd bf16)
    u16*   fgH  = (u16*)(wsb + 17699328);            // 4 MB (f|g; later topv)
    u16*   fgL  = (u16*)(wsb + 21893632);            // 4 MB (later colss)
    u16*   hvTH = (u16*)(wsb + 26087936);            // 16 MB (hv)
    float* S    = (float*)(wsb + 42865152);          // 64 MB (P u16 -> corr fp32)
    u16*   fddT = (u16*)(wsb + 109974016);           // 16 MB (fddT)
    float* topv = (float*)fgH;
    float* colss= (float*)fgL;
    u16*   Sp   = (u16*)S;

    const long sXn = 524288;    // [1024][512] elements per batch
    const long sFG = 131072;    // [1024][128]
    const long sS  = 1048576;   // [1024][1024]

    // 1) per-pixel Frobenius norm
    k_colsq<<<256, 256, 0, stream>>>(x, part);
    k_rsqrt<<<4, 256, 0, stream>>>(part, ninv);

    // 2) normalized channel-last bf16
    k_transpose<<<dim3(32, 16, 16), dim3(32, 8), 0, stream>>>(x, ninv, xnH);

    // 3) weight planes
    k_packW<<<1024, 256, 0, stream>>>(hW, hWh);
    k_packFG<<<256, 256, 0, stream>>>(fW, gW, fb, gb, fgWh, fgb);

    // 4) fg = bf16(xn @ [fW|gW]^T + bias[col])  [B,1024,128]
    k_gemm1<6><<<dim3(1, 8, 16), 256, 0, stream>>>(
        xnH, fgWh, fgb, nullptr, fgH, nullptr, nullptr,
        128, 512, 512, 512, sXn, 0, sFG);

    // 5) hv = bf16(hW @ xn^T + hb[row])  [B,512,1024]
    k_gemm1<5><<<dim3(8, 4, 16), 256, 0, stream>>>(
        hWh, xnH, hb, nullptr, hvTH, nullptr, nullptr,
        1024, 512, 512, 512, 0, sXn, sXn);

    // 6+7) fused S-GEMM + softmax -> P bf16
    k_ssoft<<<dim3(16, 16), 512, 0, stream>>>(fgH, Sp);

    // 8) fdd = bf16(scale*(P @ hv^T) + xn) in place over xnH, PLUS fddT
    //    transposed write (replaces separate transpose kernel)
    k_gemm1<7><<<dim3(4, 8, 16), 256, 0, stream>>>(
        Sp, hvTH, nullptr, nullptr, xnH, fddT, scale,
        512, 1024, 1024, 1024, sS, sXn, sXn);

    // 9) corr = fdd @ fddT^T -> fp32 into S
    k_gemm1<0><<<dim3(8, 8, 16), 256, 0, stream>>>(
        xnH, fddT, nullptr, S, nullptr, nullptr, nullptr,
        1024, 512, 512, 512, sXn, sXn, sS);

    // 10) top-48 desc + relu (wave-per-row)
    k_topk<<<B_ * HW_ / 4, 256, 0, stream>>>(S, topv);

    // 11) norm over (B,H) + output transpose
    k_colss<<<W_ * T_, 64, 0, stream>>>(topv, colss);
    k_final<<<(B_ * T_ * HW_ + 255) / 256, 256, 0, stream>>>(topv, colss, out);
}

// Round 14
// 184.960 us; speedup vs baseline: 1.2051x; 1.0074x over previous
//
#include <hip/hip_runtime.h>
#include <cstdint>
#include <cstddef>

#define B_   16
#define C_   512
#define H_   32
#define W_   32
#define HW_  1024
#define TC_  64
#define T_   48

typedef unsigned short u16;
typedef __attribute__((ext_vector_type(8))) short short8v;
typedef __attribute__((ext_vector_type(4))) float f32x4;

// ---------------------------------------------------------------------------
// bf16 helpers
// ---------------------------------------------------------------------------
__device__ __forceinline__ u16 tobf(float x) {
    unsigned u = __float_as_uint(x);
    return (u16)((u + 0x7FFFu + ((u >> 16) & 1u)) >> 16);    // RTNE
}
__device__ __forceinline__ float frombf(u16 h) {
    return __uint_as_float(((unsigned)h) << 16);
}

__device__ __forceinline__ void gld16(const void* g, void* l) {
    __builtin_amdgcn_global_load_lds(
        (const __attribute__((address_space(1))) void*)g,
        (__attribute__((address_space(3))) void*)l, 16, 0, 0);
}

// ---------------------------------------------------------------------------
// 1) Frobenius-norm helpers
// ---------------------------------------------------------------------------
__global__ void k_colsq(const float* __restrict__ x, float* __restrict__ partial) {
    int bid = blockIdx.x;
    int col = (bid & 3) * 256 + threadIdx.x;
    int r0  = (bid >> 2) * 128;
    const float* p = x + (size_t)r0 * HW_ + col;
    float s = 0.f;
    for (int r = 0; r < 128; ++r) { float v = p[(size_t)r * HW_]; s += v * v; }
    partial[(size_t)(bid >> 2) * HW_ + col] = s;
}

__global__ void k_rsqrt(const float* __restrict__ partial, float* __restrict__ ninv) {
    int i = blockIdx.x * 256 + threadIdx.x;
    if (i < HW_) {
        float s = 0.f;
        for (int r = 0; r < 64; ++r) s += partial[(size_t)r * HW_ + i];
        ninv[i] = rsqrtf(s);
    }
}

// ---------------------------------------------------------------------------
// 2) transpose + normalize: x [B,C,HW] -> xnH bf16 [B,HW,C]
// ---------------------------------------------------------------------------
__global__ void k_transpose(const float* __restrict__ x, const float* __restrict__ ninv,
                            u16* __restrict__ obH) {
    __shared__ float tile[32][33];
    int b  = blockIdx.z;
    int m0 = blockIdx.x * 32, c0 = blockIdx.y * 32;
    int tx = threadIdx.x, ty = threadIdx.y;
    const float* xb = x + (size_t)b * C_ * HW_;
    #pragma unroll
    for (int j = 0; j < 32; j += 8)
        tile[ty + j][tx] = xb[(size_t)(c0 + ty + j) * HW_ + m0 + tx];
    __syncthreads();
    size_t base = (size_t)b * HW_ * C_;
    #pragma unroll
    for (int j = 0; j < 32; j += 8) {
        int m = m0 + ty + j;
        obH[base + (size_t)m * C_ + c0 + tx] = tobf(tile[tx][ty + j] * ninv[m]);
    }
}

// ---------------------------------------------------------------------------
// 3) weight prep (hi plane only)
// ---------------------------------------------------------------------------
__global__ void k_packW(const float* __restrict__ in, u16* __restrict__ oh) {
    size_t i = (size_t)blockIdx.x * 256 + threadIdx.x;
    oh[i] = tobf(in[i]);
}
__global__ void k_packFG(const float* __restrict__ fW, const float* __restrict__ gW,
                         const float* __restrict__ fb, const float* __restrict__ gb,
                         u16* __restrict__ oh, float* __restrict__ fgb) {
    int idx = blockIdx.x * 256 + threadIdx.x;   // 65536
    int row = idx >> 9, c = idx & 511;
    float v = (row < 64) ? fW[row * 512 + c] : gW[(row - 64) * 512 + c];
    oh[idx] = tobf(v);
    if (idx < 128) fgb[idx] = (idx < 64) ? fb[idx] : gb[idx - 64];
}

// ---------------------------------------------------------------------------
// 4) 1-term bf16 MFMA GEMM, 128x128, 4 waves, 2-buffer counted-vmcnt (r9) +
//    XCD swizzle (r12). LDS 36 KB (staging 32 KB; EPI7 reuses as TL[256][72]).
//    EPI 4: Ch = bf16(acc)                      (corr bf16 out)
//    EPI 5: Ch = bf16(acc + bias[row])
//    EPI 6: Ch = bf16(acc + bias[col])
//    EPI 7: PV: Ch = bf16(scale*acc + frombf(Ch)) in place over xn, AND
//           transposed flat-view write to Ct (fddT[c][r]) via LDS bounce.
// ---------------------------------------------------------------------------
template<int EPI>
__global__ __launch_bounds__(256) void k_gemm1(
    const u16* __restrict__ A, const u16* __restrict__ Bm,
    const float* __restrict__ bias,
    float* __restrict__ Cf, u16* __restrict__ Ch, u16* __restrict__ Ct,
    const float* __restrict__ scaleP,
    int N, int K, int lda, int ldb, long sA, long sB, long sC)
{
    __shared__ u16 lds[18432];     // 2 x 8192 staging; EPI7: TL[256][72]
    // T1 XCD swizzle (all grids %8 == 0)
    const int gx = gridDim.x, gy = gridDim.y, gz = gridDim.z;
    int bidl = blockIdx.x + gx * (blockIdx.y + gy * blockIdx.z);
    int nwg = gx * gy * gz;
    int sw = (bidl & 7) * (nwg >> 3) + (bidl >> 3);
    int gxy = gx * gy;
    int bz = sw / gxy, rem = sw - bz * gxy;
    int by = rem / gx, bx = rem - by * gx;

    const int b = bz;
    const u16* pA = A + (size_t)b * sA;
    const u16* pB = Bm + (size_t)b * sB;
    const int m0 = by * 128, n0 = bx * 128;
    const int tid = threadIdx.x, wave = tid >> 6, lane = tid & 63;
    const int wm = wave >> 1, wn = wave & 1;
    const int g = lane >> 4;

    f32x4 acc[4][4];
    #pragma unroll
    for (int i = 0; i < 4; ++i)
        #pragma unroll
        for (int j = 0; j < 4; ++j) { f32x4 z = {0.f,0.f,0.f,0.f}; acc[i][j] = z; }

    auto STAGE = [&](int kt, int buf) {
        const int k0 = kt << 5;
        u16* lb = lds + buf * 8192;
        #pragma unroll
        for (int q = 0; q < 4; ++q) {
            int ci = wave * 4 + q;
            bool isA = ci < 8;
            int li = ci & 7;
            const u16* gp = isA ? pA : pB;
            int ld = isA ? lda : ldb;
            int rb = isA ? m0 : n0;
            int rp = li * 8 + (lane >> 3);
            int gg = (lane & 7) ^ (rp & 7);
            int r  = rp * 2 + (gg >> 2);
            int kc = k0 + (gg & 3) * 8;
            gld16(gp + (size_t)(rb + r) * ld + kc,
                  lb + (isA ? 0 : 4096) + li * 512 + lane * 8);
        }
    };
    auto COMPUTE = [&](int buf) {
        const u16* As = lds + buf * 8192;
        const u16* Bs = As + 4096;
        short8v av[4];
        #pragma unroll
        for (int i = 0; i < 4; ++i) {
            int r = wm * 64 + i * 16 + (lane & 15);
            int rp = r >> 1, gg = ((r & 1) << 2) + g;
            av[i] = *(const short8v*)(As + rp * 64 + ((gg ^ (rp & 7)) << 3));
        }
        #pragma unroll
        for (int j = 0; j < 4; ++j) {
            int r = wn * 64 + j * 16 + (lane & 15);
            int rp = r >> 1, gg = ((r & 1) << 2) + g;
            short8v bv = *(const short8v*)(Bs + rp * 64 + ((gg ^ (rp & 7)) << 3));
            #pragma unroll
            for (int i = 0; i < 4; ++i)
                acc[i][j] = __builtin_amdgcn_mfma_f32_16x16x32_bf16(av[i], bv, acc[i][j], 0, 0, 0);
        }
    };

    const int nkt = K >> 5;
    STAGE(0, 0);
    int cur = 0;
    for (int kt = 0; kt < nkt; ++kt) {
        if (kt + 1 < nkt) {
            STAGE(kt + 1, cur ^ 1);
            asm volatile("s_waitcnt vmcnt(4)" ::: "memory");
        } else {
            asm volatile("s_waitcnt vmcnt(0)" ::: "memory");
        }
        __builtin_amdgcn_s_barrier();
        __builtin_amdgcn_sched_barrier(0);
        COMPUTE(cur);
        __builtin_amdgcn_sched_barrier(0);
        __builtin_amdgcn_s_barrier();
        cur ^= 1;
    }

    const float sc = (EPI == 7) ? scaleP[0] : 0.f;
    const int colbase = n0 + wn * 64 + (lane & 15);
    const int rowbase = m0 + wm * 64 + ((lane >> 4) << 2);
    #pragma unroll
    for (int i = 0; i < 4; ++i)
        #pragma unroll
        for (int j = 0; j < 4; ++j) {
            int col = colbase + j * 16;
            #pragma unroll
            for (int rg = 0; rg < 4; ++rg) {
                int row = rowbase + i * 16 + rg;
                size_t idx = (size_t)b * sC + (size_t)row * N + col;
                float a = acc[i][j][rg];
                if (EPI == 4)      Ch[idx] = tobf(a);
                else if (EPI == 5) Ch[idx] = tobf(a + bias[row]);
                else if (EPI == 6) Ch[idx] = tobf(a + bias[col]);
                else {             // EPI == 7
                    u16 v = tobf(sc * a + frombf(Ch[idx]));
                    Ch[idx] = v;
                    int lr = row - m0, lc = col - n0;
                    lds[(size_t)((lr & 1) * 128 + lc) * 72 + (lr >> 1)] = v;
                }
            }
        }

    if (EPI == 7) {
        __syncthreads();
        #pragma unroll
        for (int it = 0; it < 8; ++it) {
            int task = it * 256 + tid;
            int tc = task >> 3, ch = task & 7;
            short8v v = *(const short8v*)(lds + tc * 72 + ch * 8);
            int cg = ((tc >> 7) ? 512 : 0) + n0 + (tc & 127);
            *(short8v*)(Ct + (size_t)b * 524288 + (size_t)cg * 512 + (m0 >> 1) + ch * 8) = v;
        }
    }
}

// ---------------------------------------------------------------------------
// 5) FUSED S-GEMM + row softmax -> P bf16 (verified r12/r13)
// ---------------------------------------------------------------------------
__global__ __launch_bounds__(512) void k_ssoft(
    const u16* __restrict__ fg,   // [B][1024][128] (cols 0-63 f, 64-127 g)
    u16* __restrict__ P)          // [B][1024][1024]
{
    __shared__ u16 lds[69632];
    __shared__ float red[512];
    __shared__ float rowm[64];
    __shared__ float rinv[64];

    const int b = blockIdx.y;
    const int m0 = blockIdx.x * 64;
    const u16* fgb = fg + (size_t)b * 131072;
    const int tid = threadIdx.x, wave = tid >> 6, lane = tid & 63;
    const int wn = wave;
    const int g = lane >> 4;

    #pragma unroll
    for (int kc = 0; kc < 2; ++kc) {
        #pragma unroll
        for (int q = 0; q < 8; ++q) {
            int li = wave * 8 + q;
            int rp = li * 8 + (lane >> 3);
            int gg = (lane & 7) ^ (rp & 7);
            int r  = rp * 2 + (gg >> 2);
            int n2 = ((r & 31) << 5) | (r >> 5);
            int kcol = 64 + kc * 32 + (gg & 3) * 8;
            gld16(fgb + (size_t)n2 * 128 + kcol,
                  lds + 4096 + kc * 32768 + li * 512 + lane * 8);
        }
        if (lane < 32) {
            int rp = wave * 4 + (lane >> 3);
            int gg = (lane & 7) ^ (rp & 7);
            int r  = rp * 2 + (gg >> 2);
            int kcol = kc * 32 + (gg & 3) * 8;
            gld16(fgb + (size_t)(m0 + r) * 128 + kcol,
                  lds + kc * 2048 + wave * 256 + lane * 8);
        }
    }
    __syncthreads();

    f32x4 acc[4][8];
    #pragma unroll
    for (int i = 0; i < 4; ++i)
        #pragma unroll
        for (int j = 0; j < 8; ++j) { f32x4 z = {0.f,0.f,0.f,0.f}; acc[i][j] = z; }

    #pragma unroll
    for (int kc = 0; kc < 2; ++kc) {
        const u16* As = lds + kc * 2048;
        const u16* Bs = lds + 4096 + kc * 32768;
        short8v av[4];
        #pragma unroll
        for (int i = 0; i < 4; ++i) {
            int r = i * 16 + (lane & 15);
            int rp = r >> 1, gg = ((r & 1) << 2) + g;
            av[i] = *(const short8v*)(As + rp * 64 + ((gg ^ (rp & 7)) << 3));
        }
        #pragma unroll
        for (int j = 0; j < 8; ++j) {
            int n = wn * 128 + j * 16 + (lane & 15);
            int rp = n >> 1, gg = ((n & 1) << 2) + g;
            short8v bv = *(const short8v*)(Bs + rp * 64 + ((gg ^ (rp & 7)) << 3));
            #pragma unroll
            for (int i = 0; i < 4; ++i)
                acc[i][j] = __builtin_amdgcn_mfma_f32_16x16x32_bf16(av[i], bv, acc[i][j], 0, 0, 0);
        }
    }

    const int rgrp = (lane >> 4) << 2;
    float pm[4][4];
    #pragma unroll
    for (int i = 0; i < 4; ++i)
        #pragma unroll
        for (int rg = 0; rg < 4; ++rg) {
            float m = acc[i][0][rg];
            #pragma unroll
            for (int j = 1; j < 8; ++j) m = fmaxf(m, acc[i][j][rg]);
            pm[i][rg] = m;
        }
    #pragma unroll
    for (int o = 1; o < 16; o <<= 1)
        #pragma unroll
        for (int i = 0; i < 4; ++i)
            #pragma unroll
            for (int rg = 0; rg < 4; ++rg)
                pm[i][rg] = fmaxf(pm[i][rg], __shfl_xor(pm[i][rg], o));
    if ((lane & 15) == 0)
        #pragma unroll
        for (int i = 0; i < 4; ++i)
            #pragma unroll
            for (int rg = 0; rg < 4; ++rg)
                red[wn * 64 + i * 16 + rgrp + rg] = pm[i][rg];
    __syncthreads();
    if (tid < 64) {
        float m = red[tid];
        #pragma unroll
        for (int w = 1; w < 8; ++w) m = fmaxf(m, red[w * 64 + tid]);
        rowm[tid] = m;
    }
    __syncthreads();

    float ps[4][4];
    #pragma unroll
    for (int i = 0; i < 4; ++i)
        #pragma unroll
        for (int rg = 0; rg < 4; ++rg) {
            float m = rowm[i * 16 + rgrp + rg];
            float s = 0.f;
            #pragma unroll
            for (int j = 0; j < 8; ++j) {
                float e = expf(acc[i][j][rg] - m);
                acc[i][j][rg] = e;
                s += e;
            }
            ps[i][rg] = s;
        }
    #pragma unroll
    for (int o = 1; o < 16; o <<= 1)
        #pragma unroll
        for (int i = 0; i < 4; ++i)
            #pragma unroll
            for (int rg = 0; rg < 4; ++rg)
                ps[i][rg] += __shfl_xor(ps[i][rg], o);
    if ((lane & 15) == 0)
        #pragma unroll
        for (int i = 0; i < 4; ++i)
            #pragma unroll
            for (int rg = 0; rg < 4; ++rg)
                red[wn * 64 + i * 16 + rgrp + rg] = ps[i][rg];
    __syncthreads();
    if (tid < 64) {
        float s = red[tid];
        #pragma unroll
        for (int w = 1; w < 8; ++w) s += red[w * 64 + tid];
        rinv[tid] = 1.f / s;
    }
    __syncthreads();

    u16* Plds = lds + 4096;
    #pragma unroll
    for (int i = 0; i < 4; ++i)
        #pragma unroll
        for (int rg = 0; rg < 4; ++rg) {
            int r = i * 16 + rgrp + rg;
            float riv = rinv[r];
            int sx = (r & 7) << 4;
            #pragma unroll
            for (int j = 0; j < 8; ++j) {
                u16 v = tobf(acc[i][j][rg] * riv);
                int col = wn * 128 + ((j * 16) ^ sx) + (lane & 15);
                Plds[r * 1024 + col] = v;
            }
        }
    __syncthreads();

    for (int it = 0; it < 16; ++it) {
        int r  = it * 4 + (tid >> 7);
        int cb = (tid & 127) * 8;
        int sx = (r & 7) << 4;
        int src = r * 1024 + (cb & ~127) + ((cb & 127) ^ sx);
        short8v v = *(const short8v*)(Plds + src);
        *(short8v*)(P + ((size_t)b * HW_ + m0 + r) * (size_t)HW_ + cb) = v;
    }
}

// ---------------------------------------------------------------------------
// 6) top-48, one WAVE per row, bf16 corr input (16 contiguous elems/lane)
// ---------------------------------------------------------------------------
__device__ __forceinline__ float sort64_desc(float v, int lane) {
    #pragma unroll
    for (int k = 2; k <= 64; k <<= 1) {
        #pragma unroll
        for (int j = k >> 1; j > 0; j >>= 1) {
            float o = __shfl_xor(v, j);
            bool takeMax = (((lane & k) == 0) == ((lane & j) == 0));
            v = takeMax ? fmaxf(v, o) : fminf(v, o);
        }
    }
    return v;
}
__device__ __forceinline__ float bmerge64_desc(float a, float b, int lane) {
    float br = __shfl(b, 63 - lane);
    float c = fmaxf(a, br);
    #pragma unroll
    for (int j = 32; j > 0; j >>= 1) {
        float o = __shfl_xor(c, j);
        c = ((lane & j) == 0) ? fmaxf(c, o) : fminf(c, o);
    }
    return c;
}

__global__ __launch_bounds__(256) void k_topk(const u16* __restrict__ corr,
                                              float* __restrict__ topv) {
    __shared__ float buf[4][1024];
    int wave = threadIdx.x >> 6, lane = threadIdx.x & 63;
    int row = blockIdx.x * 4 + wave;
    const u16* rp = corr + (size_t)row * HW_ + lane * 16;

    short8v w0 = *(const short8v*)(rp);
    short8v w1 = *(const short8v*)(rp + 8);
    float e[16];
    #pragma unroll
    for (int q = 0; q < 8; ++q) e[q]     = frombf((u16)w0[q]);
    #pragma unroll
    for (int q = 0; q < 8; ++q) e[q + 8] = frombf((u16)w1[q]);

    float gm = e[0];
    #pragma unroll
    for (int q = 1; q < 16; ++q) gm = fmaxf(gm, e[q]);
    float sorted = sort64_desc(gm, lane);
    float tau = __shfl(sorted, T_ - 1);

    int c = 0;
    #pragma unroll
    for (int q = 0; q < 16; ++q) c += (e[q] >= tau);
    int sc = c;
    #pragma unroll
    for (int o = 1; o < 64; o <<= 1) {
        int t2 = __shfl_up(sc, o);
        if (lane >= o) sc += t2;
    }
    int off = sc - c;
    int cnt = __shfl(sc, 63);                    // >= 48 guaranteed

    float* wb = buf[wave];
    #pragma unroll
    for (int q = 0; q < 16; ++q)
        if (e[q] >= tau) wb[off++] = e[q];

    float* orow = topv + (size_t)row * T_;
    if (cnt <= 64) {
        float a = (lane < cnt) ? wb[lane] : -INFINITY;
        a = sort64_desc(a, lane);
        if (lane < T_) orow[lane] = fmaxf(a, 0.f);
    } else if (cnt <= 128) {
        float a  = sort64_desc(wb[lane], lane);
        float b2 = sort64_desc((lane < cnt - 64) ? wb[64 + lane] : -INFINITY, lane);
        float m2 = bmerge64_desc(a, b2, lane);
        if (lane < T_) orow[lane] = fmaxf(m2, 0.f);
    } else {
        int P = 256; while (P < cnt) P <<= 1;
        for (int i = cnt + lane; i < P; i += 64) wb[i] = -INFINITY;
        for (int k = 2; k <= P; k <<= 1)
            for (int j = k >> 1; j > 0; j >>= 1)
                for (int t2 = lane; t2 < P; t2 += 64) {
                    int ixj = t2 ^ j;
                    if (ixj > t2) {
                        float a = wb[t2], b3 = wb[ixj];
                        bool desc = ((t2 & k) == 0);
                        if (desc ? (a < b3) : (a > b3)) { wb[t2] = b3; wb[ixj] = a; }
                    }
                }
        if (lane < T_) orow[lane] = fmaxf(wb[lane], 0.f);
    }
}

// ---------------------------------------------------------------------------
// 7) column norm over (B,H) and final transpose
// ---------------------------------------------------------------------------
__global__ void k_colss(const float* __restrict__ topv, float* __restrict__ colss) {
    int o = blockIdx.x;
    int w = o / T_, t = o % T_;
    int lane = threadIdx.x;
    float s = 0.f;
    for (int i = lane; i < 512; i += 64) {
        int b = i >> 5, h = i & 31;
        float v = topv[(size_t)((b << 10) + (h << 5) + w) * T_ + t];
        s += v * v;
    }
    for (int off = 32; off > 0; off >>= 1) s += __shfl_down(s, off);
    if (lane == 0) colss[o] = s;
}

__global__ void k_final(const float* __restrict__ topv, const float* __restrict__ colss,
                        float* __restrict__ out) {
    int idx = blockIdx.x * 256 + threadIdx.x;
    if (idx >= B_ * T_ * HW_) return;
    int w = idx & 31;
    int h = (idx >> 5) & 31;
    int t = (idx >> 10) % T_;
    int b = idx / (T_ * HW_);
    float v = topv[(size_t)((b << 10) + (h << 5) + w) * T_ + t];
    out[idx] = v * rsqrtf(colss[w * T_ + t]);
}

// ---------------------------------------------------------------------------
extern "C" void kernel_launch(void* const* d_in, const int* in_sizes, int n_in,
                              void* d_out, int out_size, void* d_ws, size_t ws_size,
                              hipStream_t stream) {
    const float* x     = (const float*)d_in[0];
    const float* fW    = (const float*)d_in[1];
    const float* fb    = (const float*)d_in[2];
    const float* gW    = (const float*)d_in[3];
    const float* gb    = (const float*)d_in[4];
    const float* hW    = (const float*)d_in[5];
    const float* hb    = (const float*)d_in[6];
    const float* scale = (const float*)d_in[7];
    float* out = (float*)d_out;

    char* wsb = (char*)d_ws;
    float* part = (float*)(wsb + 0);                 // 262144 B [64][1024]
    float* ninv = (float*)(wsb + 262144);            // 4096 B
    u16*   hWh  = (u16*)(wsb + 266240);              // 524288 B
    u16*   fgWh = (u16*)(wsb + 790528);              // 131072 B
    float* fgb  = (float*)(wsb + 921600);            // 512 B
    u16*   xnH  = (u16*)(wsb + 922112);              // 16 MB (xn -> fdd bf16)
    u16*   fgH  = (u16*)(wsb + 17699328);            // 4 MB (f|g; later topv)
    u16*   fgL  = (u16*)(wsb + 21893632);            // 4 MB (later colss)
    u16*   hvTH = (u16*)(wsb + 26087936);            // 16 MB (hv)
    float* S    = (float*)(wsb + 42865152);          // 64 MB (P u16 -> corr bf16)
    u16*   fddT = (u16*)(wsb + 109974016);           // 16 MB (fddT)
    float* topv = (float*)fgH;
    float* colss= (float*)fgL;
    u16*   Sp   = (u16*)S;

    const long sXn = 524288;    // [1024][512] elements per batch
    const long sFG = 131072;    // [1024][128]
    const long sS  = 1048576;   // [1024][1024]

    // 1) per-pixel Frobenius norm
    k_colsq<<<256, 256, 0, stream>>>(x, part);
    k_rsqrt<<<4, 256, 0, stream>>>(part, ninv);

    // 2) normalized channel-last bf16
    k_transpose<<<dim3(32, 16, 16), dim3(32, 8), 0, stream>>>(x, ninv, xnH);

    // 3) weight planes
    k_packW<<<1024, 256, 0, stream>>>(hW, hWh);
    k_packFG<<<256, 256, 0, stream>>>(fW, gW, fb, gb, fgWh, fgb);

    // 4) fg = bf16(xn @ [fW|gW]^T + bias[col])  [B,1024,128]
    k_gemm1<6><<<dim3(1, 8, 16), 256, 0, stream>>>(
        xnH, fgWh, fgb, nullptr, fgH, nullptr, nullptr,
        128, 512, 512, 512, sXn, 0, sFG);

    // 5) hv = bf16(hW @ xn^T + hb[row])  [B,512,1024]
    k_gemm1<5><<<dim3(8, 4, 16), 256, 0, stream>>>(
        hWh, xnH, hb, nullptr, hvTH, nullptr, nullptr,
        1024, 512, 512, 512, 0, sXn, sXn);

    // 6+7) fused S-GEMM + softmax -> P bf16
    k_ssoft<<<dim3(16, 16), 512, 0, stream>>>(fgH, Sp);

    // 8) fdd = bf16(scale*(P @ hv^T) + xn) in place over xnH, PLUS fddT write
    k_gemm1<7><<<dim3(4, 8, 16), 256, 0, stream>>>(
        Sp, hvTH, nullptr, nullptr, xnH, fddT, scale,
        512, 1024, 1024, 1024, sS, sXn, sXn);

    // 9) corr = bf16(fdd @ fddT^T) into S region (u16 view)
    k_gemm1<4><<<dim3(8, 8, 16), 256, 0, stream>>>(
        xnH, fddT, nullptr, nullptr, Sp, nullptr, nullptr,
        1024, 512, 512, 512, sXn, sXn, sS);

    // 10) top-48 desc + relu (wave-per-row, bf16 input)
    k_topk<<<B_ * HW_ / 4, 256, 0, stream>>>(Sp, topv);

    // 11) norm over (B,H) + output transpose
    k_colss<<<W_ * T_, 64, 0, stream>>>(topv, colss);
    k_final<<<(B_ * T_ * HW_ + 255) / 256, 256, 0, stream>>>(topv, colss, out);
}

// Round 15
// 184.066 us; speedup vs baseline: 1.2110x; 1.0049x over previous
//
#include <hip/hip_runtime.h>
#include <cstdint>
#include <cstddef>

#define B_   16
#define C_   512
#define H_   32
#define W_   32
#define HW_  1024
#define TC_  64
#define T_   48

typedef unsigned short u16;
typedef __attribute__((ext_vector_type(8))) short short8v;
typedef __attribute__((ext_vector_type(4))) float f32x4;

// ---------------------------------------------------------------------------
// bf16 helpers
// ---------------------------------------------------------------------------
__device__ __forceinline__ u16 tobf(float x) {
    unsigned u = __float_as_uint(x);
    return (u16)((u + 0x7FFFu + ((u >> 16) & 1u)) >> 16);    // RTNE
}
__device__ __forceinline__ float frombf(u16 h) {
    return __uint_as_float(((unsigned)h) << 16);
}

__device__ __forceinline__ void gld16(const void* g, void* l) {
    __builtin_amdgcn_global_load_lds(
        (const __attribute__((address_space(1))) void*)g,
        (__attribute__((address_space(3))) void*)l, 16, 0, 0);
}

// ---------------------------------------------------------------------------
// 1) Frobenius-norm helpers
// ---------------------------------------------------------------------------
__global__ void k_colsq(const float* __restrict__ x, float* __restrict__ partial) {
    int bid = blockIdx.x;
    int col = (bid & 3) * 256 + threadIdx.x;
    int r0  = (bid >> 2) * 128;
    const float* p = x + (size_t)r0 * HW_ + col;
    float s = 0.f;
    for (int r = 0; r < 128; ++r) { float v = p[(size_t)r * HW_]; s += v * v; }
    partial[(size_t)(bid >> 2) * HW_ + col] = s;
}

__global__ void k_rsqrt(const float* __restrict__ partial, float* __restrict__ ninv) {
    int i = blockIdx.x * 256 + threadIdx.x;
    if (i < HW_) {
        float s = 0.f;
        for (int r = 0; r < 64; ++r) s += partial[(size_t)r * HW_ + i];
        ninv[i] = rsqrtf(s);
    }
}

// ---------------------------------------------------------------------------
// 2) transpose + normalize: x [B,C,HW] -> xnH bf16 [B,HW,C]
// ---------------------------------------------------------------------------
__global__ void k_transpose(const float* __restrict__ x, const float* __restrict__ ninv,
                            u16* __restrict__ obH) {
    __shared__ float tile[32][33];
    int b  = blockIdx.z;
    int m0 = blockIdx.x * 32, c0 = blockIdx.y * 32;
    int tx = threadIdx.x, ty = threadIdx.y;
    const float* xb = x + (size_t)b * C_ * HW_;
    #pragma unroll
    for (int j = 0; j < 32; j += 8)
        tile[ty + j][tx] = xb[(size_t)(c0 + ty + j) * HW_ + m0 + tx];
    __syncthreads();
    size_t base = (size_t)b * HW_ * C_;
    #pragma unroll
    for (int j = 0; j < 32; j += 8) {
        int m = m0 + ty + j;
        obH[base + (size_t)m * C_ + c0 + tx] = tobf(tile[tx][ty + j] * ninv[m]);
    }
}

// ---------------------------------------------------------------------------
// 3) weight prep (hi plane only)
// ---------------------------------------------------------------------------
__global__ void k_packW(const float* __restrict__ in, u16* __restrict__ oh) {
    size_t i = (size_t)blockIdx.x * 256 + threadIdx.x;
    oh[i] = tobf(in[i]);
}
__global__ void k_packFG(const float* __restrict__ fW, const float* __restrict__ gW,
                         const float* __restrict__ fb, const float* __restrict__ gb,
                         u16* __restrict__ oh, float* __restrict__ fgb) {
    int idx = blockIdx.x * 256 + threadIdx.x;   // 65536
    int row = idx >> 9, c = idx & 511;
    float v = (row < 64) ? fW[row * 512 + c] : gW[(row - 64) * 512 + c];
    oh[idx] = tobf(v);
    if (idx < 128) fgb[idx] = (idx < 64) ? fb[idx] : gb[idx - 64];
}

// ---------------------------------------------------------------------------
// 4) 1-term bf16 MFMA GEMM, 128x128, 4 waves, 2-buffer counted-vmcnt (r9) +
//    XCD swizzle (r12) + setprio(T5) + minimal LDS (32 KB unless EPI7's
//    transpose bounce needs 36 KB).
//    EPI 4: Ch = bf16(acc)                      (corr bf16 out)
//    EPI 5: Ch = bf16(acc + bias[row])
//    EPI 6: Ch = bf16(acc + bias[col])
//    EPI 7: PV: Ch = bf16(scale*acc + frombf(Ch)) in place over xn, AND
//           transposed flat-view write to Ct (fddT[c][r]) via LDS bounce.
// ---------------------------------------------------------------------------
template<int EPI>
__global__ __launch_bounds__(256, 4) void k_gemm1(
    const u16* __restrict__ A, const u16* __restrict__ Bm,
    const float* __restrict__ bias,
    float* __restrict__ Cf, u16* __restrict__ Ch, u16* __restrict__ Ct,
    const float* __restrict__ scaleP,
    int N, int K, int lda, int ldb, long sA, long sB, long sC)
{
    __shared__ u16 lds[(EPI == 7) ? 18432 : 16384];
    // T1 XCD swizzle (all grids %8 == 0)
    const int gx = gridDim.x, gy = gridDim.y, gz = gridDim.z;
    int bidl = blockIdx.x + gx * (blockIdx.y + gy * blockIdx.z);
    int nwg = gx * gy * gz;
    int sw = (bidl & 7) * (nwg >> 3) + (bidl >> 3);
    int gxy = gx * gy;
    int bz = sw / gxy, rem = sw - bz * gxy;
    int by = rem / gx, bx = rem - by * gx;

    const int b = bz;
    const u16* pA = A + (size_t)b * sA;
    const u16* pB = Bm + (size_t)b * sB;
    const int m0 = by * 128, n0 = bx * 128;
    const int tid = threadIdx.x, wave = tid >> 6, lane = tid & 63;
    const int wm = wave >> 1, wn = wave & 1;
    const int g = lane >> 4;

    f32x4 acc[4][4];
    #pragma unroll
    for (int i = 0; i < 4; ++i)
        #pragma unroll
        for (int j = 0; j < 4; ++j) { f32x4 z = {0.f,0.f,0.f,0.f}; acc[i][j] = z; }

    auto STAGE = [&](int kt, int buf) {
        const int k0 = kt << 5;
        u16* lb = lds + buf * 8192;
        #pragma unroll
        for (int q = 0; q < 4; ++q) {
            int ci = wave * 4 + q;
            bool isA = ci < 8;
            int li = ci & 7;
            const u16* gp = isA ? pA : pB;
            int ld = isA ? lda : ldb;
            int rb = isA ? m0 : n0;
            int rp = li * 8 + (lane >> 3);
            int gg = (lane & 7) ^ (rp & 7);
            int r  = rp * 2 + (gg >> 2);
            int kc = k0 + (gg & 3) * 8;
            gld16(gp + (size_t)(rb + r) * ld + kc,
                  lb + (isA ? 0 : 4096) + li * 512 + lane * 8);
        }
    };
    auto COMPUTE = [&](int buf) {
        const u16* As = lds + buf * 8192;
        const u16* Bs = As + 4096;
        short8v av[4];
        #pragma unroll
        for (int i = 0; i < 4; ++i) {
            int r = wm * 64 + i * 16 + (lane & 15);
            int rp = r >> 1, gg = ((r & 1) << 2) + g;
            av[i] = *(const short8v*)(As + rp * 64 + ((gg ^ (rp & 7)) << 3));
        }
        __builtin_amdgcn_s_setprio(1);
        #pragma unroll
        for (int j = 0; j < 4; ++j) {
            int r = wn * 64 + j * 16 + (lane & 15);
            int rp = r >> 1, gg = ((r & 1) << 2) + g;
            short8v bv = *(const short8v*)(Bs + rp * 64 + ((gg ^ (rp & 7)) << 3));
            #pragma unroll
            for (int i = 0; i < 4; ++i)
                acc[i][j] = __builtin_amdgcn_mfma_f32_16x16x32_bf16(av[i], bv, acc[i][j], 0, 0, 0);
        }
        __builtin_amdgcn_s_setprio(0);
    };

    const int nkt = K >> 5;
    STAGE(0, 0);
    int cur = 0;
    for (int kt = 0; kt < nkt; ++kt) {
        if (kt + 1 < nkt) {
            STAGE(kt + 1, cur ^ 1);
            asm volatile("s_waitcnt vmcnt(4)" ::: "memory");
        } else {
            asm volatile("s_waitcnt vmcnt(0)" ::: "memory");
        }
        __builtin_amdgcn_s_barrier();
        __builtin_amdgcn_sched_barrier(0);
        COMPUTE(cur);
        __builtin_amdgcn_sched_barrier(0);
        __builtin_amdgcn_s_barrier();
        cur ^= 1;
    }

    const float sc = (EPI == 7) ? scaleP[0] : 0.f;
    const int colbase = n0 + wn * 64 + (lane & 15);
    const int rowbase = m0 + wm * 64 + ((lane >> 4) << 2);
    #pragma unroll
    for (int i = 0; i < 4; ++i)
        #pragma unroll
        for (int j = 0; j < 4; ++j) {
            int col = colbase + j * 16;
            #pragma unroll
            for (int rg = 0; rg < 4; ++rg) {
                int row = rowbase + i * 16 + rg;
                size_t idx = (size_t)b * sC + (size_t)row * N + col;
                float a = acc[i][j][rg];
                if (EPI == 4)      Ch[idx] = tobf(a);
                else if (EPI == 5) Ch[idx] = tobf(a + bias[row]);
                else if (EPI == 6) Ch[idx] = tobf(a + bias[col]);
                else {             // EPI == 7
                    u16 v = tobf(sc * a + frombf(Ch[idx]));
                    Ch[idx] = v;
                    int lr = row - m0, lc = col - n0;
                    lds[(size_t)((lr & 1) * 128 + lc) * 72 + (lr >> 1)] = v;
                }
            }
        }

    if (EPI == 7) {
        __syncthreads();
        #pragma unroll
        for (int it = 0; it < 8; ++it) {
            int task = it * 256 + tid;
            int tc = task >> 3, ch = task & 7;
            short8v v = *(const short8v*)(lds + tc * 72 + ch * 8);
            int cg = ((tc >> 7) ? 512 : 0) + n0 + (tc & 127);
            *(short8v*)(Ct + (size_t)b * 524288 + (size_t)cg * 512 + (m0 >> 1) + ch * 8) = v;
        }
    }
}

// ---------------------------------------------------------------------------
// 5) FUSED S-GEMM + row softmax -> P bf16 (verified r12/r13)
// ---------------------------------------------------------------------------
__global__ __launch_bounds__(512) void k_ssoft(
    const u16* __restrict__ fg,   // [B][1024][128] (cols 0-63 f, 64-127 g)
    u16* __restrict__ P)          // [B][1024][1024]
{
    __shared__ u16 lds[69632];
    __shared__ float red[512];
    __shared__ float rowm[64];
    __shared__ float rinv[64];

    const int b = blockIdx.y;
    const int m0 = blockIdx.x * 64;
    const u16* fgb = fg + (size_t)b * 131072;
    const int tid = threadIdx.x, wave = tid >> 6, lane = tid & 63;
    const int wn = wave;
    const int g = lane >> 4;

    #pragma unroll
    for (int kc = 0; kc < 2; ++kc) {
        #pragma unroll
        for (int q = 0; q < 8; ++q) {
            int li = wave * 8 + q;
            int rp = li * 8 + (lane >> 3);
            int gg = (lane & 7) ^ (rp & 7);
            int r  = rp * 2 + (gg >> 2);
            int n2 = ((r & 31) << 5) | (r >> 5);
            int kcol = 64 + kc * 32 + (gg & 3) * 8;
            gld16(fgb + (size_t)n2 * 128 + kcol,
                  lds + 4096 + kc * 32768 + li * 512 + lane * 8);
        }
        if (lane < 32) {
            int rp = wave * 4 + (lane >> 3);
            int gg = (lane & 7) ^ (rp & 7);
            int r  = rp * 2 + (gg >> 2);
            int kcol = kc * 32 + (gg & 3) * 8;
            gld16(fgb + (size_t)(m0 + r) * 128 + kcol,
                  lds + kc * 2048 + wave * 256 + lane * 8);
        }
    }
    __syncthreads();

    f32x4 acc[4][8];
    #pragma unroll
    for (int i = 0; i < 4; ++i)
        #pragma unroll
        for (int j = 0; j < 8; ++j) { f32x4 z = {0.f,0.f,0.f,0.f}; acc[i][j] = z; }

    #pragma unroll
    for (int kc = 0; kc < 2; ++kc) {
        const u16* As = lds + kc * 2048;
        const u16* Bs = lds + 4096 + kc * 32768;
        short8v av[4];
        #pragma unroll
        for (int i = 0; i < 4; ++i) {
            int r = i * 16 + (lane & 15);
            int rp = r >> 1, gg = ((r & 1) << 2) + g;
            av[i] = *(const short8v*)(As + rp * 64 + ((gg ^ (rp & 7)) << 3));
        }
        #pragma unroll
        for (int j = 0; j < 8; ++j) {
            int n = wn * 128 + j * 16 + (lane & 15);
            int rp = n >> 1, gg = ((n & 1) << 2) + g;
            short8v bv = *(const short8v*)(Bs + rp * 64 + ((gg ^ (rp & 7)) << 3));
            #pragma unroll
            for (int i = 0; i < 4; ++i)
                acc[i][j] = __builtin_amdgcn_mfma_f32_16x16x32_bf16(av[i], bv, acc[i][j], 0, 0, 0);
        }
    }

    const int rgrp = (lane >> 4) << 2;
    float pm[4][4];
    #pragma unroll
    for (int i = 0; i < 4; ++i)
        #pragma unroll
        for (int rg = 0; rg < 4; ++rg) {
            float m = acc[i][0][rg];
            #pragma unroll
            for (int j = 1; j < 8; ++j) m = fmaxf(m, acc[i][j][rg]);
            pm[i][rg] = m;
        }
    #pragma unroll
    for (int o = 1; o < 16; o <<= 1)
        #pragma unroll
        for (int i = 0; i < 4; ++i)
            #pragma unroll
            for (int rg = 0; rg < 4; ++rg)
                pm[i][rg] = fmaxf(pm[i][rg], __shfl_xor(pm[i][rg], o));
    if ((lane & 15) == 0)
        #pragma unroll
        for (int i = 0; i < 4; ++i)
            #pragma unroll
            for (int rg = 0; rg < 4; ++rg)
                red[wn * 64 + i * 16 + rgrp + rg] = pm[i][rg];
    __syncthreads();
    if (tid < 64) {
        float m = red[tid];
        #pragma unroll
        for (int w = 1; w < 8; ++w) m = fmaxf(m, red[w * 64 + tid]);
        rowm[tid] = m;
    }
    __syncthreads();

    float ps[4][4];
    #pragma unroll
    for (int i = 0; i < 4; ++i)
        #pragma unroll
        for (int rg = 0; rg < 4; ++rg) {
            float m = rowm[i * 16 + rgrp + rg];
            float s = 0.f;
            #pragma unroll
            for (int j = 0; j < 8; ++j) {
                float e = expf(acc[i][j][rg] - m);
                acc[i][j][rg] = e;
                s += e;
            }
            ps[i][rg] = s;
        }
    #pragma unroll
    for (int o = 1; o < 16; o <<= 1)
        #pragma unroll
        for (int i = 0; i < 4; ++i)
            #pragma unroll
            for (int rg = 0; rg < 4; ++rg)
                ps[i][rg] += __shfl_xor(ps[i][rg], o);
    if ((lane & 15) == 0)
        #pragma unroll
        for (int i = 0; i < 4; ++i)
            #pragma unroll
            for (int rg = 0; rg < 4; ++rg)
                red[wn * 64 + i * 16 + rgrp + rg] = ps[i][rg];
    __syncthreads();
    if (tid < 64) {
        float s = red[tid];
        #pragma unroll
        for (int w = 1; w < 8; ++w) s += red[w * 64 + tid];
        rinv[tid] = 1.f / s;
    }
    __syncthreads();

    u16* Plds = lds + 4096;
    #pragma unroll
    for (int i = 0; i < 4; ++i)
        #pragma unroll
        for (int rg = 0; rg < 4; ++rg) {
            int r = i * 16 + rgrp + rg;
            float riv = rinv[r];
            int sx = (r & 7) << 4;
            #pragma unroll
            for (int j = 0; j < 8; ++j) {
                u16 v = tobf(acc[i][j][rg] * riv);
                int col = wn * 128 + ((j * 16) ^ sx) + (lane & 15);
                Plds[r * 1024 + col] = v;
            }
        }
    __syncthreads();

    for (int it = 0; it < 16; ++it) {
        int r  = it * 4 + (tid >> 7);
        int cb = (tid & 127) * 8;
        int sx = (r & 7) << 4;
        int src = r * 1024 + (cb & ~127) + ((cb & 127) ^ sx);
        short8v v = *(const short8v*)(Plds + src);
        *(short8v*)(P + ((size_t)b * HW_ + m0 + r) * (size_t)HW_ + cb) = v;
    }
}

// ---------------------------------------------------------------------------
// 6) top-48, one WAVE per row, bf16 corr input (verified r14)
// ---------------------------------------------------------------------------
__device__ __forceinline__ float sort64_desc(float v, int lane) {
    #pragma unroll
    for (int k = 2; k <= 64; k <<= 1) {
        #pragma unroll
        for (int j = k >> 1; j > 0; j >>= 1) {
            float o = __shfl_xor(v, j);
            bool takeMax = (((lane & k) == 0) == ((lane & j) == 0));
            v = takeMax ? fmaxf(v, o) : fminf(v, o);
        }
    }
    return v;
}
__device__ __forceinline__ float bmerge64_desc(float a, float b, int lane) {
    float br = __shfl(b, 63 - lane);
    float c = fmaxf(a, br);
    #pragma unroll
    for (int j = 32; j > 0; j >>= 1) {
        float o = __shfl_xor(c, j);
        c = ((lane & j) == 0) ? fmaxf(c, o) : fminf(c, o);
    }
    return c;
}

__global__ __launch_bounds__(256) void k_topk(const u16* __restrict__ corr,
                                              float* __restrict__ topv) {
    __shared__ float buf[4][1024];
    int wave = threadIdx.x >> 6, lane = threadIdx.x & 63;
    int row = blockIdx.x * 4 + wave;
    const u16* rp = corr + (size_t)row * HW_ + lane * 16;

    short8v w0 = *(const short8v*)(rp);
    short8v w1 = *(const short8v*)(rp + 8);
    float e[16];
    #pragma unroll
    for (int q = 0; q < 8; ++q) e[q]     = frombf((u16)w0[q]);
    #pragma unroll
    for (int q = 0; q < 8; ++q) e[q + 8] = frombf((u16)w1[q]);

    float gm = e[0];
    #pragma unroll
    for (int q = 1; q < 16; ++q) gm = fmaxf(gm, e[q]);
    float sorted = sort64_desc(gm, lane);
    float tau = __shfl(sorted, T_ - 1);

    int c = 0;
    #pragma unroll
    for (int q = 0; q < 16; ++q) c += (e[q] >= tau);
    int sc = c;
    #pragma unroll
    for (int o = 1; o < 64; o <<= 1) {
        int t2 = __shfl_up(sc, o);
        if (lane >= o) sc += t2;
    }
    int off = sc - c;
    int cnt = __shfl(sc, 63);                    // >= 48 guaranteed

    float* wb = buf[wave];
    #pragma unroll
    for (int q = 0; q < 16; ++q)
        if (e[q] >= tau) wb[off++] = e[q];

    float* orow = topv + (size_t)row * T_;
    if (cnt <= 64) {
        float a = (lane < cnt) ? wb[lane] : -INFINITY;
        a = sort64_desc(a, lane);
        if (lane < T_) orow[lane] = fmaxf(a, 0.f);
    } else if (cnt <= 128) {
        float a  = sort64_desc(wb[lane], lane);
        float b2 = sort64_desc((lane < cnt - 64) ? wb[64 + lane] : -INFINITY, lane);
        float m2 = bmerge64_desc(a, b2, lane);
        if (lane < T_) orow[lane] = fmaxf(m2, 0.f);
    } else {
        int P = 256; while (P < cnt) P <<= 1;
        for (int i = cnt + lane; i < P; i += 64) wb[i] = -INFINITY;
        for (int k = 2; k <= P; k <<= 1)
            for (int j = k >> 1; j > 0; j >>= 1)
                for (int t2 = lane; t2 < P; t2 += 64) {
                    int ixj = t2 ^ j;
                    if (ixj > t2) {
                        float a = wb[t2], b3 = wb[ixj];
                        bool desc = ((t2 & k) == 0);
                        if (desc ? (a < b3) : (a > b3)) { wb[t2] = b3; wb[ixj] = a; }
                    }
                }
        if (lane < T_) orow[lane] = fmaxf(wb[lane], 0.f);
    }
}

// ---------------------------------------------------------------------------
// 7) column norm over (B,H) and final transpose
// ---------------------------------------------------------------------------
__global__ void k_colss(const float* __restrict__ topv, float* __restrict__ colss) {
    int o = blockIdx.x;
    int w = o / T_, t = o % T_;
    int lane = threadIdx.x;
    float s = 0.f;
    for (int i = lane; i < 512; i += 64) {
        int b = i >> 5, h = i & 31;
        float v = topv[(size_t)((b << 10) + (h << 5) + w) * T_ + t];
        s += v * v;
    }
    for (int off = 32; off > 0; off >>= 1) s += __shfl_down(s, off);
    if (lane == 0) colss[o] = s;
}

__global__ void k_final(const float* __restrict__ topv, const float* __restrict__ colss,
                        float* __restrict__ out) {
    int idx = blockIdx.x * 256 + threadIdx.x;
    if (idx >= B_ * T_ * HW_) return;
    int w = idx & 31;
    int h = (idx >> 5) & 31;
    int t = (idx >> 10) % T_;
    int b = idx / (T_ * HW_);
    float v = topv[(size_t)((b << 10) + (h << 5) + w) * T_ + t];
    out[idx] = v * rsqrtf(colss[w * T_ + t]);
}

// ---------------------------------------------------------------------------
extern "C" void kernel_launch(void* const* d_in, const int* in_sizes, int n_in,
                              void* d_out, int out_size, void* d_ws, size_t ws_size,
                              hipStream_t stream) {
    const float* x     = (const float*)d_in[0];
    const float* fW    = (const float*)d_in[1];
    const float* fb    = (const float*)d_in[2];
    const float* gW    = (const float*)d_in[3];
    const float* gb    = (const float*)d_in[4];
    const float* hW    = (const float*)d_in[5];
    const float* hb    = (const float*)d_in[6];
    const float* scale = (const float*)d_in[7];
    float* out = (float*)d_out;

    char* wsb = (char*)d_ws;
    float* part = (float*)(wsb + 0);                 // 262144 B [64][1024]
    float* ninv = (float*)(wsb + 262144);            // 4096 B
    u16*   hWh  = (u16*)(wsb + 266240);              // 524288 B
    u16*   fgWh = (u16*)(wsb + 790528);              // 131072 B
    float* fgb  = (float*)(wsb + 921600);            // 512 B
    u16*   xnH  = (u16*)(wsb + 922112);              // 16 MB (xn -> fdd bf16)
    u16*   fgH  = (u16*)(wsb + 17699328);            // 4 MB (f|g; later topv)
    u16*   fgL  = (u16*)(wsb + 21893632);            // 4 MB (later colss)
    u16*   hvTH = (u16*)(wsb + 26087936);            // 16 MB (hv)
    float* S    = (float*)(wsb + 42865152);          // 64 MB (P u16 -> corr bf16)
    u16*   fddT = (u16*)(wsb + 109974016);           // 16 MB (fddT)
    float* topv = (float*)fgH;
    float* colss= (float*)fgL;
    u16*   Sp   = (u16*)S;

    const long sXn = 524288;    // [1024][512] elements per batch
    const long sFG = 131072;    // [1024][128]
    const long sS  = 1048576;   // [1024][1024]

    // 1) per-pixel Frobenius norm
    k_colsq<<<256, 256, 0, stream>>>(x, part);
    k_rsqrt<<<4, 256, 0, stream>>>(part, ninv);

    // 2) normalized channel-last bf16
    k_transpose<<<dim3(32, 16, 16), dim3(32, 8), 0, stream>>>(x, ninv, xnH);

    // 3) weight planes
    k_packW<<<1024, 256, 0, stream>>>(hW, hWh);
    k_packFG<<<256, 256, 0, stream>>>(fW, gW, fb, gb, fgWh, fgb);

    // 4) fg = bf16(xn @ [fW|gW]^T + bias[col])  [B,1024,128]
    k_gemm1<6><<<dim3(1, 8, 16), 256, 0, stream>>>(
        xnH, fgWh, fgb, nullptr, fgH, nullptr, nullptr,
        128, 512, 512, 512, sXn, 0, sFG);

    // 5) hv = bf16(hW @ xn^T + hb[row])  [B,512,1024]
    k_gemm1<5><<<dim3(8, 4, 16), 256, 0, stream>>>(
        hWh, xnH, hb, nullptr, hvTH, nullptr, nullptr,
        1024, 512, 512, 512, 0, sXn, sXn);

    // 6+7) fused S-GEMM + softmax -> P bf16
    k_ssoft<<<dim3(16, 16), 512, 0, stream>>>(fgH, Sp);

    // 8) fdd = bf16(scale*(P @ hv^T) + xn) in place over xnH, PLUS fddT write
    k_gemm1<7><<<dim3(4, 8, 16), 256, 0, stream>>>(
        Sp, hvTH, nullptr, nullptr, xnH, fddT, scale,
        512, 1024, 1024, 1024, sS, sXn, sXn);

    // 9) corr = bf16(fdd @ fddT^T) into S region (u16 view)
    k_gemm1<4><<<dim3(8, 8, 16), 256, 0, stream>>>(
        xnH, fddT, nullptr, nullptr, Sp, nullptr, nullptr,
        1024, 512, 512, 512, sXn, sXn, sS);

    // 10) top-48 desc + relu (wave-per-row, bf16 input)
    k_topk<<<B_ * HW_ / 4, 256, 0, stream>>>(Sp, topv);

    // 11) norm over (B,H) + output transpose
    k_colss<<<W_ * T_, 64, 0, stream>>>(topv, colss);
    k_final<<<(B_ * T_ * HW_ + 255) / 256, 256, 0, stream>>>(topv, colss, out);
}

// Round 16
// 179.752 us; speedup vs baseline: 1.2401x; 1.0240x over previous
//
#include <hip/hip_runtime.h>
#include <cstdint>
#include <cstddef>

#define B_   16
#define C_   512
#define H_   32
#define W_   32
#define HW_  1024
#define TC_  64
#define T_   48

typedef unsigned short u16;
typedef __attribute__((ext_vector_type(8))) short short8v;
typedef __attribute__((ext_vector_type(4))) float f32x4;

// ---------------------------------------------------------------------------
// bf16 helpers
// ---------------------------------------------------------------------------
__device__ __forceinline__ u16 tobf(float x) {
    unsigned u = __float_as_uint(x);
    return (u16)((u + 0x7FFFu + ((u >> 16) & 1u)) >> 16);    // RTNE
}
__device__ __forceinline__ float frombf(u16 h) {
    return __uint_as_float(((unsigned)h) << 16);
}

__device__ __forceinline__ void gld16(const void* g, void* l) {
    __builtin_amdgcn_global_load_lds(
        (const __attribute__((address_space(1))) void*)g,
        (__attribute__((address_space(3))) void*)l, 16, 0, 0);
}

// ---------------------------------------------------------------------------
// 1) Frobenius-norm helpers
// ---------------------------------------------------------------------------
__global__ void k_colsq(const float* __restrict__ x, float* __restrict__ partial) {
    int bid = blockIdx.x;
    int col = (bid & 3) * 256 + threadIdx.x;
    int r0  = (bid >> 2) * 128;
    const float* p = x + (size_t)r0 * HW_ + col;
    float s = 0.f;
    for (int r = 0; r < 128; ++r) { float v = p[(size_t)r * HW_]; s += v * v; }
    partial[(size_t)(bid >> 2) * HW_ + col] = s;
}

__global__ void k_rsqrt(const float* __restrict__ partial, float* __restrict__ ninv) {
    int i = blockIdx.x * 256 + threadIdx.x;
    if (i < HW_) {
        float s = 0.f;
        for (int r = 0; r < 64; ++r) s += partial[(size_t)r * HW_ + i];
        ninv[i] = rsqrtf(s);
    }
}

// ---------------------------------------------------------------------------
// 2) transpose + normalize: x [B,C,HW] -> xnH bf16 [B,HW,C]
// ---------------------------------------------------------------------------
__global__ void k_transpose(const float* __restrict__ x, const float* __restrict__ ninv,
                            u16* __restrict__ obH) {
    __shared__ float tile[32][33];
    int b  = blockIdx.z;
    int m0 = blockIdx.x * 32, c0 = blockIdx.y * 32;
    int tx = threadIdx.x, ty = threadIdx.y;
    const float* xb = x + (size_t)b * C_ * HW_;
    #pragma unroll
    for (int j = 0; j < 32; j += 8)
        tile[ty + j][tx] = xb[(size_t)(c0 + ty + j) * HW_ + m0 + tx];
    __syncthreads();
    size_t base = (size_t)b * HW_ * C_;
    #pragma unroll
    for (int j = 0; j < 32; j += 8) {
        int m = m0 + ty + j;
        obH[base + (size_t)m * C_ + c0 + tx] = tobf(tile[tx][ty + j] * ninv[m]);
    }
}

// ---------------------------------------------------------------------------
// 3) weight prep (hi plane only)
// ---------------------------------------------------------------------------
__global__ void k_packW(const float* __restrict__ in, u16* __restrict__ oh) {
    size_t i = (size_t)blockIdx.x * 256 + threadIdx.x;
    oh[i] = tobf(in[i]);
}
__global__ void k_packFG(const float* __restrict__ fW, const float* __restrict__ gW,
                         const float* __restrict__ fb, const float* __restrict__ gb,
                         u16* __restrict__ oh, float* __restrict__ fgb) {
    int idx = blockIdx.x * 256 + threadIdx.x;   // 65536
    int row = idx >> 9, c = idx & 511;
    float v = (row < 64) ? fW[row * 512 + c] : gW[(row - 64) * 512 + c];
    oh[idx] = tobf(v);
    if (idx < 128) fgb[idx] = (idx < 64) ? fb[idx] : gb[idx - 64];
}

// ---------------------------------------------------------------------------
// 4) 1-term bf16 MFMA GEMM, 128x128, 4 waves, 2-buffer counted-vmcnt (r9) +
//    XCD swizzle (r12) + KU k-tiles per phase (KU=2 for grid-limited GEMMs:
//    halves barriers, doubles MFMA/phase; 64 KB LDS is free at <=2 blocks/CU).
//    Layout per buffer: KU consecutive verified BK=32 sub-tiles.
//    EPI 4: Ch = bf16(acc)                      (corr bf16 out)
//    EPI 5: Ch = bf16(acc + bias[row])
//    EPI 6: Ch = bf16(acc + bias[col])
//    EPI 7: PV: Ch = bf16(scale*acc + frombf(Ch)) in place over xn, AND
//           transposed flat-view write to Ct (fddT[c][r]) via LDS bounce.
// ---------------------------------------------------------------------------
template<int EPI, int KU>
__global__ __launch_bounds__(256, 4) void k_gemm1(
    const u16* __restrict__ A, const u16* __restrict__ Bm,
    const float* __restrict__ bias,
    float* __restrict__ Cf, u16* __restrict__ Ch, u16* __restrict__ Ct,
    const float* __restrict__ scaleP,
    int N, int K, int lda, int ldb, long sA, long sB, long sC)
{
    constexpr int BUFSZ = KU * 8192;
    constexpr int LDSZ = (2 * BUFSZ > 18432 || EPI != 7) ? 2 * BUFSZ : 18432;
    __shared__ u16 lds[LDSZ];
    // T1 XCD swizzle (all grids %8 == 0)
    const int gx = gridDim.x, gy = gridDim.y, gz = gridDim.z;
    int bidl = blockIdx.x + gx * (blockIdx.y + gy * blockIdx.z);
    int nwg = gx * gy * gz;
    int sw = (bidl & 7) * (nwg >> 3) + (bidl >> 3);
    int gxy = gx * gy;
    int bz = sw / gxy, rem = sw - bz * gxy;
    int by = rem / gx, bx = rem - by * gx;

    const int b = bz;
    const u16* pA = A + (size_t)b * sA;
    const u16* pB = Bm + (size_t)b * sB;
    const int m0 = by * 128, n0 = bx * 128;
    const int tid = threadIdx.x, wave = tid >> 6, lane = tid & 63;
    const int wm = wave >> 1, wn = wave & 1;
    const int g = lane >> 4;

    f32x4 acc[4][4];
    #pragma unroll
    for (int i = 0; i < 4; ++i)
        #pragma unroll
        for (int j = 0; j < 4; ++j) { f32x4 z = {0.f,0.f,0.f,0.f}; acc[i][j] = z; }

    auto STAGE = [&](int kt2, int buf) {
        #pragma unroll
        for (int u = 0; u < KU; ++u) {
            const int k0 = (kt2 * KU + u) << 5;
            u16* lb = lds + buf * BUFSZ + u * 8192;
            #pragma unroll
            for (int q = 0; q < 4; ++q) {
                int ci = wave * 4 + q;
                bool isA = ci < 8;
                int li = ci & 7;
                const u16* gp = isA ? pA : pB;
                int ld = isA ? lda : ldb;
                int rb = isA ? m0 : n0;
                int rp = li * 8 + (lane >> 3);
                int gg = (lane & 7) ^ (rp & 7);
                int r  = rp * 2 + (gg >> 2);
                int kc = k0 + (gg & 3) * 8;
                gld16(gp + (size_t)(rb + r) * ld + kc,
                      lb + (isA ? 0 : 4096) + li * 512 + lane * 8);
            }
        }
    };
    auto COMPUTE = [&](int buf) {
        #pragma unroll
        for (int u = 0; u < KU; ++u) {
            const u16* As = lds + buf * BUFSZ + u * 8192;
            const u16* Bs = As + 4096;
            short8v av[4];
            #pragma unroll
            for (int i = 0; i < 4; ++i) {
                int r = wm * 64 + i * 16 + (lane & 15);
                int rp = r >> 1, gg = ((r & 1) << 2) + g;
                av[i] = *(const short8v*)(As + rp * 64 + ((gg ^ (rp & 7)) << 3));
            }
            #pragma unroll
            for (int j = 0; j < 4; ++j) {
                int r = wn * 64 + j * 16 + (lane & 15);
                int rp = r >> 1, gg = ((r & 1) << 2) + g;
                short8v bv = *(const short8v*)(Bs + rp * 64 + ((gg ^ (rp & 7)) << 3));
                #pragma unroll
                for (int i = 0; i < 4; ++i)
                    acc[i][j] = __builtin_amdgcn_mfma_f32_16x16x32_bf16(av[i], bv, acc[i][j], 0, 0, 0);
            }
        }
    };

    const int nkt = K >> (KU == 2 ? 6 : 5);
    STAGE(0, 0);
    int cur = 0;
    for (int kt = 0; kt < nkt; ++kt) {
        if (kt + 1 < nkt) {
            STAGE(kt + 1, cur ^ 1);
            if (KU == 2) asm volatile("s_waitcnt vmcnt(8)" ::: "memory");
            else         asm volatile("s_waitcnt vmcnt(4)" ::: "memory");
        } else {
            asm volatile("s_waitcnt vmcnt(0)" ::: "memory");
        }
        __builtin_amdgcn_s_barrier();
        __builtin_amdgcn_sched_barrier(0);
        COMPUTE(cur);
        __builtin_amdgcn_sched_barrier(0);
        __builtin_amdgcn_s_barrier();
        cur ^= 1;
    }

    const float sc = (EPI == 7) ? scaleP[0] : 0.f;
    const int colbase = n0 + wn * 64 + (lane & 15);
    const int rowbase = m0 + wm * 64 + ((lane >> 4) << 2);
    #pragma unroll
    for (int i = 0; i < 4; ++i)
        #pragma unroll
        for (int j = 0; j < 4; ++j) {
            int col = colbase + j * 16;
            #pragma unroll
            for (int rg = 0; rg < 4; ++rg) {
                int row = rowbase + i * 16 + rg;
                size_t idx = (size_t)b * sC + (size_t)row * N + col;
                float a = acc[i][j][rg];
                if (EPI == 4)      Ch[idx] = tobf(a);
                else if (EPI == 5) Ch[idx] = tobf(a + bias[row]);
                else if (EPI == 6) Ch[idx] = tobf(a + bias[col]);
                else {             // EPI == 7
                    u16 v = tobf(sc * a + frombf(Ch[idx]));
                    Ch[idx] = v;
                    int lr = row - m0, lc = col - n0;
                    lds[(size_t)((lr & 1) * 128 + lc) * 72 + (lr >> 1)] = v;
                }
            }
        }

    if (EPI == 7) {
        __syncthreads();
        #pragma unroll
        for (int it = 0; it < 8; ++it) {
            int task = it * 256 + tid;
            int tc = task >> 3, ch = task & 7;
            short8v v = *(const short8v*)(lds + tc * 72 + ch * 8);
            int cg = ((tc >> 7) ? 512 : 0) + n0 + (tc & 127);
            *(short8v*)(Ct + (size_t)b * 524288 + (size_t)cg * 512 + (m0 >> 1) + ch * 8) = v;
        }
    }
}

// ---------------------------------------------------------------------------
// 5) FUSED S-GEMM + row softmax -> P bf16 (verified r12/r13)
// ---------------------------------------------------------------------------
__global__ __launch_bounds__(512) void k_ssoft(
    const u16* __restrict__ fg,   // [B][1024][128] (cols 0-63 f, 64-127 g)
    u16* __restrict__ P)          // [B][1024][1024]
{
    __shared__ u16 lds[69632];
    __shared__ float red[512];
    __shared__ float rowm[64];
    __shared__ float rinv[64];

    const int b = blockIdx.y;
    const int m0 = blockIdx.x * 64;
    const u16* fgb = fg + (size_t)b * 131072;
    const int tid = threadIdx.x, wave = tid >> 6, lane = tid & 63;
    const int wn = wave;
    const int g = lane >> 4;

    #pragma unroll
    for (int kc = 0; kc < 2; ++kc) {
        #pragma unroll
        for (int q = 0; q < 8; ++q) {
            int li = wave * 8 + q;
            int rp = li * 8 + (lane >> 3);
            int gg = (lane & 7) ^ (rp & 7);
            int r  = rp * 2 + (gg >> 2);
            int n2 = ((r & 31) << 5) | (r >> 5);
            int kcol = 64 + kc * 32 + (gg & 3) * 8;
            gld16(fgb + (size_t)n2 * 128 + kcol,
                  lds + 4096 + kc * 32768 + li * 512 + lane * 8);
        }
        if (lane < 32) {
            int rp = wave * 4 + (lane >> 3);
            int gg = (lane & 7) ^ (rp & 7);
            int r  = rp * 2 + (gg >> 2);
            int kcol = kc * 32 + (gg & 3) * 8;
            gld16(fgb + (size_t)(m0 + r) * 128 + kcol,
                  lds + kc * 2048 + wave * 256 + lane * 8);
        }
    }
    __syncthreads();

    f32x4 acc[4][8];
    #pragma unroll
    for (int i = 0; i < 4; ++i)
        #pragma unroll
        for (int j = 0; j < 8; ++j) { f32x4 z = {0.f,0.f,0.f,0.f}; acc[i][j] = z; }

    #pragma unroll
    for (int kc = 0; kc < 2; ++kc) {
        const u16* As = lds + kc * 2048;
        const u16* Bs = lds + 4096 + kc * 32768;
        short8v av[4];
        #pragma unroll
        for (int i = 0; i < 4; ++i) {
            int r = i * 16 + (lane & 15);
            int rp = r >> 1, gg = ((r & 1) << 2) + g;
            av[i] = *(const short8v*)(As + rp * 64 + ((gg ^ (rp & 7)) << 3));
        }
        #pragma unroll
        for (int j = 0; j < 8; ++j) {
            int n = wn * 128 + j * 16 + (lane & 15);
            int rp = n >> 1, gg = ((n & 1) << 2) + g;
            short8v bv = *(const short8v*)(Bs + rp * 64 + ((gg ^ (rp & 7)) << 3));
            #pragma unroll
            for (int i = 0; i < 4; ++i)
                acc[i][j] = __builtin_amdgcn_mfma_f32_16x16x32_bf16(av[i], bv, acc[i][j], 0, 0, 0);
        }
    }

    const int rgrp = (lane >> 4) << 2;
    float pm[4][4];
    #pragma unroll
    for (int i = 0; i < 4; ++i)
        #pragma unroll
        for (int rg = 0; rg < 4; ++rg) {
            float m = acc[i][0][rg];
            #pragma unroll
            for (int j = 1; j < 8; ++j) m = fmaxf(m, acc[i][j][rg]);
            pm[i][rg] = m;
        }
    #pragma unroll
    for (int o = 1; o < 16; o <<= 1)
        #pragma unroll
        for (int i = 0; i < 4; ++i)
            #pragma unroll
            for (int rg = 0; rg < 4; ++rg)
                pm[i][rg] = fmaxf(pm[i][rg], __shfl_xor(pm[i][rg], o));
    if ((lane & 15) == 0)
        #pragma unroll
        for (int i = 0; i < 4; ++i)
            #pragma unroll
            for (int rg = 0; rg < 4; ++rg)
                red[wn * 64 + i * 16 + rgrp + rg] = pm[i][rg];
    __syncthreads();
    if (tid < 64) {
        float m = red[tid];
        #pragma unroll
        for (int w = 1; w < 8; ++w) m = fmaxf(m, red[w * 64 + tid]);
        rowm[tid] = m;
    }
    __syncthreads();

    float ps[4][4];
    #pragma unroll
    for (int i = 0; i < 4; ++i)
        #pragma unroll
        for (int rg = 0; rg < 4; ++rg) {
            float m = rowm[i * 16 + rgrp + rg];
            float s = 0.f;
            #pragma unroll
            for (int j = 0; j < 8; ++j) {
                float e = expf(acc[i][j][rg] - m);
                acc[i][j][rg] = e;
                s += e;
            }
            ps[i][rg] = s;
        }
    #pragma unroll
    for (int o = 1; o < 16; o <<= 1)
        #pragma unroll
        for (int i = 0; i < 4; ++i)
            #pragma unroll
            for (int rg = 0; rg < 4; ++rg)
                ps[i][rg] += __shfl_xor(ps[i][rg], o);
    if ((lane & 15) == 0)
        #pragma unroll
        for (int i = 0; i < 4; ++i)
            #pragma unroll
            for (int rg = 0; rg < 4; ++rg)
                red[wn * 64 + i * 16 + rgrp + rg] = ps[i][rg];
    __syncthreads();
    if (tid < 64) {
        float s = red[tid];
        #pragma unroll
        for (int w = 1; w < 8; ++w) s += red[w * 64 + tid];
        rinv[tid] = 1.f / s;
    }
    __syncthreads();

    u16* Plds = lds + 4096;
    #pragma unroll
    for (int i = 0; i < 4; ++i)
        #pragma unroll
        for (int rg = 0; rg < 4; ++rg) {
            int r = i * 16 + rgrp + rg;
            float riv = rinv[r];
            int sx = (r & 7) << 4;
            #pragma unroll
            for (int j = 0; j < 8; ++j) {
                u16 v = tobf(acc[i][j][rg] * riv);
                int col = wn * 128 + ((j * 16) ^ sx) + (lane & 15);
                Plds[r * 1024 + col] = v;
            }
        }
    __syncthreads();

    for (int it = 0; it < 16; ++it) {
        int r  = it * 4 + (tid >> 7);
        int cb = (tid & 127) * 8;
        int sx = (r & 7) << 4;
        int src = r * 1024 + (cb & ~127) + ((cb & 127) ^ sx);
        short8v v = *(const short8v*)(Plds + src);
        *(short8v*)(P + ((size_t)b * HW_ + m0 + r) * (size_t)HW_ + cb) = v;
    }
}

// ---------------------------------------------------------------------------
// 6) top-48, one WAVE per row, bf16 corr input (verified r14)
// ---------------------------------------------------------------------------
__device__ __forceinline__ float sort64_desc(float v, int lane) {
    #pragma unroll
    for (int k = 2; k <= 64; k <<= 1) {
        #pragma unroll
        for (int j = k >> 1; j > 0; j >>= 1) {
            float o = __shfl_xor(v, j);
            bool takeMax = (((lane & k) == 0) == ((lane & j) == 0));
            v = takeMax ? fmaxf(v, o) : fminf(v, o);
        }
    }
    return v;
}
__device__ __forceinline__ float bmerge64_desc(float a, float b, int lane) {
    float br = __shfl(b, 63 - lane);
    float c = fmaxf(a, br);
    #pragma unroll
    for (int j = 32; j > 0; j >>= 1) {
        float o = __shfl_xor(c, j);
        c = ((lane & j) == 0) ? fmaxf(c, o) : fminf(c, o);
    }
    return c;
}

__global__ __launch_bounds__(256) void k_topk(const u16* __restrict__ corr,
                                              float* __restrict__ topv) {
    __shared__ float buf[4][1024];
    int wave = threadIdx.x >> 6, lane = threadIdx.x & 63;
    int row = blockIdx.x * 4 + wave;
    const u16* rp = corr + (size_t)row * HW_ + lane * 16;

    short8v w0 = *(const short8v*)(rp);
    short8v w1 = *(const short8v*)(rp + 8);
    float e[16];
    #pragma unroll
    for (int q = 0; q < 8; ++q) e[q]     = frombf((u16)w0[q]);
    #pragma unroll
    for (int q = 0; q < 8; ++q) e[q + 8] = frombf((u16)w1[q]);

    float gm = e[0];
    #pragma unroll
    for (int q = 1; q < 16; ++q) gm = fmaxf(gm, e[q]);
    float sorted = sort64_desc(gm, lane);
    float tau = __shfl(sorted, T_ - 1);

    int c = 0;
    #pragma unroll
    for (int q = 0; q < 16; ++q) c += (e[q] >= tau);
    int sc = c;
    #pragma unroll
    for (int o = 1; o < 64; o <<= 1) {
        int t2 = __shfl_up(sc, o);
        if (lane >= o) sc += t2;
    }
    int off = sc - c;
    int cnt = __shfl(sc, 63);                    // >= 48 guaranteed

    float* wb = buf[wave];
    #pragma unroll
    for (int q = 0; q < 16; ++q)
        if (e[q] >= tau) wb[off++] = e[q];

    float* orow = topv + (size_t)row * T_;
    if (cnt <= 64) {
        float a = (lane < cnt) ? wb[lane] : -INFINITY;
        a = sort64_desc(a, lane);
        if (lane < T_) orow[lane] = fmaxf(a, 0.f);
    } else if (cnt <= 128) {
        float a  = sort64_desc(wb[lane], lane);
        float b2 = sort64_desc((lane < cnt - 64) ? wb[64 + lane] : -INFINITY, lane);
        float m2 = bmerge64_desc(a, b2, lane);
        if (lane < T_) orow[lane] = fmaxf(m2, 0.f);
    } else {
        int P = 256; while (P < cnt) P <<= 1;
        for (int i = cnt + lane; i < P; i += 64) wb[i] = -INFINITY;
        for (int k = 2; k <= P; k <<= 1)
            for (int j = k >> 1; j > 0; j >>= 1)
                for (int t2 = lane; t2 < P; t2 += 64) {
                    int ixj = t2 ^ j;
                    if (ixj > t2) {
                        float a = wb[t2], b3 = wb[ixj];
                        bool desc = ((t2 & k) == 0);
                        if (desc ? (a < b3) : (a > b3)) { wb[t2] = b3; wb[ixj] = a; }
                    }
                }
        if (lane < T_) orow[lane] = fmaxf(wb[lane], 0.f);
    }
}

// ---------------------------------------------------------------------------
// 7) column norm over (B,H) and final transpose
// ---------------------------------------------------------------------------
__global__ void k_colss(const float* __restrict__ topv, float* __restrict__ colss) {
    int o = blockIdx.x;
    int w = o / T_, t = o % T_;
    int lane = threadIdx.x;
    float s = 0.f;
    for (int i = lane; i < 512; i += 64) {
        int b = i >> 5, h = i & 31;
        float v = topv[(size_t)((b << 10) + (h << 5) + w) * T_ + t];
        s += v * v;
    }
    for (int off = 32; off > 0; off >>= 1) s += __shfl_down(s, off);
    if (lane == 0) colss[o] = s;
}

__global__ void k_final(const float* __restrict__ topv, const float* __restrict__ colss,
                        float* __restrict__ out) {
    int idx = blockIdx.x * 256 + threadIdx.x;
    if (idx >= B_ * T_ * HW_) return;
    int w = idx & 31;
    int h = (idx >> 5) & 31;
    int t = (idx >> 10) % T_;
    int b = idx / (T_ * HW_);
    float v = topv[(size_t)((b << 10) + (h << 5) + w) * T_ + t];
    out[idx] = v * rsqrtf(colss[w * T_ + t]);
}

// ---------------------------------------------------------------------------
extern "C" void kernel_launch(void* const* d_in, const int* in_sizes, int n_in,
                              void* d_out, int out_size, void* d_ws, size_t ws_size,
                              hipStream_t stream) {
    const float* x     = (const float*)d_in[0];
    const float* fW    = (const float*)d_in[1];
    const float* fb    = (const float*)d_in[2];
    const float* gW    = (const float*)d_in[3];
    const float* gb    = (const float*)d_in[4];
    const float* hW    = (const float*)d_in[5];
    const float* hb    = (const float*)d_in[6];
    const float* scale = (const float*)d_in[7];
    float* out = (float*)d_out;

    char* wsb = (char*)d_ws;
    float* part = (float*)(wsb + 0);                 // 262144 B [64][1024]
    float* ninv = (float*)(wsb + 262144);            // 4096 B
    u16*   hWh  = (u16*)(wsb + 266240);              // 524288 B
    u16*   fgWh = (u16*)(wsb + 790528);              // 131072 B
    float* fgb  = (float*)(wsb + 921600);            // 512 B
    u16*   xnH  = (u16*)(wsb + 922112);              // 16 MB (xn -> fdd bf16)
    u16*   fgH  = (u16*)(wsb + 17699328);            // 4 MB (f|g; later topv)
    u16*   fgL  = (u16*)(wsb + 21893632);            // 4 MB (later colss)
    u16*   hvTH = (u16*)(wsb + 26087936);            // 16 MB (hv)
    float* S    = (float*)(wsb + 42865152);          // 64 MB (P u16 -> corr bf16)
    u16*   fddT = (u16*)(wsb + 109974016);           // 16 MB (fddT)
    float* topv = (float*)fgH;
    float* colss= (float*)fgL;
    u16*   Sp   = (u16*)S;

    const long sXn = 524288;    // [1024][512] elements per batch
    const long sFG = 131072;    // [1024][128]
    const long sS  = 1048576;   // [1024][1024]

    // 1) per-pixel Frobenius norm
    k_colsq<<<256, 256, 0, stream>>>(x, part);
    k_rsqrt<<<4, 256, 0, stream>>>(part, ninv);

    // 2) normalized channel-last bf16
    k_transpose<<<dim3(32, 16, 16), dim3(32, 8), 0, stream>>>(x, ninv, xnH);

    // 3) weight planes
    k_packW<<<1024, 256, 0, stream>>>(hW, hWh);
    k_packFG<<<256, 256, 0, stream>>>(fW, gW, fb, gb, fgWh, fgb);

    // 4) fg = bf16(xn @ [fW|gW]^T + bias[col])  [B,1024,128]  (grid-limited, KU=2)
    k_gemm1<6, 2><<<dim3(1, 8, 16), 256, 0, stream>>>(
        xnH, fgWh, fgb, nullptr, fgH, nullptr, nullptr,
        128, 512, 512, 512, sXn, 0, sFG);

    // 5) hv = bf16(hW @ xn^T + hb[row])  [B,512,1024]  (grid-limited, KU=2)
    k_gemm1<5, 2><<<dim3(8, 4, 16), 256, 0, stream>>>(
        hWh, xnH, hb, nullptr, hvTH, nullptr, nullptr,
        1024, 512, 512, 512, 0, sXn, sXn);

    // 6+7) fused S-GEMM + softmax -> P bf16
    k_ssoft<<<dim3(16, 16), 512, 0, stream>>>(fgH, Sp);

    // 8) fdd = bf16(scale*(P @ hv^T) + xn) in place over xnH + fddT write (KU=2)
    k_gemm1<7, 2><<<dim3(4, 8, 16), 256, 0, stream>>>(
        Sp, hvTH, nullptr, nullptr, xnH, fddT, scale,
        512, 1024, 1024, 1024, sS, sXn, sXn);

    // 9) corr = bf16(fdd @ fddT^T) into S region (KU=1: 4 blocks/CU)
    k_gemm1<4, 1><<<dim3(8, 8, 16), 256, 0, stream>>>(
        xnH, fddT, nullptr, nullptr, Sp, nullptr, nullptr,
        1024, 512, 512, 512, sXn, sXn, sS);

    // 10) top-48 desc + relu (wave-per-row, bf16 input)
    k_topk<<<B_ * HW_ / 4, 256, 0, stream>>>(Sp, topv);

    // 11) norm over (B,H) + output transpose
    k_colss<<<W_ * T_, 64, 0, stream>>>(topv, colss);
    k_final<<<(B_ * T_ * HW_ + 255) / 256, 256, 0, stream>>>(topv, colss, out);
}

// Round 17
// 177.946 us; speedup vs baseline: 1.2526x; 1.0101x over previous
//
#include <hip/hip_runtime.h>
#include <cstdint>
#include <cstddef>

#define B_   16
#define C_   512
#define H_   32
#define W_   32
#define HW_  1024
#define TC_  64
#define T_   48

typedef unsigned short u16;
typedef __attribute__((ext_vector_type(8))) short short8v;
typedef __attribute__((ext_vector_type(4))) float f32x4;

// ---------------------------------------------------------------------------
// bf16 helpers
// ---------------------------------------------------------------------------
__device__ __forceinline__ u16 tobf(float x) {
    unsigned u = __float_as_uint(x);
    return (u16)((u + 0x7FFFu + ((u >> 16) & 1u)) >> 16);    // RTNE
}
__device__ __forceinline__ float frombf(u16 h) {
    return __uint_as_float(((unsigned)h) << 16);
}

__device__ __forceinline__ void gld16(const void* g, void* l) {
    __builtin_amdgcn_global_load_lds(
        (const __attribute__((address_space(1))) void*)g,
        (__attribute__((address_space(3))) void*)l, 16, 0, 0);
}

// ---------------------------------------------------------------------------
// 1) Frobenius-norm helpers
// ---------------------------------------------------------------------------
__global__ void k_colsq(const float* __restrict__ x, float* __restrict__ partial) {
    int bid = blockIdx.x;
    int col = (bid & 3) * 256 + threadIdx.x;
    int r0  = (bid >> 2) * 128;
    const float* p = x + (size_t)r0 * HW_ + col;
    float s = 0.f;
    for (int r = 0; r < 128; ++r) { float v = p[(size_t)r * HW_]; s += v * v; }
    partial[(size_t)(bid >> 2) * HW_ + col] = s;
}

__global__ void k_rsqrt(const float* __restrict__ partial, float* __restrict__ ninv) {
    int i = blockIdx.x * 256 + threadIdx.x;
    if (i < HW_) {
        float s = 0.f;
        for (int r = 0; r < 64; ++r) s += partial[(size_t)r * HW_ + i];
        ninv[i] = rsqrtf(s);
    }
}

// ---------------------------------------------------------------------------
// 2) transpose + normalize: x [B,C,HW] -> xnH bf16 [B,HW,C]
// ---------------------------------------------------------------------------
__global__ void k_transpose(const float* __restrict__ x, const float* __restrict__ ninv,
                            u16* __restrict__ obH) {
    __shared__ float tile[32][33];
    int b  = blockIdx.z;
    int m0 = blockIdx.x * 32, c0 = blockIdx.y * 32;
    int tx = threadIdx.x, ty = threadIdx.y;
    const float* xb = x + (size_t)b * C_ * HW_;
    #pragma unroll
    for (int j = 0; j < 32; j += 8)
        tile[ty + j][tx] = xb[(size_t)(c0 + ty + j) * HW_ + m0 + tx];
    __syncthreads();
    size_t base = (size_t)b * HW_ * C_;
    #pragma unroll
    for (int j = 0; j < 32; j += 8) {
        int m = m0 + ty + j;
        obH[base + (size_t)m * C_ + c0 + tx] = tobf(tile[tx][ty + j] * ninv[m]);
    }
}

// ---------------------------------------------------------------------------
// 3) weight prep (hi plane only)
// ---------------------------------------------------------------------------
__global__ void k_packW(const float* __restrict__ in, u16* __restrict__ oh) {
    size_t i = (size_t)blockIdx.x * 256 + threadIdx.x;
    oh[i] = tobf(in[i]);
}
__global__ void k_packFG(const float* __restrict__ fW, const float* __restrict__ gW,
                         const float* __restrict__ fb, const float* __restrict__ gb,
                         u16* __restrict__ oh, float* __restrict__ fgb) {
    int idx = blockIdx.x * 256 + threadIdx.x;   // 65536
    int row = idx >> 9, c = idx & 511;
    float v = (row < 64) ? fW[row * 512 + c] : gW[(row - 64) * 512 + c];
    oh[idx] = tobf(v);
    if (idx < 128) fgb[idx] = (idx < 64) ? fb[idx] : gb[idx - 64];
}

// ---------------------------------------------------------------------------
// 4) 1-term bf16 MFMA GEMM, 128x128, 4 waves, 2-buffer counted-vmcnt (r9) +
//    XCD swizzle (r12) + KU k-tiles per phase (r16).
//    EPI 5: Ch = bf16(acc + bias[row])
//    EPI 6: Ch = bf16(acc + bias[col])
//    EPI 7: PV: Ch = bf16(scale*acc + frombf(Ch)) in place over xn, AND
//           transposed flat-view write to Ct (fddT[c][r]) via LDS bounce.
// ---------------------------------------------------------------------------
template<int EPI, int KU>
__global__ __launch_bounds__(256, 4) void k_gemm1(
    const u16* __restrict__ A, const u16* __restrict__ Bm,
    const float* __restrict__ bias,
    float* __restrict__ Cf, u16* __restrict__ Ch, u16* __restrict__ Ct,
    const float* __restrict__ scaleP,
    int N, int K, int lda, int ldb, long sA, long sB, long sC)
{
    constexpr int BUFSZ = KU * 8192;
    constexpr int LDSZ = (2 * BUFSZ > 18432 || EPI != 7) ? 2 * BUFSZ : 18432;
    __shared__ u16 lds[LDSZ];
    // T1 XCD swizzle (all grids %8 == 0)
    const int gx = gridDim.x, gy = gridDim.y, gz = gridDim.z;
    int bidl = blockIdx.x + gx * (blockIdx.y + gy * blockIdx.z);
    int nwg = gx * gy * gz;
    int sw = (bidl & 7) * (nwg >> 3) + (bidl >> 3);
    int gxy = gx * gy;
    int bz = sw / gxy, rem = sw - bz * gxy;
    int by = rem / gx, bx = rem - by * gx;

    const int b = bz;
    const u16* pA = A + (size_t)b * sA;
    const u16* pB = Bm + (size_t)b * sB;
    const int m0 = by * 128, n0 = bx * 128;
    const int tid = threadIdx.x, wave = tid >> 6, lane = tid & 63;
    const int wm = wave >> 1, wn = wave & 1;
    const int g = lane >> 4;

    f32x4 acc[4][4];
    #pragma unroll
    for (int i = 0; i < 4; ++i)
        #pragma unroll
        for (int j = 0; j < 4; ++j) { f32x4 z = {0.f,0.f,0.f,0.f}; acc[i][j] = z; }

    auto STAGE = [&](int kt2, int buf) {
        #pragma unroll
        for (int u = 0; u < KU; ++u) {
            const int k0 = (kt2 * KU + u) << 5;
            u16* lb = lds + buf * BUFSZ + u * 8192;
            #pragma unroll
            for (int q = 0; q < 4; ++q) {
                int ci = wave * 4 + q;
                bool isA = ci < 8;
                int li = ci & 7;
                const u16* gp = isA ? pA : pB;
                int ld = isA ? lda : ldb;
                int rb = isA ? m0 : n0;
                int rp = li * 8 + (lane >> 3);
                int gg = (lane & 7) ^ (rp & 7);
                int r  = rp * 2 + (gg >> 2);
                int kc = k0 + (gg & 3) * 8;
                gld16(gp + (size_t)(rb + r) * ld + kc,
                      lb + (isA ? 0 : 4096) + li * 512 + lane * 8);
            }
        }
    };
    auto COMPUTE = [&](int buf) {
        #pragma unroll
        for (int u = 0; u < KU; ++u) {
            const u16* As = lds + buf * BUFSZ + u * 8192;
            const u16* Bs = As + 4096;
            short8v av[4];
            #pragma unroll
            for (int i = 0; i < 4; ++i) {
                int r = wm * 64 + i * 16 + (lane & 15);
                int rp = r >> 1, gg = ((r & 1) << 2) + g;
                av[i] = *(const short8v*)(As + rp * 64 + ((gg ^ (rp & 7)) << 3));
            }
            #pragma unroll
            for (int j = 0; j < 4; ++j) {
                int r = wn * 64 + j * 16 + (lane & 15);
                int rp = r >> 1, gg = ((r & 1) << 2) + g;
                short8v bv = *(const short8v*)(Bs + rp * 64 + ((gg ^ (rp & 7)) << 3));
                #pragma unroll
                for (int i = 0; i < 4; ++i)
                    acc[i][j] = __builtin_amdgcn_mfma_f32_16x16x32_bf16(av[i], bv, acc[i][j], 0, 0, 0);
            }
        }
    };

    const int nkt = K >> (KU == 2 ? 6 : 5);
    STAGE(0, 0);
    int cur = 0;
    for (int kt = 0; kt < nkt; ++kt) {
        if (kt + 1 < nkt) {
            STAGE(kt + 1, cur ^ 1);
            if (KU == 2) asm volatile("s_waitcnt vmcnt(8)" ::: "memory");
            else         asm volatile("s_waitcnt vmcnt(4)" ::: "memory");
        } else {
            asm volatile("s_waitcnt vmcnt(0)" ::: "memory");
        }
        __builtin_amdgcn_s_barrier();
        __builtin_amdgcn_sched_barrier(0);
        COMPUTE(cur);
        __builtin_amdgcn_sched_barrier(0);
        __builtin_amdgcn_s_barrier();
        cur ^= 1;
    }

    const float sc = (EPI == 7) ? scaleP[0] : 0.f;
    const int colbase = n0 + wn * 64 + (lane & 15);
    const int rowbase = m0 + wm * 64 + ((lane >> 4) << 2);
    #pragma unroll
    for (int i = 0; i < 4; ++i)
        #pragma unroll
        for (int j = 0; j < 4; ++j) {
            int col = colbase + j * 16;
            #pragma unroll
            for (int rg = 0; rg < 4; ++rg) {
                int row = rowbase + i * 16 + rg;
                size_t idx = (size_t)b * sC + (size_t)row * N + col;
                float a = acc[i][j][rg];
                if (EPI == 5)      Ch[idx] = tobf(a + bias[row]);
                else if (EPI == 6) Ch[idx] = tobf(a + bias[col]);
                else {             // EPI == 7
                    u16 v = tobf(sc * a + frombf(Ch[idx]));
                    Ch[idx] = v;
                    int lr = row - m0, lc = col - n0;
                    lds[(size_t)((lr & 1) * 128 + lc) * 72 + (lr >> 1)] = v;
                }
            }
        }

    if (EPI == 7) {
        __syncthreads();
        #pragma unroll
        for (int it = 0; it < 8; ++it) {
            int task = it * 256 + tid;
            int tc = task >> 3, ch = task & 7;
            short8v v = *(const short8v*)(lds + tc * 72 + ch * 8);
            int cg = ((tc >> 7) ? 512 : 0) + n0 + (tc & 127);
            *(short8v*)(Ct + (size_t)b * 524288 + (size_t)cg * 512 + (m0 >> 1) + ch * 8) = v;
        }
    }
}

// ---------------------------------------------------------------------------
// 4b) corr GEMM: 128x256 tile, 8 waves, counted vmcnt(3), XCD swizzle,
//     bf16 out. Structure verified r8/r9; swizzle identical to k_gemm1.
// ---------------------------------------------------------------------------
__global__ __launch_bounds__(512) void k_gemm2c(
    const u16* __restrict__ A, const u16* __restrict__ Bm,
    u16* __restrict__ Ch,
    int N, int K, int lda, int ldb, long sA, long sB, long sC)
{
    __shared__ u16 lds[2 * 12288];
    const int gx = gridDim.x, gy = gridDim.y, gz = gridDim.z;
    int bidl = blockIdx.x + gx * (blockIdx.y + gy * blockIdx.z);
    int nwg = gx * gy * gz;
    int sw = (bidl & 7) * (nwg >> 3) + (bidl >> 3);
    int gxy = gx * gy;
    int bz = sw / gxy, rem = sw - bz * gxy;
    int by = rem / gx, bx = rem - by * gx;

    const int b = bz;
    const u16* pA = A + (size_t)b * sA;
    const u16* pB = Bm + (size_t)b * sB;
    const int m0 = by * 128, n0 = bx * 256;
    const int tid = threadIdx.x, wave = tid >> 6, lane = tid & 63;
    const int wm = wave >> 2, wn = wave & 3;
    const int g = lane >> 4;

    f32x4 acc[4][4];
    #pragma unroll
    for (int i = 0; i < 4; ++i)
        #pragma unroll
        for (int j = 0; j < 4; ++j) { f32x4 z = {0.f,0.f,0.f,0.f}; acc[i][j] = z; }

    auto STAGE = [&](int kt, int buf) {
        const int k0 = kt << 5;
        u16* lb = lds + buf * 12288;
        #pragma unroll
        for (int q = 0; q < 3; ++q) {
            int ci = wave * 3 + q;
            bool isA = ci < 8;
            int li = isA ? ci : ci - 8;
            const u16* gp = isA ? pA : pB;
            int ld = isA ? lda : ldb;
            int rb = isA ? m0 : n0;
            int rp = li * 8 + (lane >> 3);
            int gg = (lane & 7) ^ (rp & 7);
            int r  = rp * 2 + (gg >> 2);
            int kc = k0 + (gg & 3) * 8;
            gld16(gp + (size_t)(rb + r) * ld + kc,
                  lb + (isA ? 0 : 4096) + li * 512 + lane * 8);
        }
    };
    auto COMPUTE = [&](int buf) {
        const u16* As = lds + buf * 12288;
        const u16* Bs = As + 4096;
        short8v av[4];
        #pragma unroll
        for (int i = 0; i < 4; ++i) {
            int r = wm * 64 + i * 16 + (lane & 15);
            int rp = r >> 1, gg = ((r & 1) << 2) + g;
            av[i] = *(const short8v*)(As + rp * 64 + ((gg ^ (rp & 7)) << 3));
        }
        #pragma unroll
        for (int j = 0; j < 4; ++j) {
            int r = wn * 64 + j * 16 + (lane & 15);
            int rp = r >> 1, gg = ((r & 1) << 2) + g;
            short8v bv = *(const short8v*)(Bs + rp * 64 + ((gg ^ (rp & 7)) << 3));
            #pragma unroll
            for (int i = 0; i < 4; ++i)
                acc[i][j] = __builtin_amdgcn_mfma_f32_16x16x32_bf16(av[i], bv, acc[i][j], 0, 0, 0);
        }
    };

    const int nkt = K >> 5;
    STAGE(0, 0);
    int cur = 0;
    for (int kt = 0; kt < nkt; ++kt) {
        if (kt + 1 < nkt) {
            STAGE(kt + 1, cur ^ 1);
            asm volatile("s_waitcnt vmcnt(3)" ::: "memory");
        } else {
            asm volatile("s_waitcnt vmcnt(0)" ::: "memory");
        }
        __builtin_amdgcn_s_barrier();
        __builtin_amdgcn_sched_barrier(0);
        COMPUTE(cur);
        __builtin_amdgcn_sched_barrier(0);
        __builtin_amdgcn_s_barrier();
        cur ^= 1;
    }

    const int colbase = n0 + wn * 64 + (lane & 15);
    const int rowbase = m0 + wm * 64 + ((lane >> 4) << 2);
    #pragma unroll
    for (int i = 0; i < 4; ++i)
        #pragma unroll
        for (int j = 0; j < 4; ++j) {
            int col = colbase + j * 16;
            #pragma unroll
            for (int rg = 0; rg < 4; ++rg) {
                int row = rowbase + i * 16 + rg;
                Ch[(size_t)b * sC + (size_t)row * N + col] = tobf(acc[i][j][rg]);
            }
        }
}

// ---------------------------------------------------------------------------
// 5) FUSED S-GEMM + row softmax -> P bf16 (verified r12/r13)
// ---------------------------------------------------------------------------
__global__ __launch_bounds__(512) void k_ssoft(
    const u16* __restrict__ fg,   // [B][1024][128] (cols 0-63 f, 64-127 g)
    u16* __restrict__ P)          // [B][1024][1024]
{
    __shared__ u16 lds[69632];
    __shared__ float red[512];
    __shared__ float rowm[64];
    __shared__ float rinv[64];

    const int b = blockIdx.y;
    const int m0 = blockIdx.x * 64;
    const u16* fgb = fg + (size_t)b * 131072;
    const int tid = threadIdx.x, wave = tid >> 6, lane = tid & 63;
    const int wn = wave;
    const int g = lane >> 4;

    #pragma unroll
    for (int kc = 0; kc < 2; ++kc) {
        #pragma unroll
        for (int q = 0; q < 8; ++q) {
            int li = wave * 8 + q;
            int rp = li * 8 + (lane >> 3);
            int gg = (lane & 7) ^ (rp & 7);
            int r  = rp * 2 + (gg >> 2);
            int n2 = ((r & 31) << 5) | (r >> 5);
            int kcol = 64 + kc * 32 + (gg & 3) * 8;
            gld16(fgb + (size_t)n2 * 128 + kcol,
                  lds + 4096 + kc * 32768 + li * 512 + lane * 8);
        }
        if (lane < 32) {
            int rp = wave * 4 + (lane >> 3);
            int gg = (lane & 7) ^ (rp & 7);
            int r  = rp * 2 + (gg >> 2);
            int kcol = kc * 32 + (gg & 3) * 8;
            gld16(fgb + (size_t)(m0 + r) * 128 + kcol,
                  lds + kc * 2048 + wave * 256 + lane * 8);
        }
    }
    __syncthreads();

    f32x4 acc[4][8];
    #pragma unroll
    for (int i = 0; i < 4; ++i)
        #pragma unroll
        for (int j = 0; j < 8; ++j) { f32x4 z = {0.f,0.f,0.f,0.f}; acc[i][j] = z; }

    #pragma unroll
    for (int kc = 0; kc < 2; ++kc) {
        const u16* As = lds + kc * 2048;
        const u16* Bs = lds + 4096 + kc * 32768;
        short8v av[4];
        #pragma unroll
        for (int i = 0; i < 4; ++i) {
            int r = i * 16 + (lane & 15);
            int rp = r >> 1, gg = ((r & 1) << 2) + g;
            av[i] = *(const short8v*)(As + rp * 64 + ((gg ^ (rp & 7)) << 3));
        }
        #pragma unroll
        for (int j = 0; j < 8; ++j) {
            int n = wn * 128 + j * 16 + (lane & 15);
            int rp = n >> 1, gg = ((n & 1) << 2) + g;
            short8v bv = *(const short8v*)(Bs + rp * 64 + ((gg ^ (rp & 7)) << 3));
            #pragma unroll
            for (int i = 0; i < 4; ++i)
                acc[i][j] = __builtin_amdgcn_mfma_f32_16x16x32_bf16(av[i], bv, acc[i][j], 0, 0, 0);
        }
    }

    const int rgrp = (lane >> 4) << 2;
    float pm[4][4];
    #pragma unroll
    for (int i = 0; i < 4; ++i)
        #pragma unroll
        for (int rg = 0; rg < 4; ++rg) {
            float m = acc[i][0][rg];
            #pragma unroll
            for (int j = 1; j < 8; ++j) m = fmaxf(m, acc[i][j][rg]);
            pm[i][rg] = m;
        }
    #pragma unroll
    for (int o = 1; o < 16; o <<= 1)
        #pragma unroll
        for (int i = 0; i < 4; ++i)
            #pragma unroll
            for (int rg = 0; rg < 4; ++rg)
                pm[i][rg] = fmaxf(pm[i][rg], __shfl_xor(pm[i][rg], o));
    if ((lane & 15) == 0)
        #pragma unroll
        for (int i = 0; i < 4; ++i)
            #pragma unroll
            for (int rg = 0; rg < 4; ++rg)
                red[wn * 64 + i * 16 + rgrp + rg] = pm[i][rg];
    __syncthreads();
    if (tid < 64) {
        float m = red[tid];
        #pragma unroll
        for (int w = 1; w < 8; ++w) m = fmaxf(m, red[w * 64 + tid]);
        rowm[tid] = m;
    }
    __syncthreads();

    float ps[4][4];
    #pragma unroll
    for (int i = 0; i < 4; ++i)
        #pragma unroll
        for (int rg = 0; rg < 4; ++rg) {
            float m = rowm[i * 16 + rgrp + rg];
            float s = 0.f;
            #pragma unroll
            for (int j = 0; j < 8; ++j) {
                float e = expf(acc[i][j][rg] - m);
                acc[i][j][rg] = e;
                s += e;
            }
            ps[i][rg] = s;
        }
    #pragma unroll
    for (int o = 1; o < 16; o <<= 1)
        #pragma unroll
        for (int i = 0; i < 4; ++i)
            #pragma unroll
            for (int rg = 0; rg < 4; ++rg)
                ps[i][rg] += __shfl_xor(ps[i][rg], o);
    if ((lane & 15) == 0)
        #pragma unroll
        for (int i = 0; i < 4; ++i)
            #pragma unroll
            for (int rg = 0; rg < 4; ++rg)
                red[wn * 64 + i * 16 + rgrp + rg] = ps[i][rg];
    __syncthreads();
    if (tid < 64) {
        float s = red[tid];
        #pragma unroll
        for (int w = 1; w < 8; ++w) s += red[w * 64 + tid];
        rinv[tid] = 1.f / s;
    }
    __syncthreads();

    u16* Plds = lds + 4096;
    #pragma unroll
    for (int i = 0; i < 4; ++i)
        #pragma unroll
        for (int rg = 0; rg < 4; ++rg) {
            int r = i * 16 + rgrp + rg;
            float riv = rinv[r];
            int sx = (r & 7) << 4;
            #pragma unroll
            for (int j = 0; j < 8; ++j) {
                u16 v = tobf(acc[i][j][rg] * riv);
                int col = wn * 128 + ((j * 16) ^ sx) + (lane & 15);
                Plds[r * 1024 + col] = v;
            }
        }
    __syncthreads();

    for (int it = 0; it < 16; ++it) {
        int r  = it * 4 + (tid >> 7);
        int cb = (tid & 127) * 8;
        int sx = (r & 7) << 4;
        int src = r * 1024 + (cb & ~127) + ((cb & 127) ^ sx);
        short8v v = *(const short8v*)(Plds + src);
        *(short8v*)(P + ((size_t)b * HW_ + m0 + r) * (size_t)HW_ + cb) = v;
    }
}

// ---------------------------------------------------------------------------
// 6) top-48, one WAVE per row, bf16 corr input (verified r14)
// ---------------------------------------------------------------------------
__device__ __forceinline__ float sort64_desc(float v, int lane) {
    #pragma unroll
    for (int k = 2; k <= 64; k <<= 1) {
        #pragma unroll
        for (int j = k >> 1; j > 0; j >>= 1) {
            float o = __shfl_xor(v, j);
            bool takeMax = (((lane & k) == 0) == ((lane & j) == 0));
            v = takeMax ? fmaxf(v, o) : fminf(v, o);
        }
    }
    return v;
}
__device__ __forceinline__ float bmerge64_desc(float a, float b, int lane) {
    float br = __shfl(b, 63 - lane);
    float c = fmaxf(a, br);
    #pragma unroll
    for (int j = 32; j > 0; j >>= 1) {
        float o = __shfl_xor(c, j);
        c = ((lane & j) == 0) ? fmaxf(c, o) : fminf(c, o);
    }
    return c;
}

__global__ __launch_bounds__(256) void k_topk(const u16* __restrict__ corr,
                                              float* __restrict__ topv) {
    __shared__ float buf[4][1024];
    int wave = threadIdx.x >> 6, lane = threadIdx.x & 63;
    int row = blockIdx.x * 4 + wave;
    const u16* rp = corr + (size_t)row * HW_ + lane * 16;

    short8v w0 = *(const short8v*)(rp);
    short8v w1 = *(const short8v*)(rp + 8);
    float e[16];
    #pragma unroll
    for (int q = 0; q < 8; ++q) e[q]     = frombf((u16)w0[q]);
    #pragma unroll
    for (int q = 0; q < 8; ++q) e[q + 8] = frombf((u16)w1[q]);

    float gm = e[0];
    #pragma unroll
    for (int q = 1; q < 16; ++q) gm = fmaxf(gm, e[q]);
    float sorted = sort64_desc(gm, lane);
    float tau = __shfl(sorted, T_ - 1);

    int c = 0;
    #pragma unroll
    for (int q = 0; q < 16; ++q) c += (e[q] >= tau);
    int sc = c;
    #pragma unroll
    for (int o = 1; o < 64; o <<= 1) {
        int t2 = __shfl_up(sc, o);
        if (lane >= o) sc += t2;
    }
    int off = sc - c;
    int cnt = __shfl(sc, 63);                    // >= 48 guaranteed

    float* wb = buf[wave];
    #pragma unroll
    for (int q = 0; q < 16; ++q)
        if (e[q] >= tau) wb[off++] = e[q];

    float* orow = topv + (size_t)row * T_;
    if (cnt <= 64) {
        float a = (lane < cnt) ? wb[lane] : -INFINITY;
        a = sort64_desc(a, lane);
        if (lane < T_) orow[lane] = fmaxf(a, 0.f);
    } else if (cnt <= 128) {
        float a  = sort64_desc(wb[lane], lane);
        float b2 = sort64_desc((lane < cnt - 64) ? wb[64 + lane] : -INFINITY, lane);
        float m2 = bmerge64_desc(a, b2, lane);
        if (lane < T_) orow[lane] = fmaxf(m2, 0.f);
    } else {
        int P = 256; while (P < cnt) P <<= 1;
        for (int i = cnt + lane; i < P; i += 64) wb[i] = -INFINITY;
        for (int k = 2; k <= P; k <<= 1)
            for (int j = k >> 1; j > 0; j >>= 1)
                for (int t2 = lane; t2 < P; t2 += 64) {
                    int ixj = t2 ^ j;
                    if (ixj > t2) {
                        float a = wb[t2], b3 = wb[ixj];
                        bool desc = ((t2 & k) == 0);
                        if (desc ? (a < b3) : (a > b3)) { wb[t2] = b3; wb[ixj] = a; }
                    }
                }
        if (lane < T_) orow[lane] = fmaxf(wb[lane], 0.f);
    }
}

// ---------------------------------------------------------------------------
// 7) column norm over (B,H) and final transpose
// ---------------------------------------------------------------------------
__global__ void k_colss(const float* __restrict__ topv, float* __restrict__ colss) {
    int o = blockIdx.x;
    int w = o / T_, t = o % T_;
    int lane = threadIdx.x;
    float s = 0.f;
    for (int i = lane; i < 512; i += 64) {
        int b = i >> 5, h = i & 31;
        float v = topv[(size_t)((b << 10) + (h << 5) + w) * T_ + t];
        s += v * v;
    }
    for (int off = 32; off > 0; off >>= 1) s += __shfl_down(s, off);
    if (lane == 0) colss[o] = s;
}

__global__ void k_final(const float* __restrict__ topv, const float* __restrict__ colss,
                        float* __restrict__ out) {
    int idx = blockIdx.x * 256 + threadIdx.x;
    if (idx >= B_ * T_ * HW_) return;
    int w = idx & 31;
    int h = (idx >> 5) & 31;
    int t = (idx >> 10) % T_;
    int b = idx / (T_ * HW_);
    float v = topv[(size_t)((b << 10) + (h << 5) + w) * T_ + t];
    out[idx] = v * rsqrtf(colss[w * T_ + t]);
}

// ---------------------------------------------------------------------------
extern "C" void kernel_launch(void* const* d_in, const int* in_sizes, int n_in,
                              void* d_out, int out_size, void* d_ws, size_t ws_size,
                              hipStream_t stream) {
    const float* x     = (const float*)d_in[0];
    const float* fW    = (const float*)d_in[1];
    const float* fb    = (const float*)d_in[2];
    const float* gW    = (const float*)d_in[3];
    const float* gb    = (const float*)d_in[4];
    const float* hW    = (const float*)d_in[5];
    const float* hb    = (const float*)d_in[6];
    const float* scale = (const float*)d_in[7];
    float* out = (float*)d_out;

    char* wsb = (char*)d_ws;
    float* part = (float*)(wsb + 0);                 // 262144 B [64][1024]
    float* ninv = (float*)(wsb + 262144);            // 4096 B
    u16*   hWh  = (u16*)(wsb + 266240);              // 524288 B
    u16*   fgWh = (u16*)(wsb + 790528);              // 131072 B
    float* fgb  = (float*)(wsb + 921600);            // 512 B
    u16*   xnH  = (u16*)(wsb + 922112);              // 16 MB (xn -> fdd bf16)
    u16*   fgH  = (u16*)(wsb + 17699328);            // 4 MB (f|g; later topv)
    u16*   fgL  = (u16*)(wsb + 21893632);            // 4 MB (later colss)
    u16*   hvTH = (u16*)(wsb + 26087936);            // 16 MB (hv)
    float* S    = (float*)(wsb + 42865152);          // 64 MB (P u16 -> corr bf16)
    u16*   fddT = (u16*)(wsb + 109974016);           // 16 MB (fddT)
    float* topv = (float*)fgH;
    float* colss= (float*)fgL;
    u16*   Sp   = (u16*)S;

    const long sXn = 524288;    // [1024][512] elements per batch
    const long sFG = 131072;    // [1024][128]
    const long sS  = 1048576;   // [1024][1024]

    // 1) per-pixel Frobenius norm
    k_colsq<<<256, 256, 0, stream>>>(x, part);
    k_rsqrt<<<4, 256, 0, stream>>>(part, ninv);

    // 2) normalized channel-last bf16
    k_transpose<<<dim3(32, 16, 16), dim3(32, 8), 0, stream>>>(x, ninv, xnH);

    // 3) weight planes
    k_packW<<<1024, 256, 0, stream>>>(hW, hWh);
    k_packFG<<<256, 256, 0, stream>>>(fW, gW, fb, gb, fgWh, fgb);

    // 4) fg = bf16(xn @ [fW|gW]^T + bias[col])  [B,1024,128]  (KU=2)
    k_gemm1<6, 2><<<dim3(1, 8, 16), 256, 0, stream>>>(
        xnH, fgWh, fgb, nullptr, fgH, nullptr, nullptr,
        128, 512, 512, 512, sXn, 0, sFG);

    // 5) hv = bf16(hW @ xn^T + hb[row])  [B,512,1024]  (KU=2)
    k_gemm1<5, 2><<<dim3(8, 4, 16), 256, 0, stream>>>(
        hWh, xnH, hb, nullptr, hvTH, nullptr, nullptr,
        1024, 512, 512, 512, 0, sXn, sXn);

    // 6+7) fused S-GEMM + softmax -> P bf16
    k_ssoft<<<dim3(16, 16), 512, 0, stream>>>(fgH, Sp);

    // 8) fdd = bf16(scale*(P @ hv^T) + xn) in place over xnH + fddT write (KU=2)
    k_gemm1<7, 2><<<dim3(4, 8, 16), 256, 0, stream>>>(
        Sp, hvTH, nullptr, nullptr, xnH, fddT, scale,
        512, 1024, 1024, 1024, sS, sXn, sXn);

    // 9) corr = bf16(fdd @ fddT^T) into S region (128x256 8-wave)
    k_gemm2c<<<dim3(4, 8, 16), 512, 0, stream>>>(
        xnH, fddT, Sp,
        1024, 512, 512, 512, sXn, sXn, sS);

    // 10) top-48 desc + relu (wave-per-row, bf16 input)
    k_topk<<<B_ * HW_ / 4, 256, 0, stream>>>(Sp, topv);

    // 11) norm over (B,H) + output transpose
    k_colss<<<W_ * T_, 64, 0, stream>>>(topv, colss);
    k_final<<<(B_ * T_ * HW_ + 255) / 256, 256, 0, stream>>>(topv, colss, out);
}